// Round 6
// baseline (4029.656 us; speedup 1.0000x reference)
//
#include <hip/hip_runtime.h>
#include <math.h>

#define N_LIT 200000
#define N_CLS 800000
#define NEDGE 2400000
#define NVAR  (N_LIT / 2)

typedef __attribute__((ext_vector_type(8))) short bf16x8;
typedef __attribute__((ext_vector_type(4))) float f32x4;

__device__ __forceinline__ float silu_f(float x) { return x / (1.0f + expf(-x)); }

__device__ __forceinline__ float bf2f(unsigned short u) {
    unsigned int x = ((unsigned int)u) << 16;
    return __uint_as_float(x);
}
__device__ __forceinline__ unsigned short f2bf(float f) {
    unsigned int x = __float_as_uint(f);
    unsigned int r = (x + 0x7fffu + ((x >> 16) & 1u)) >> 16;
    return (unsigned short)r;
}

// ---------------------------------------------------------------- diagnostics
__global__ void diag_kernel(float* __restrict__ out, int n, float val) {
    int i = blockIdx.x * blockDim.x + threadIdx.x;
    int stride = gridDim.x * blockDim.x;
    for (; i < n; i += stride) out[i] = val;
}

// ---------------------------------------------------------------- int utils
__global__ void zero_int4_kernel(int4* __restrict__ p, long n4) {
    long i = (long)blockIdx.x * blockDim.x + threadIdx.x;
    long stride = (long)gridDim.x * blockDim.x;
    for (; i < n4; i += stride) p[i] = make_int4(0, 0, 0, 0);
}

__global__ void copy_int_kernel(int* __restrict__ dst, const int* __restrict__ src, int n) {
    int i = blockIdx.x * blockDim.x + threadIdx.x;
    int stride = gridDim.x * blockDim.x;
    for (; i < n; i += stride) dst[i] = src[i];
}

// ---------------------------------------------------------------- degrees + bucket histograms
// deg via global atomics (low contention); bucket hist via LDS pre-aggregation
__global__ __launch_bounds__(256) void deg_hist_kernel(
    const int* __restrict__ e_lit, const int* __restrict__ e_cls,
    int* __restrict__ deg_lit, int* __restrict__ deg_cls,
    int* __restrict__ bkt_lit, int* __restrict__ bkt_cls) {
    __shared__ int hl[1024], hc[1024];
    int t = threadIdx.x;
    for (int i = t; i < 1024; i += 256) { hl[i] = 0; hc[i] = 0; }
    __syncthreads();
    int stride = gridDim.x * blockDim.x;
    for (int e = blockIdx.x * blockDim.x + t; e < NEDGE; e += stride) {
        int l = e_lit[e], c = e_cls[e];
        atomicAdd(&deg_lit[l], 1);
        atomicAdd(&deg_cls[c], 1);
        atomicAdd(&hl[l >> 8], 1);
        atomicAdd(&hc[c >> 10], 1);
    }
    __syncthreads();
    for (int i = t; i < 1024; i += 256) {
        if (hl[i]) atomicAdd(&bkt_lit[i], hl[i]);
        if (hc[i]) atomicAdd(&bkt_cls[i], hc[i]);
    }
}

__global__ void inv_deg_kernel(const int* __restrict__ deg, float* __restrict__ inv, int n) {
    int i = blockIdx.x * blockDim.x + threadIdx.x;
    if (i < n) {
        int d = deg[i];
        inv[i] = 1.0f / (float)(d > 0 ? d : 1);
    }
}

// ---------------------------------------------------------------- exclusive scan (3-pass)
__global__ void scan_partial_kernel(const int* __restrict__ in, int n, int* __restrict__ part) {
    __shared__ int sh[256];
    int b = blockIdx.x, t = threadIdx.x;
    int base = b * 1024 + t * 4;
    int s = 0;
    #pragma unroll
    for (int i = 0; i < 4; ++i) { int idx = base + i; if (idx < n) s += in[idx]; }
    sh[t] = s; __syncthreads();
    for (int off = 128; off > 0; off >>= 1) {
        if (t < off) sh[t] += sh[t + off];
        __syncthreads();
    }
    if (t == 0) part[b] = sh[0];
}

__global__ void scan_root_kernel(int* __restrict__ part, int nb) {
    __shared__ int sh[1024];
    int t = threadIdx.x;
    int v = (t < nb) ? part[t] : 0;
    sh[t] = v; __syncthreads();
    for (int off = 1; off < 1024; off <<= 1) {
        int add = (t >= off) ? sh[t - off] : 0;
        __syncthreads();
        sh[t] += add;
        __syncthreads();
    }
    if (t < nb) part[t] = sh[t] - v;   // exclusive offsets
}

__global__ void scan_final_kernel(const int* __restrict__ in, const int* __restrict__ part,
                                  int* __restrict__ out, int n) {
    __shared__ int sh[256];
    int b = blockIdx.x, t = threadIdx.x;
    int base = b * 1024 + t * 4;
    int v[4]; int s = 0;
    #pragma unroll
    for (int i = 0; i < 4; ++i) { int idx = base + i; v[i] = (idx < n) ? in[idx] : 0; s += v[i]; }
    sh[t] = s; __syncthreads();
    for (int off = 1; off < 256; off <<= 1) {
        int add = (t >= off) ? sh[t - off] : 0;
        __syncthreads();
        sh[t] += add;
        __syncthreads();
    }
    int run = part[b] + sh[t] - s;
    #pragma unroll
    for (int i = 0; i < 4; ++i) { int idx = base + i; if (idx < n) { out[idx] = run; run += v[i]; } }
}

__global__ void tail_kernel(int* __restrict__ rp_cls, int* __restrict__ rp_lit) {
    if (blockIdx.x == 0 && threadIdx.x == 0) {
        rp_cls[N_CLS] = NEDGE;
        rp_lit[N_LIT] = NEDGE;
    }
}

// ---------------------------------------------------------------- bucketed CSR build
// scatter edges into coarse buckets (contiguous regions -> L2-resident full-line writes)
__global__ __launch_bounds__(256) void bucket_scatter_kernel(
    const int* __restrict__ key, const int* __restrict__ val, int shift,
    int* __restrict__ bktcur, int2* __restrict__ tmp) {
    int stride = gridDim.x * blockDim.x;
    for (int e = blockIdx.x * blockDim.x + threadIdx.x; e < NEDGE; e += stride) {
        int k = key[e], v = val[e];
        int p = atomicAdd(&bktcur[k >> shift], 1);
        tmp[p] = make_int2(k, v);
    }
}

// bucket-ordered pairs -> final CSR adjacency (writes localized per bucket window)
__global__ __launch_bounds__(256) void fill_from_tmp_kernel(
    const int2* __restrict__ tmp, int* __restrict__ cur, int* __restrict__ out) {
    int stride = gridDim.x * blockDim.x;
    for (int i = blockIdx.x * blockDim.x + threadIdx.x; i < NEDGE; i += stride) {
        int2 pr = tmp[i];
        int q = atomicAdd(&cur[pr.x], 1);
        out[q] = pr.y;
    }
}

// ---------------------------------------------------------------- encoder (MFMA 2nd GEMM)
__global__ __launch_bounds__(256, 4) void encoder_kernel(
    const float* __restrict__ x_lit, const float* __restrict__ x_cls,
    const float* __restrict__ w1, const float* __restrict__ b1,
    const float* __restrict__ w2, const float* __restrict__ b2,
    float* __restrict__ h_lit, unsigned short* __restrict__ h_cls) {
    __shared__ float w1s[4 * 64];
    __shared__ float b1s[64], b2s[64];
    __shared__ __align__(16) unsigned short Bp[8 * 64 * 8];
    __shared__ float xt[4][64];
    __shared__ float hs[4][16 * 68];
    int t = threadIdx.x;
    w1s[t] = w1[t];
    if (t < 64) { b1s[t] = b1[t]; b2s[t] = b2[t]; }
    for (int idx = t; idx < 8 * 64 * 8; idx += 256) {
        int i = idx & 7, ln = (idx >> 3) & 63, fid = idx >> 9;
        int ks = fid >> 2, nt = fid & 3;
        Bp[idx] = f2bf(w2[(ks * 32 + ((ln >> 4) << 3) + i) * 64 + nt * 16 + (ln & 15)]);
    }
    __syncthreads();
    int w = t >> 6, lane = t & 63;
    int c = lane & 15, q = lane >> 4;
    bf16x8 Bf[8];
    #pragma unroll
    for (int f = 0; f < 8; ++f) Bf[f] = *(const bf16x8*)&Bp[(f * 64 + lane) * 8];
    float* hw = hs[w];
    int nwaves = gridDim.x * 4;
    int wid = blockIdx.x * 4 + w;
    const int ntiles = (N_LIT + N_CLS) / 16;
    for (int tile = wid; tile < ntiles; tile += nwaves) {
        int row0 = tile * 16;
        const float* xsrc = (row0 < N_LIT) ? x_lit + (size_t)row0 * 4
                                           : x_cls + (size_t)(row0 - N_LIT) * 4;
        xt[w][lane] = xsrc[lane];
        for (int r = 0; r < 16; ++r) {
            float pre = b1s[lane];
            #pragma unroll
            for (int k = 0; k < 4; ++k) pre += xt[w][r * 4 + k] * w1s[k * 64 + lane];
            hw[r * 68 + lane] = silu_f(pre);
        }
        bf16x8 A0, A1;
        const float* ap = &hw[c * 68 + q * 8];
        #pragma unroll
        for (int i = 0; i < 8; ++i) {
            A0[i] = (short)f2bf(ap[i]);
            A1[i] = (short)f2bf(ap[32 + i]);
        }
        f32x4 acc[4];
        #pragma unroll
        for (int nt = 0; nt < 4; ++nt) {
            float bv = b2s[nt * 16 + c];
            acc[nt] = (f32x4){bv, bv, bv, bv};
            acc[nt] = __builtin_amdgcn_mfma_f32_16x16x32_bf16(A0, Bf[nt], acc[nt], 0, 0, 0);
            acc[nt] = __builtin_amdgcn_mfma_f32_16x16x32_bf16(A1, Bf[4 + nt], acc[nt], 0, 0, 0);
        }
        #pragma unroll
        for (int nt = 0; nt < 4; ++nt)
            #pragma unroll
            for (int rg = 0; rg < 4; ++rg)
                hw[(q * 4 + rg) * 68 + nt * 16 + c] = acc[nt][rg];
        if (row0 < N_LIT) {
            for (int r = 0; r < 16; ++r)
                h_lit[(size_t)(row0 + r) * 64 + lane] = hw[r * 68 + lane];
        } else {
            for (int r = 0; r < 16; ++r)
                h_cls[(size_t)(row0 + r - N_LIT) * 64 + lane] = f2bf(hw[r * 68 + lane]);
        }
    }
}

// ---------------------------------------------------------------- X = h_lit @ Wc_bot (MFMA)
__global__ __launch_bounds__(256, 4) void gemmX_kernel(
    const float* __restrict__ in, const float* __restrict__ W,
    unsigned short* __restrict__ out) {
    __shared__ __align__(16) unsigned short Bp[8 * 64 * 8];
    __shared__ float stage[4][16 * 66];
    int t = threadIdx.x;
    for (int idx = t; idx < 8 * 64 * 8; idx += 256) {
        int i = idx & 7, ln = (idx >> 3) & 63, fid = idx >> 9;
        int ks = fid >> 2, nt = fid & 3;
        Bp[idx] = f2bf(W[(ks * 32 + ((ln >> 4) << 3) + i) * 64 + nt * 16 + (ln & 15)]);
    }
    __syncthreads();
    int w = t >> 6, lane = t & 63;
    int c = lane & 15, q = lane >> 4;
    bf16x8 Bf[8];
    #pragma unroll
    for (int f = 0; f < 8; ++f) Bf[f] = *(const bf16x8*)&Bp[(f * 64 + lane) * 8];
    float* ms = stage[w];
    int nwaves = gridDim.x * 4;
    int wid = blockIdx.x * 4 + w;
    for (int tile = wid; tile < N_LIT / 16; tile += nwaves) {
        int row0 = tile * 16;
        const float* ap = in + (size_t)(row0 + c) * 64 + q * 8;
        bf16x8 A0, A1;
        #pragma unroll
        for (int i = 0; i < 8; ++i) {
            A0[i] = (short)f2bf(ap[i]);
            A1[i] = (short)f2bf(ap[32 + i]);
        }
        f32x4 acc[4];
        #pragma unroll
        for (int nt = 0; nt < 4; ++nt) {
            acc[nt] = (f32x4){0.f, 0.f, 0.f, 0.f};
            acc[nt] = __builtin_amdgcn_mfma_f32_16x16x32_bf16(A0, Bf[nt], acc[nt], 0, 0, 0);
            acc[nt] = __builtin_amdgcn_mfma_f32_16x16x32_bf16(A1, Bf[4 + nt], acc[nt], 0, 0, 0);
        }
        #pragma unroll
        for (int nt = 0; nt < 4; ++nt)
            #pragma unroll
            for (int rg = 0; rg < 4; ++rg)
                ms[(q * 4 + rg) * 66 + nt * 16 + c] = acc[nt][rg];
        for (int r = 0; r < 16; ++r)
            out[(size_t)(row0 + r) * 64 + lane] = f2bf(ms[r * 66 + lane]);
    }
}

// ---------------------------------------------------------------- clause update (MFMA + fused gather)
__global__ __launch_bounds__(256, 5) void cls_update_kernel(
    unsigned short* __restrict__ h_cls, const unsigned short* __restrict__ X,
    const int* __restrict__ rp, const int* __restrict__ lits,
    const float* __restrict__ inv_deg, const float* __restrict__ W,
    const float* __restrict__ b, int silu_in) {
    __shared__ __align__(16) unsigned short Bp[8 * 64 * 8];
    __shared__ float bs[64];
    __shared__ float stage[4][16 * 66];
    int t = threadIdx.x;
    for (int idx = t; idx < 8 * 64 * 8; idx += 256) {
        int i = idx & 7, ln = (idx >> 3) & 63, fid = idx >> 9;
        int ks = fid >> 2, nt = fid & 3;
        Bp[idx] = f2bf(W[(ks * 32 + ((ln >> 4) << 3) + i) * 64 + nt * 16 + (ln & 15)]);
    }
    if (t < 64) bs[t] = b[t];
    __syncthreads();
    int w = t >> 6, lane = t & 63;
    int c = lane & 15, q = lane >> 4;
    bf16x8 Bf[8];
    #pragma unroll
    for (int f = 0; f < 8; ++f) Bf[f] = *(const bf16x8*)&Bp[(f * 64 + lane) * 8];
    float* ms = stage[w];
    int nwaves = gridDim.x * 4;
    int wid = blockIdx.x * 4 + w;
    for (int tile = wid; tile < N_CLS / 16; tile += nwaves) {
        int row0 = tile * 16;
        const unsigned short* ap = h_cls + (size_t)(row0 + c) * 64 + q * 8;
        bf16x8 A0 = *(const bf16x8*)(ap);
        bf16x8 A1 = *(const bf16x8*)(ap + 32);
        if (silu_in) {
            #pragma unroll
            for (int i = 0; i < 8; ++i) {
                A0[i] = (short)f2bf(silu_f(bf2f((unsigned short)A0[i])));
                A1[i] = (short)f2bf(silu_f(bf2f((unsigned short)A1[i])));
            }
        }
        f32x4 acc[4];
        #pragma unroll
        for (int nt = 0; nt < 4; ++nt) {
            float bv = bs[nt * 16 + c];
            acc[nt] = (f32x4){bv, bv, bv, bv};
            acc[nt] = __builtin_amdgcn_mfma_f32_16x16x32_bf16(A0, Bf[nt], acc[nt], 0, 0, 0);
            acc[nt] = __builtin_amdgcn_mfma_f32_16x16x32_bf16(A1, Bf[4 + nt], acc[nt], 0, 0, 0);
        }
        for (int r = 0; r < 16; ++r) {
            int row = row0 + r;
            int e0 = rp[row], e1 = rp[row + 1];
            float g0 = 0.f, g1 = 0.f;
            int e = e0;
            for (; e + 1 < e1; e += 2) {
                g0 += bf2f(X[(size_t)lits[e] * 64 + lane]);
                g1 += bf2f(X[(size_t)lits[e + 1] * 64 + lane]);
            }
            if (e < e1) g0 += bf2f(X[(size_t)lits[e] * 64 + lane]);
            ms[r * 66 + lane] = (g0 + g1) * inv_deg[row];
        }
        #pragma unroll
        for (int nt = 0; nt < 4; ++nt)
            #pragma unroll
            for (int rg = 0; rg < 4; ++rg)
                ms[(q * 4 + rg) * 66 + nt * 16 + c] += acc[nt][rg];
        for (int r = 0; r < 16; ++r)
            h_cls[(size_t)(row0 + r) * 64 + lane] = f2bf(ms[r * 66 + lane]);
    }
}

// ---------------------------------------------------------------- lit-side gather (standalone, 4-way MLP)
__global__ __launch_bounds__(256, 8) void gather_lit_kernel(
    const unsigned short* __restrict__ h_cls, const int* __restrict__ rp,
    const int* __restrict__ clss, const float* __restrict__ inv_deg,
    unsigned short* __restrict__ m_out) {
    int nw = (gridDim.x * blockDim.x) >> 6;
    int wid = (blockIdx.x * blockDim.x + threadIdx.x) >> 6;
    int lane = threadIdx.x & 63;
    for (int row = wid; row < N_LIT; row += nw) {
        int e0 = rp[row], e1 = rp[row + 1];
        float g0 = 0.f, g1 = 0.f, g2 = 0.f, g3 = 0.f;
        int e = e0;
        for (; e + 3 < e1; e += 4) {
            int c0 = clss[e], c1 = clss[e + 1], c2 = clss[e + 2], c3 = clss[e + 3];
            g0 += silu_f(bf2f(h_cls[(size_t)c0 * 64 + lane]));
            g1 += silu_f(bf2f(h_cls[(size_t)c1 * 64 + lane]));
            g2 += silu_f(bf2f(h_cls[(size_t)c2 * 64 + lane]));
            g3 += silu_f(bf2f(h_cls[(size_t)c3 * 64 + lane]));
        }
        for (; e < e1; ++e)
            g0 += silu_f(bf2f(h_cls[(size_t)clss[e] * 64 + lane]));
        m_out[(size_t)row * 64 + lane] = f2bf(((g0 + g1) + (g2 + g3)) * inv_deg[row]);
    }
}

// ---------------------------------------------------------------- literal update (MFMA, in-place fp32)
__global__ __launch_bounds__(256, 3) void lit_update_kernel(
    float* __restrict__ h, const unsigned short* __restrict__ m,
    const float* __restrict__ W, const float* __restrict__ b) {
    __shared__ __align__(16) unsigned short Bp[24 * 64 * 8];
    __shared__ float bs[64];
    __shared__ float stage[4][16 * 66];
    int t = threadIdx.x;
    for (int idx = t; idx < 24 * 64 * 8; idx += 256) {
        int i = idx & 7, ln = (idx >> 3) & 63, fid = idx >> 9;
        int ks = fid >> 2, nt = fid & 3;
        Bp[idx] = f2bf(W[(ks * 32 + ((ln >> 4) << 3) + i) * 64 + nt * 16 + (ln & 15)]);
    }
    if (t < 64) bs[t] = b[t];
    __syncthreads();
    int w = t >> 6, lane = t & 63;
    int c = lane & 15, q = lane >> 4;
    bf16x8 Bf[24];
    #pragma unroll
    for (int f = 0; f < 24; ++f) Bf[f] = *(const bf16x8*)&Bp[(f * 64 + lane) * 8];
    float* ms = stage[w];
    int nwaves = gridDim.x * 4;
    int wid = blockIdx.x * 4 + w;
    for (int tile = wid; tile < N_LIT / 16; tile += nwaves) {
        int row0 = tile * 16;
        bf16x8 A[6];
        const float* hp = h + (size_t)(row0 + c) * 64 + q * 8;
        const float* hf = h + (size_t)((row0 + c) ^ 1) * 64 + q * 8;
        const unsigned short* mp = m + (size_t)(row0 + c) * 64 + q * 8;
        #pragma unroll
        for (int i = 0; i < 8; ++i) {
            A[0][i] = (short)f2bf(hp[i]);
            A[1][i] = (short)f2bf(hp[32 + i]);
            A[4][i] = (short)f2bf(hf[i]);
            A[5][i] = (short)f2bf(hf[32 + i]);
        }
        A[2] = *(const bf16x8*)(mp);
        A[3] = *(const bf16x8*)(mp + 32);
        f32x4 acc[4];
        #pragma unroll
        for (int nt = 0; nt < 4; ++nt) {
            float bv = bs[nt * 16 + c];
            acc[nt] = (f32x4){bv, bv, bv, bv};
            #pragma unroll
            for (int ks = 0; ks < 6; ++ks)
                acc[nt] = __builtin_amdgcn_mfma_f32_16x16x32_bf16(A[ks], Bf[ks * 4 + nt], acc[nt], 0, 0, 0);
        }
        #pragma unroll
        for (int nt = 0; nt < 4; ++nt)
            #pragma unroll
            for (int rg = 0; rg < 4; ++rg)
                ms[(q * 4 + rg) * 66 + nt * 16 + c] = silu_f(acc[nt][rg]);
        for (int r = 0; r < 16; ++r)
            h[(size_t)(row0 + r) * 64 + lane] = ms[r * 66 + lane];
    }
}

// ---------------------------------------------------------------- readout stage 1 (fp32 VALU -> bf16 hid)
__global__ __launch_bounds__(256) void var_hidden_kernel(
    const float* __restrict__ h_var, const float* __restrict__ W,
    const float* __restrict__ b, int colofs, unsigned short* __restrict__ hid) {
    __shared__ float Ws[128 * 64];
    __shared__ float bs[64];
    __shared__ float rs[16 * 128];
    int t = threadIdx.x;
    for (int i = t; i < 128 * 64; i += 256) {
        int k = i >> 6, j = i & 63;
        Ws[i] = W[k * 128 + colofs + j];
    }
    if (t < 64) bs[t] = b[colofs + t];
    __syncthreads();
    const int ntiles = NVAR / 16;
    int w = t >> 6, j = t & 63;
    for (int tile = blockIdx.x; tile < ntiles; tile += gridDim.x) {
        int row0 = tile * 16;
        for (int i = t; i < 2048; i += 256) rs[i] = h_var[(size_t)row0 * 128 + i];
        __syncthreads();
        float acc0 = bs[j], acc1 = bs[j], acc2 = bs[j], acc3 = bs[j];
        const float* r0 = &rs[(w * 4 + 0) * 128];
        const float* r1 = &rs[(w * 4 + 1) * 128];
        const float* r2 = &rs[(w * 4 + 2) * 128];
        const float* r3 = &rs[(w * 4 + 3) * 128];
        #pragma unroll 4
        for (int k = 0; k < 128; k += 4) {
            float w0 = Ws[k * 64 + j], w1v = Ws[(k + 1) * 64 + j];
            float w2v = Ws[(k + 2) * 64 + j], w3v = Ws[(k + 3) * 64 + j];
            float4 a;
            a = *(const float4*)(r0 + k); acc0 += a.x * w0 + a.y * w1v + a.z * w2v + a.w * w3v;
            a = *(const float4*)(r1 + k); acc1 += a.x * w0 + a.y * w1v + a.z * w2v + a.w * w3v;
            a = *(const float4*)(r2 + k); acc2 += a.x * w0 + a.y * w1v + a.z * w2v + a.w * w3v;
            a = *(const float4*)(r3 + k); acc3 += a.x * w0 + a.y * w1v + a.z * w2v + a.w * w3v;
        }
        int row = row0 + w * 4;
        hid[(size_t)(row + 0) * 128 + colofs + j] = f2bf(silu_f(acc0));
        hid[(size_t)(row + 1) * 128 + colofs + j] = f2bf(silu_f(acc1));
        hid[(size_t)(row + 2) * 128 + colofs + j] = f2bf(silu_f(acc2));
        hid[(size_t)(row + 3) * 128 + colofs + j] = f2bf(silu_f(acc3));
        __syncthreads();
    }
}

// ---------------------------------------------------------------- readout stage 2
__global__ __launch_bounds__(256) void out2_kernel(
    const unsigned short* __restrict__ hid, const float* __restrict__ w2,
    const float* __restrict__ b2, float* __restrict__ out) {
    int nw = (gridDim.x * blockDim.x) >> 6;
    int wid = (blockIdx.x * blockDim.x + threadIdx.x) >> 6;
    int lane = threadIdx.x & 63;
    float w00 = w2[lane * 2 + 0], w01 = w2[lane * 2 + 1];
    float w10 = w2[(lane + 64) * 2 + 0], w11 = w2[(lane + 64) * 2 + 1];
    for (int row = wid; row < NVAR; row += nw) {
        float h0 = bf2f(hid[(size_t)row * 128 + lane]);
        float h1 = bf2f(hid[(size_t)row * 128 + 64 + lane]);
        float p0 = h0 * w00 + h1 * w10;
        float p1 = h0 * w01 + h1 * w11;
        #pragma unroll
        for (int off = 32; off > 0; off >>= 1) {
            p0 += __shfl_down(p0, off);
            p1 += __shfl_down(p1, off);
        }
        if (lane == 0) {
            out[(size_t)row * 2 + 0] = p0 + b2[0];
            out[(size_t)row * 2 + 1] = p1 + b2[1];
        }
    }
}

// ---------------------------------------------------------------- launch
extern "C" void kernel_launch(void* const* d_in, const int* in_sizes, int n_in,
                              void* d_out, int out_size, void* d_ws, size_t ws_size,
                              hipStream_t stream) {
    const float* x_lit  = (const float*)d_in[0];
    const float* x_cls  = (const float*)d_in[1];
    const int* edge_lit = (const int*)d_in[2];
    const int* edge_cls = (const int*)d_in[3];
    const float* enc_w1 = (const float*)d_in[4];
    const float* enc_b1 = (const float*)d_in[5];
    const float* enc_w2 = (const float*)d_in[6];
    const float* enc_b2 = (const float*)d_in[7];
    const float* Wc     = (const float*)d_in[8];    // [4][128][64]
    const float* bc     = (const float*)d_in[9];
    const float* Wl     = (const float*)d_in[10];   // [4][192][64]
    const float* bl     = (const float*)d_in[11];
    const float* out_w1 = (const float*)d_in[12];   // [128][128]
    const float* out_b1 = (const float*)d_in[13];
    const float* out_w2 = (const float*)d_in[14];   // [128][2]
    const float* out_b2 = (const float*)d_in[15];
    float* y = (float*)d_out;

    // ---- workspace carve (~211 MB) ----
    const size_t SZ_HLIT = (size_t)N_LIT * 64;
    const size_t SZ_HCLS = (size_t)N_CLS * 64;
    char* p = (char*)d_ws;
    auto take = [&](size_t bytes) -> char* {
        char* r = p; p += (bytes + 255) & ~(size_t)255; return r;
    };
    float*          h_lit      = (float*)take(SZ_HLIT * 4);
    unsigned short* h_cls      = (unsigned short*)take(SZ_HCLS * 2);
    unsigned short* X          = (unsigned short*)take(SZ_HLIT * 2);
    float*          inv_cls    = (float*)take((size_t)N_CLS * 4);
    float*          inv_lit    = (float*)take((size_t)N_LIT * 4);
    int*            row_ptr_cls= (int*)take((size_t)(N_CLS + 1) * 4);
    int*            row_ptr_lit= (int*)take((size_t)(N_LIT + 1) * 4);
    int*            cur_cls    = (int*)take((size_t)(N_CLS + N_LIT + 2048) * 4);
    int*            cur_lit    = cur_cls + N_CLS;
    int*            bktA       = cur_lit + N_LIT;   // cls buckets (c>>10), 1024
    int*            bktB       = bktA + 1024;       // lit buckets (l>>8), 1024
    int*            lit_by_cls = (int*)take((size_t)NEDGE * 4);
    int*            cls_by_lit = (int*)take((size_t)NEDGE * 4);
    int*            partA      = (int*)take(1024 * 4);
    int*            partB      = (int*)take(1024 * 4);
    size_t need = (size_t)(p - (char*)d_ws);

    // pair buffer aliases h_lit (dead until encoder): 2.4M * 8B = 19.2 MB <= 51.2 MB
    int2* tmp_pairs = (int2*)h_lit;

    dim3 B(256);

    if (ws_size < need) {
        float mb = (float)((double)ws_size / (1024.0 * 1024.0));
        diag_kernel<<<256, B, 0, stream>>>(y, out_size, mb);
        return;
    }

    // ---- CSR build (bucketed, write-locality-friendly) ----
    zero_int4_kernel<<<512, B, 0, stream>>>((int4*)cur_cls, (long)(N_CLS + N_LIT + 2048) / 4);
    deg_hist_kernel<<<2048, B, 0, stream>>>(edge_lit, edge_cls, cur_lit, cur_cls, bktB, bktA);
    inv_deg_kernel<<<(N_CLS + 255) / 256, B, 0, stream>>>(cur_cls, inv_cls, N_CLS);
    inv_deg_kernel<<<(N_LIT + 255) / 256, B, 0, stream>>>(cur_lit, inv_lit, N_LIT);
    int nbc = (N_CLS + 1023) / 1024;
    int nbl = (N_LIT + 1023) / 1024;
    scan_partial_kernel<<<nbc, B, 0, stream>>>(cur_cls, N_CLS, partA);
    scan_root_kernel<<<1, 1024, 0, stream>>>(partA, nbc);
    scan_final_kernel<<<nbc, B, 0, stream>>>(cur_cls, partA, row_ptr_cls, N_CLS);
    scan_partial_kernel<<<nbl, B, 0, stream>>>(cur_lit, N_LIT, partB);
    scan_root_kernel<<<1, 1024, 0, stream>>>(partB, nbl);
    scan_final_kernel<<<nbl, B, 0, stream>>>(cur_lit, partB, row_ptr_lit, N_LIT);
    tail_kernel<<<1, 64, 0, stream>>>(row_ptr_cls, row_ptr_lit);
    copy_int_kernel<<<1024, B, 0, stream>>>(cur_cls, row_ptr_cls, N_CLS);
    copy_int_kernel<<<512, B, 0, stream>>>(cur_lit, row_ptr_lit, N_LIT);
    scan_root_kernel<<<1, 1024, 0, stream>>>(bktA, 1024);   // bucket counts -> cursors
    scan_root_kernel<<<1, 1024, 0, stream>>>(bktB, 1024);
    // cls side: bucket-scatter then localized fill
    bucket_scatter_kernel<<<2048, B, 0, stream>>>(edge_cls, edge_lit, 10, bktA, tmp_pairs);
    fill_from_tmp_kernel<<<2048, B, 0, stream>>>(tmp_pairs, cur_cls, lit_by_cls);
    // lit side
    bucket_scatter_kernel<<<2048, B, 0, stream>>>(edge_lit, edge_cls, 8, bktB, tmp_pairs);
    fill_from_tmp_kernel<<<2048, B, 0, stream>>>(tmp_pairs, cur_lit, cls_by_lit);

    // ---- encoder (overwrites the tmp_pairs alias region) ----
    encoder_kernel<<<2048, B, 0, stream>>>(x_lit, x_cls, enc_w1, enc_b1, enc_w2, enc_b2,
                                           h_lit, h_cls);

    for (int l = 0; l < 4; ++l) {
        const float* Wc_l = Wc + (size_t)l * 128 * 64;
        const float* Wl_l = Wl + (size_t)l * 192 * 64;
        gemmX_kernel<<<1024, B, 0, stream>>>(h_lit, Wc_l + 64 * 64, X);
        cls_update_kernel<<<2048, B, 0, stream>>>(h_cls, X, row_ptr_cls, lit_by_cls,
                                                  inv_cls, Wc_l, bc + l * 64, l > 0);
        gather_lit_kernel<<<4096, B, 0, stream>>>(h_cls, row_ptr_lit, cls_by_lit,
                                                  inv_lit, X);
        lit_update_kernel<<<1024, B, 0, stream>>>(h_lit, X, Wl_l, bl + l * 64);
    }

    // ---- readout ----
    var_hidden_kernel<<<4096, B, 0, stream>>>(h_lit, out_w1, out_b1, 0, X);
    var_hidden_kernel<<<4096, B, 0, stream>>>(h_lit, out_w1, out_b1, 64, X);
    out2_kernel<<<2048, B, 0, stream>>>(X, out_w2, out_b2, y);
}

// Round 7
// 2594.881 us; speedup vs baseline: 1.5529x; 1.5529x over previous
//
#include <hip/hip_runtime.h>
#include <math.h>

#define N_LIT 200000
#define N_CLS 800000
#define NEDGE 2400000
#define NVAR  (N_LIT / 2)

typedef __attribute__((ext_vector_type(8))) short bf16x8;
typedef __attribute__((ext_vector_type(4))) float f32x4;

__device__ __forceinline__ float silu_f(float x) { return x / (1.0f + expf(-x)); }

__device__ __forceinline__ float bf2f(unsigned short u) {
    unsigned int x = ((unsigned int)u) << 16;
    return __uint_as_float(x);
}
__device__ __forceinline__ unsigned short f2bf(float f) {
    unsigned int x = __float_as_uint(f);
    unsigned int r = (x + 0x7fffu + ((x >> 16) & 1u)) >> 16;
    return (unsigned short)r;
}

// ---------------------------------------------------------------- diagnostics
__global__ void diag_kernel(float* __restrict__ out, int n, float val) {
    int i = blockIdx.x * blockDim.x + threadIdx.x;
    int stride = gridDim.x * blockDim.x;
    for (; i < n; i += stride) out[i] = val;
}

// ---------------------------------------------------------------- int utils
__global__ void zero_int4_kernel(int4* __restrict__ p, long n4) {
    long i = (long)blockIdx.x * blockDim.x + threadIdx.x;
    long stride = (long)gridDim.x * blockDim.x;
    for (; i < n4; i += stride) p[i] = make_int4(0, 0, 0, 0);
}

__global__ void copy_int_kernel(int* __restrict__ dst, const int* __restrict__ src, int n) {
    int i = blockIdx.x * blockDim.x + threadIdx.x;
    int stride = gridDim.x * blockDim.x;
    for (; i < n; i += stride) dst[i] = src[i];
}

// ---------------------------------------------------------------- degrees
__global__ void deg_kernel(const int* __restrict__ edge_lit, const int* __restrict__ edge_cls,
                           int* __restrict__ deg_lit, int* __restrict__ deg_cls) {
    int stride = gridDim.x * blockDim.x;
    for (int e = blockIdx.x * blockDim.x + threadIdx.x; e < NEDGE; e += stride) {
        atomicAdd(&deg_lit[edge_lit[e]], 1);
        atomicAdd(&deg_cls[edge_cls[e]], 1);
    }
}

__global__ void inv_deg_kernel(const int* __restrict__ deg, float* __restrict__ inv, int n) {
    int i = blockIdx.x * blockDim.x + threadIdx.x;
    if (i < n) {
        int d = deg[i];
        inv[i] = 1.0f / (float)(d > 0 ? d : 1);
    }
}

// ---------------------------------------------------------------- exclusive scan (3-pass)
__global__ void scan_partial_kernel(const int* __restrict__ in, int n, int* __restrict__ part) {
    __shared__ int sh[256];
    int b = blockIdx.x, t = threadIdx.x;
    int base = b * 1024 + t * 4;
    int s = 0;
    #pragma unroll
    for (int i = 0; i < 4; ++i) { int idx = base + i; if (idx < n) s += in[idx]; }
    sh[t] = s; __syncthreads();
    for (int off = 128; off > 0; off >>= 1) {
        if (t < off) sh[t] += sh[t + off];
        __syncthreads();
    }
    if (t == 0) part[b] = sh[0];
}

__global__ void scan_root_kernel(int* __restrict__ part, int nb) {
    __shared__ int sh[1024];
    int t = threadIdx.x;
    int v = (t < nb) ? part[t] : 0;
    sh[t] = v; __syncthreads();
    for (int off = 1; off < 1024; off <<= 1) {
        int add = (t >= off) ? sh[t - off] : 0;
        __syncthreads();
        sh[t] += add;
        __syncthreads();
    }
    if (t < nb) part[t] = sh[t] - v;   // exclusive offsets
}

__global__ void scan_final_kernel(const int* __restrict__ in, const int* __restrict__ part,
                                  int* __restrict__ out, int n) {
    __shared__ int sh[256];
    int b = blockIdx.x, t = threadIdx.x;
    int base = b * 1024 + t * 4;
    int v[4]; int s = 0;
    #pragma unroll
    for (int i = 0; i < 4; ++i) { int idx = base + i; v[i] = (idx < n) ? in[idx] : 0; s += v[i]; }
    sh[t] = s; __syncthreads();
    for (int off = 1; off < 256; off <<= 1) {
        int add = (t >= off) ? sh[t - off] : 0;
        __syncthreads();
        sh[t] += add;
        __syncthreads();
    }
    int run = part[b] + sh[t] - s;
    #pragma unroll
    for (int i = 0; i < 4; ++i) { int idx = base + i; if (idx < n) { out[idx] = run; run += v[i]; } }
}

__global__ void tail_kernel(int* __restrict__ rp_cls, int* __restrict__ rp_lit) {
    if (blockIdx.x == 0 && threadIdx.x == 0) {
        rp_cls[N_CLS] = NEDGE;
        rp_lit[N_LIT] = NEDGE;
    }
}

// ---------------------------------------------------------------- CSR fill (direct; write-allocate-bound but proven fastest)
__global__ __launch_bounds__(256) void fill_csr_kernel(
    const int* __restrict__ e_lit, const int* __restrict__ e_cls,
    int* __restrict__ cur_cls, int* __restrict__ cur_lit,
    int* __restrict__ lit_by_cls, int* __restrict__ cls_by_lit) {
    int stride = gridDim.x * blockDim.x;
    for (int e = blockIdx.x * blockDim.x + threadIdx.x; e < NEDGE; e += stride) {
        int l = e_lit[e], c = e_cls[e];
        int p = atomicAdd(&cur_cls[c], 1); lit_by_cls[p] = l;
        int q = atomicAdd(&cur_lit[l], 1); cls_by_lit[q] = c;
    }
}

// ---------------------------------------------------------------- encoder (MFMA 2nd GEMM)
__global__ __launch_bounds__(256, 4) void encoder_kernel(
    const float* __restrict__ x_lit, const float* __restrict__ x_cls,
    const float* __restrict__ w1, const float* __restrict__ b1,
    const float* __restrict__ w2, const float* __restrict__ b2,
    float* __restrict__ h_lit, unsigned short* __restrict__ h_cls) {
    __shared__ float w1s[4 * 64];
    __shared__ float b1s[64], b2s[64];
    __shared__ __align__(16) unsigned short Bp[8 * 64 * 8];
    __shared__ float xt[4][64];
    __shared__ float hs[4][16 * 68];
    int t = threadIdx.x;
    w1s[t] = w1[t];
    if (t < 64) { b1s[t] = b1[t]; b2s[t] = b2[t]; }
    for (int idx = t; idx < 8 * 64 * 8; idx += 256) {
        int i = idx & 7, ln = (idx >> 3) & 63, fid = idx >> 9;
        int ks = fid >> 2, nt = fid & 3;
        Bp[idx] = f2bf(w2[(ks * 32 + ((ln >> 4) << 3) + i) * 64 + nt * 16 + (ln & 15)]);
    }
    __syncthreads();
    int w = t >> 6, lane = t & 63;
    int c = lane & 15, q = lane >> 4;
    bf16x8 Bf[8];
    #pragma unroll
    for (int f = 0; f < 8; ++f) Bf[f] = *(const bf16x8*)&Bp[(f * 64 + lane) * 8];
    float* hw = hs[w];
    int nwaves = gridDim.x * 4;
    int wid = blockIdx.x * 4 + w;
    const int ntiles = (N_LIT + N_CLS) / 16;
    for (int tile = wid; tile < ntiles; tile += nwaves) {
        int row0 = tile * 16;
        const float* xsrc = (row0 < N_LIT) ? x_lit + (size_t)row0 * 4
                                           : x_cls + (size_t)(row0 - N_LIT) * 4;
        xt[w][lane] = xsrc[lane];
        for (int r = 0; r < 16; ++r) {
            float pre = b1s[lane];
            #pragma unroll
            for (int k = 0; k < 4; ++k) pre += xt[w][r * 4 + k] * w1s[k * 64 + lane];
            hw[r * 68 + lane] = silu_f(pre);
        }
        bf16x8 A0, A1;
        const float* ap = &hw[c * 68 + q * 8];
        #pragma unroll
        for (int i = 0; i < 8; ++i) {
            A0[i] = (short)f2bf(ap[i]);
            A1[i] = (short)f2bf(ap[32 + i]);
        }
        f32x4 acc[4];
        #pragma unroll
        for (int nt = 0; nt < 4; ++nt) {
            float bv = b2s[nt * 16 + c];
            acc[nt] = (f32x4){bv, bv, bv, bv};
            acc[nt] = __builtin_amdgcn_mfma_f32_16x16x32_bf16(A0, Bf[nt], acc[nt], 0, 0, 0);
            acc[nt] = __builtin_amdgcn_mfma_f32_16x16x32_bf16(A1, Bf[4 + nt], acc[nt], 0, 0, 0);
        }
        #pragma unroll
        for (int nt = 0; nt < 4; ++nt)
            #pragma unroll
            for (int rg = 0; rg < 4; ++rg)
                hw[(q * 4 + rg) * 68 + nt * 16 + c] = acc[nt][rg];
        if (row0 < N_LIT) {
            for (int r = 0; r < 16; ++r)
                h_lit[(size_t)(row0 + r) * 64 + lane] = hw[r * 68 + lane];
        } else {
            for (int r = 0; r < 16; ++r)
                h_cls[(size_t)(row0 + r - N_LIT) * 64 + lane] = f2bf(hw[r * 68 + lane]);
        }
    }
}

// ---------------------------------------------------------------- X = h_lit @ Wc_bot (MFMA) — layer 0 only
__global__ __launch_bounds__(256, 4) void gemmX_kernel(
    const float* __restrict__ in, const float* __restrict__ W,
    unsigned short* __restrict__ out) {
    __shared__ __align__(16) unsigned short Bp[8 * 64 * 8];
    __shared__ float stage[4][16 * 66];
    int t = threadIdx.x;
    for (int idx = t; idx < 8 * 64 * 8; idx += 256) {
        int i = idx & 7, ln = (idx >> 3) & 63, fid = idx >> 9;
        int ks = fid >> 2, nt = fid & 3;
        Bp[idx] = f2bf(W[(ks * 32 + ((ln >> 4) << 3) + i) * 64 + nt * 16 + (ln & 15)]);
    }
    __syncthreads();
    int w = t >> 6, lane = t & 63;
    int c = lane & 15, q = lane >> 4;
    bf16x8 Bf[8];
    #pragma unroll
    for (int f = 0; f < 8; ++f) Bf[f] = *(const bf16x8*)&Bp[(f * 64 + lane) * 8];
    float* ms = stage[w];
    int nwaves = gridDim.x * 4;
    int wid = blockIdx.x * 4 + w;
    for (int tile = wid; tile < N_LIT / 16; tile += nwaves) {
        int row0 = tile * 16;
        const float* ap = in + (size_t)(row0 + c) * 64 + q * 8;
        bf16x8 A0, A1;
        #pragma unroll
        for (int i = 0; i < 8; ++i) {
            A0[i] = (short)f2bf(ap[i]);
            A1[i] = (short)f2bf(ap[32 + i]);
        }
        f32x4 acc[4];
        #pragma unroll
        for (int nt = 0; nt < 4; ++nt) {
            acc[nt] = (f32x4){0.f, 0.f, 0.f, 0.f};
            acc[nt] = __builtin_amdgcn_mfma_f32_16x16x32_bf16(A0, Bf[nt], acc[nt], 0, 0, 0);
            acc[nt] = __builtin_amdgcn_mfma_f32_16x16x32_bf16(A1, Bf[4 + nt], acc[nt], 0, 0, 0);
        }
        #pragma unroll
        for (int nt = 0; nt < 4; ++nt)
            #pragma unroll
            for (int rg = 0; rg < 4; ++rg)
                ms[(q * 4 + rg) * 66 + nt * 16 + c] = acc[nt][rg];
        for (int r = 0; r < 16; ++r)
            out[(size_t)(row0 + r) * 64 + lane] = f2bf(ms[r * 66 + lane]);
    }
}

// ---------------------------------------------------------------- clause update (MFMA + flattened-tile gather)
// h_cls[c] = (silu?(h_cls[c]) @ Wc_top + bc) + inv[c] * sum_e X[lit[e]]
// gather: tile's edges are ONE contiguous CSR range; stage lits in LDS, 8-deep
// pipelined independent X loads, accumulate into LDS D-staging rows.
__global__ __launch_bounds__(256, 5) void cls_update_kernel(
    unsigned short* __restrict__ h_cls, const unsigned short* __restrict__ X,
    const int* __restrict__ rp, const int* __restrict__ lits,
    const float* __restrict__ inv_deg, const float* __restrict__ W,
    const float* __restrict__ b, int silu_in) {
    __shared__ __align__(16) unsigned short Bp[8 * 64 * 8];
    __shared__ float bs[64];
    __shared__ float stage[4][16 * 66];
    __shared__ int rps[4][17];
    __shared__ int lse[4][128];
    int t = threadIdx.x;
    for (int idx = t; idx < 8 * 64 * 8; idx += 256) {
        int i = idx & 7, ln = (idx >> 3) & 63, fid = idx >> 9;
        int ks = fid >> 2, nt = fid & 3;
        Bp[idx] = f2bf(W[(ks * 32 + ((ln >> 4) << 3) + i) * 64 + nt * 16 + (ln & 15)]);
    }
    if (t < 64) bs[t] = b[t];
    __syncthreads();
    int w = t >> 6, lane = t & 63;
    int c = lane & 15, q = lane >> 4;
    bf16x8 Bf[8];
    #pragma unroll
    for (int f = 0; f < 8; ++f) Bf[f] = *(const bf16x8*)&Bp[(f * 64 + lane) * 8];
    float* ms = stage[w];
    int* rpw = rps[w];
    int* lsw = lse[w];
    int nwaves = gridDim.x * 4;
    int wid = blockIdx.x * 4 + w;
    for (int tile = wid; tile < N_CLS / 16; tile += nwaves) {
        int row0 = tile * 16;
        const unsigned short* ap = h_cls + (size_t)(row0 + c) * 64 + q * 8;
        bf16x8 A0 = *(const bf16x8*)(ap);
        bf16x8 A1 = *(const bf16x8*)(ap + 32);
        if (silu_in) {
            #pragma unroll
            for (int i = 0; i < 8; ++i) {
                A0[i] = (short)f2bf(silu_f(bf2f((unsigned short)A0[i])));
                A1[i] = (short)f2bf(silu_f(bf2f((unsigned short)A1[i])));
            }
        }
        f32x4 acc[4];
        #pragma unroll
        for (int nt = 0; nt < 4; ++nt) {
            float bv = bs[nt * 16 + c];
            acc[nt] = (f32x4){bv, bv, bv, bv};
            acc[nt] = __builtin_amdgcn_mfma_f32_16x16x32_bf16(A0, Bf[nt], acc[nt], 0, 0, 0);
            acc[nt] = __builtin_amdgcn_mfma_f32_16x16x32_bf16(A1, Bf[4 + nt], acc[nt], 0, 0, 0);
        }
        // zero accumulation rows; stage row pointers (wave-synchronous LDS)
        #pragma unroll
        for (int r = 0; r < 16; ++r) ms[r * 66 + lane] = 0.f;
        if (lane < 17) rpw[lane] = rp[row0 + lane];
        int E0 = rpw[0], E1 = rpw[16];
        int r = 0, endr = rpw[1];
        for (int base = E0; base < E1; base += 128) {
            int n = E1 - base; if (n > 128) n = 128;
            for (int i = lane; i < n; i += 64) lsw[i] = lits[base + i];
            int i = 0;
            for (; i + 7 < n; i += 8) {
                float v[8];
                #pragma unroll
                for (int k = 0; k < 8; ++k)
                    v[k] = bf2f(X[(size_t)lsw[i + k] * 64 + lane]);
                #pragma unroll
                for (int k = 0; k < 8; ++k) {
                    int g = base + i + k;
                    while (g >= endr) { ++r; endr = rpw[r + 1]; }
                    ms[r * 66 + lane] += v[k];
                }
            }
            for (; i < n; ++i) {
                float v0 = bf2f(X[(size_t)lsw[i] * 64 + lane]);
                int g = base + i;
                while (g >= endr) { ++r; endr = rpw[r + 1]; }
                ms[r * 66 + lane] += v0;
            }
        }
        for (int rr = 0; rr < 16; ++rr)
            ms[rr * 66 + lane] *= inv_deg[row0 + rr];
        #pragma unroll
        for (int nt = 0; nt < 4; ++nt)
            #pragma unroll
            for (int rg = 0; rg < 4; ++rg)
                ms[(q * 4 + rg) * 66 + nt * 16 + c] += acc[nt][rg];
        for (int rr = 0; rr < 16; ++rr)
            h_cls[(size_t)(row0 + rr) * 64 + lane] = f2bf(ms[rr * 66 + lane]);
    }
}

// ---------------------------------------------------------------- lit-side gather (standalone, 4-way MLP)
__global__ __launch_bounds__(256, 8) void gather_lit_kernel(
    const unsigned short* __restrict__ h_cls, const int* __restrict__ rp,
    const int* __restrict__ clss, const float* __restrict__ inv_deg,
    unsigned short* __restrict__ m_out) {
    int nw = (gridDim.x * blockDim.x) >> 6;
    int wid = (blockIdx.x * blockDim.x + threadIdx.x) >> 6;
    int lane = threadIdx.x & 63;
    for (int row = wid; row < N_LIT; row += nw) {
        int e0 = rp[row], e1 = rp[row + 1];
        float g0 = 0.f, g1 = 0.f, g2 = 0.f, g3 = 0.f;
        int e = e0;
        for (; e + 3 < e1; e += 4) {
            int c0 = clss[e], c1 = clss[e + 1], c2 = clss[e + 2], c3 = clss[e + 3];
            g0 += silu_f(bf2f(h_cls[(size_t)c0 * 64 + lane]));
            g1 += silu_f(bf2f(h_cls[(size_t)c1 * 64 + lane]));
            g2 += silu_f(bf2f(h_cls[(size_t)c2 * 64 + lane]));
            g3 += silu_f(bf2f(h_cls[(size_t)c3 * 64 + lane]));
        }
        for (; e < e1; ++e)
            g0 += silu_f(bf2f(h_cls[(size_t)clss[e] * 64 + lane]));
        m_out[(size_t)row * 64 + lane] = f2bf(((g0 + g1) + (g2 + g3)) * inv_deg[row]);
    }
}

// ---------------------------------------------------------------- literal update (MFMA, in-place fp32, + fused next-layer X)
// h[row] = silu([h[row], m[row], h[row^1]] @ W + b); if Wc_next: X[row] = h_new @ Wc_next
__global__ __launch_bounds__(256, 3) void lit_update_kernel(
    float* __restrict__ h, const unsigned short* __restrict__ m,
    const float* __restrict__ W, const float* __restrict__ b,
    const float* __restrict__ Wc_next, unsigned short* __restrict__ Xout) {
    __shared__ __align__(16) unsigned short Bp[24 * 64 * 8];   // 24 KB
    __shared__ __align__(16) unsigned short Bp2[8 * 64 * 8];   // 8 KB (next-layer Wc_bot)
    __shared__ float bs[64];
    __shared__ float stage[4][16 * 66];
    int t = threadIdx.x;
    for (int idx = t; idx < 24 * 64 * 8; idx += 256) {
        int i = idx & 7, ln = (idx >> 3) & 63, fid = idx >> 9;
        int ks = fid >> 2, nt = fid & 3;
        Bp[idx] = f2bf(W[(ks * 32 + ((ln >> 4) << 3) + i) * 64 + nt * 16 + (ln & 15)]);
    }
    if (Wc_next) {
        for (int idx = t; idx < 8 * 64 * 8; idx += 256) {
            int i = idx & 7, ln = (idx >> 3) & 63, fid = idx >> 9;
            int ks = fid >> 2, nt = fid & 3;
            Bp2[idx] = f2bf(Wc_next[(ks * 32 + ((ln >> 4) << 3) + i) * 64 + nt * 16 + (ln & 15)]);
        }
    }
    if (t < 64) bs[t] = b[t];
    __syncthreads();
    int w = t >> 6, lane = t & 63;
    int c = lane & 15, q = lane >> 4;
    bf16x8 Bf[24];
    #pragma unroll
    for (int f = 0; f < 24; ++f) Bf[f] = *(const bf16x8*)&Bp[(f * 64 + lane) * 8];
    float* ms = stage[w];
    int nwaves = gridDim.x * 4;
    int wid = blockIdx.x * 4 + w;
    for (int tile = wid; tile < N_LIT / 16; tile += nwaves) {
        int row0 = tile * 16;
        bf16x8 A[6];
        const float* hp = h + (size_t)(row0 + c) * 64 + q * 8;
        const float* hf = h + (size_t)((row0 + c) ^ 1) * 64 + q * 8;
        const unsigned short* mp = m + (size_t)(row0 + c) * 64 + q * 8;
        #pragma unroll
        for (int i = 0; i < 8; ++i) {
            A[0][i] = (short)f2bf(hp[i]);
            A[1][i] = (short)f2bf(hp[32 + i]);
            A[4][i] = (short)f2bf(hf[i]);
            A[5][i] = (short)f2bf(hf[32 + i]);
        }
        A[2] = *(const bf16x8*)(mp);
        A[3] = *(const bf16x8*)(mp + 32);
        f32x4 acc[4];
        #pragma unroll
        for (int nt = 0; nt < 4; ++nt) {
            float bv = bs[nt * 16 + c];
            acc[nt] = (f32x4){bv, bv, bv, bv};
            #pragma unroll
            for (int ks = 0; ks < 6; ++ks)
                acc[nt] = __builtin_amdgcn_mfma_f32_16x16x32_bf16(A[ks], Bf[ks * 4 + nt], acc[nt], 0, 0, 0);
        }
        #pragma unroll
        for (int nt = 0; nt < 4; ++nt)
            #pragma unroll
            for (int rg = 0; rg < 4; ++rg)
                ms[(q * 4 + rg) * 66 + nt * 16 + c] = silu_f(acc[nt][rg]);
        for (int r = 0; r < 16; ++r)
            h[(size_t)(row0 + r) * 64 + lane] = ms[r * 66 + lane];
        if (Wc_next) {
            // X_{l+1} = h_new @ Wc_bot_{l+1}; A frags from staged h_new (wave-synchronous)
            bf16x8 NA0, NA1;
            const float* np = &ms[c * 66 + q * 8];
            #pragma unroll
            for (int i = 0; i < 8; ++i) {
                NA0[i] = (short)f2bf(np[i]);
                NA1[i] = (short)f2bf(np[32 + i]);
            }
            f32x4 xacc[4];
            #pragma unroll
            for (int nt = 0; nt < 4; ++nt) {
                xacc[nt] = (f32x4){0.f, 0.f, 0.f, 0.f};
                bf16x8 B0 = *(const bf16x8*)&Bp2[(nt * 64 + lane) * 8];
                xacc[nt] = __builtin_amdgcn_mfma_f32_16x16x32_bf16(NA0, B0, xacc[nt], 0, 0, 0);
                bf16x8 B1 = *(const bf16x8*)&Bp2[((4 + nt) * 64 + lane) * 8];
                xacc[nt] = __builtin_amdgcn_mfma_f32_16x16x32_bf16(NA1, B1, xacc[nt], 0, 0, 0);
            }
            #pragma unroll
            for (int nt = 0; nt < 4; ++nt)
                #pragma unroll
                for (int rg = 0; rg < 4; ++rg)
                    ms[(q * 4 + rg) * 66 + nt * 16 + c] = xacc[nt][rg];
            for (int r = 0; r < 16; ++r)
                Xout[(size_t)(row0 + r) * 64 + lane] = f2bf(ms[r * 66 + lane]);
        }
    }
}

// ---------------------------------------------------------------- readout stage 1 (fp32 VALU -> bf16 hid)
__global__ __launch_bounds__(256) void var_hidden_kernel(
    const float* __restrict__ h_var, const float* __restrict__ W,
    const float* __restrict__ b, int colofs, unsigned short* __restrict__ hid) {
    __shared__ float Ws[128 * 64];
    __shared__ float bs[64];
    __shared__ float rs[16 * 128];
    int t = threadIdx.x;
    for (int i = t; i < 128 * 64; i += 256) {
        int k = i >> 6, j = i & 63;
        Ws[i] = W[k * 128 + colofs + j];
    }
    if (t < 64) bs[t] = b[colofs + t];
    __syncthreads();
    const int ntiles = NVAR / 16;
    int w = t >> 6, j = t & 63;
    for (int tile = blockIdx.x; tile < ntiles; tile += gridDim.x) {
        int row0 = tile * 16;
        for (int i = t; i < 2048; i += 256) rs[i] = h_var[(size_t)row0 * 128 + i];
        __syncthreads();
        float acc0 = bs[j], acc1 = bs[j], acc2 = bs[j], acc3 = bs[j];
        const float* r0 = &rs[(w * 4 + 0) * 128];
        const float* r1 = &rs[(w * 4 + 1) * 128];
        const float* r2 = &rs[(w * 4 + 2) * 128];
        const float* r3 = &rs[(w * 4 + 3) * 128];
        #pragma unroll 4
        for (int k = 0; k < 128; k += 4) {
            float w0 = Ws[k * 64 + j], w1v = Ws[(k + 1) * 64 + j];
            float w2v = Ws[(k + 2) * 64 + j], w3v = Ws[(k + 3) * 64 + j];
            float4 a;
            a = *(const float4*)(r0 + k); acc0 += a.x * w0 + a.y * w1v + a.z * w2v + a.w * w3v;
            a = *(const float4*)(r1 + k); acc1 += a.x * w0 + a.y * w1v + a.z * w2v + a.w * w3v;
            a = *(const float4*)(r2 + k); acc2 += a.x * w0 + a.y * w1v + a.z * w2v + a.w * w3v;
            a = *(const float4*)(r3 + k); acc3 += a.x * w0 + a.y * w1v + a.z * w2v + a.w * w3v;
        }
        int row = row0 + w * 4;
        hid[(size_t)(row + 0) * 128 + colofs + j] = f2bf(silu_f(acc0));
        hid[(size_t)(row + 1) * 128 + colofs + j] = f2bf(silu_f(acc1));
        hid[(size_t)(row + 2) * 128 + colofs + j] = f2bf(silu_f(acc2));
        hid[(size_t)(row + 3) * 128 + colofs + j] = f2bf(silu_f(acc3));
        __syncthreads();
    }
}

// ---------------------------------------------------------------- readout stage 2
__global__ __launch_bounds__(256) void out2_kernel(
    const unsigned short* __restrict__ hid, const float* __restrict__ w2,
    const float* __restrict__ b2, float* __restrict__ out) {
    int nw = (gridDim.x * blockDim.x) >> 6;
    int wid = (blockIdx.x * blockDim.x + threadIdx.x) >> 6;
    int lane = threadIdx.x & 63;
    float w00 = w2[lane * 2 + 0], w01 = w2[lane * 2 + 1];
    float w10 = w2[(lane + 64) * 2 + 0], w11 = w2[(lane + 64) * 2 + 1];
    for (int row = wid; row < NVAR; row += nw) {
        float h0 = bf2f(hid[(size_t)row * 128 + lane]);
        float h1 = bf2f(hid[(size_t)row * 128 + 64 + lane]);
        float p0 = h0 * w00 + h1 * w10;
        float p1 = h0 * w01 + h1 * w11;
        #pragma unroll
        for (int off = 32; off > 0; off >>= 1) {
            p0 += __shfl_down(p0, off);
            p1 += __shfl_down(p1, off);
        }
        if (lane == 0) {
            out[(size_t)row * 2 + 0] = p0 + b2[0];
            out[(size_t)row * 2 + 1] = p1 + b2[1];
        }
    }
}

// ---------------------------------------------------------------- launch
extern "C" void kernel_launch(void* const* d_in, const int* in_sizes, int n_in,
                              void* d_out, int out_size, void* d_ws, size_t ws_size,
                              hipStream_t stream) {
    const float* x_lit  = (const float*)d_in[0];
    const float* x_cls  = (const float*)d_in[1];
    const int* edge_lit = (const int*)d_in[2];
    const int* edge_cls = (const int*)d_in[3];
    const float* enc_w1 = (const float*)d_in[4];
    const float* enc_b1 = (const float*)d_in[5];
    const float* enc_w2 = (const float*)d_in[6];
    const float* enc_b2 = (const float*)d_in[7];
    const float* Wc     = (const float*)d_in[8];    // [4][128][64]
    const float* bc     = (const float*)d_in[9];
    const float* Wl     = (const float*)d_in[10];   // [4][192][64]
    const float* bl     = (const float*)d_in[11];
    const float* out_w1 = (const float*)d_in[12];   // [128][128]
    const float* out_b1 = (const float*)d_in[13];
    const float* out_w2 = (const float*)d_in[14];   // [128][2]
    const float* out_b2 = (const float*)d_in[15];
    float* y = (float*)d_out;

    // ---- workspace carve (~211 MB) ----
    const size_t SZ_HLIT = (size_t)N_LIT * 64;
    const size_t SZ_HCLS = (size_t)N_CLS * 64;
    char* p = (char*)d_ws;
    auto take = [&](size_t bytes) -> char* {
        char* r = p; p += (bytes + 255) & ~(size_t)255; return r;
    };
    float*          h_lit      = (float*)take(SZ_HLIT * 4);
    unsigned short* h_cls      = (unsigned short*)take(SZ_HCLS * 2);
    unsigned short* X          = (unsigned short*)take(SZ_HLIT * 2);
    float*          inv_cls    = (float*)take((size_t)N_CLS * 4);
    float*          inv_lit    = (float*)take((size_t)N_LIT * 4);
    int*            row_ptr_cls= (int*)take((size_t)(N_CLS + 1) * 4);
    int*            row_ptr_lit= (int*)take((size_t)(N_LIT + 1) * 4);
    int*            cur_cls    = (int*)take((size_t)(N_CLS + N_LIT) * 4);
    int*            cur_lit    = cur_cls + N_CLS;
    int*            lit_by_cls = (int*)take((size_t)NEDGE * 4);
    int*            cls_by_lit = (int*)take((size_t)NEDGE * 4);
    int*            partA      = (int*)take(1024 * 4);
    int*            partB      = (int*)take(1024 * 4);
    size_t need = (size_t)(p - (char*)d_ws);

    dim3 B(256);

    if (ws_size < need) {
        float mb = (float)((double)ws_size / (1024.0 * 1024.0));
        diag_kernel<<<256, B, 0, stream>>>(y, out_size, mb);
        return;
    }

    // ---- CSR build (direct R5 scheme) ----
    zero_int4_kernel<<<512, B, 0, stream>>>((int4*)cur_cls, (long)(N_CLS + N_LIT) / 4);
    deg_kernel<<<2048, B, 0, stream>>>(edge_lit, edge_cls, cur_lit, cur_cls);
    inv_deg_kernel<<<(N_CLS + 255) / 256, B, 0, stream>>>(cur_cls, inv_cls, N_CLS);
    inv_deg_kernel<<<(N_LIT + 255) / 256, B, 0, stream>>>(cur_lit, inv_lit, N_LIT);
    int nbc = (N_CLS + 1023) / 1024;
    int nbl = (N_LIT + 1023) / 1024;
    scan_partial_kernel<<<nbc, B, 0, stream>>>(cur_cls, N_CLS, partA);
    scan_root_kernel<<<1, 1024, 0, stream>>>(partA, nbc);
    scan_final_kernel<<<nbc, B, 0, stream>>>(cur_cls, partA, row_ptr_cls, N_CLS);
    scan_partial_kernel<<<nbl, B, 0, stream>>>(cur_lit, N_LIT, partB);
    scan_root_kernel<<<1, 1024, 0, stream>>>(partB, nbl);
    scan_final_kernel<<<nbl, B, 0, stream>>>(cur_lit, partB, row_ptr_lit, N_LIT);
    tail_kernel<<<1, 64, 0, stream>>>(row_ptr_cls, row_ptr_lit);
    copy_int_kernel<<<1024, B, 0, stream>>>(cur_cls, row_ptr_cls, N_CLS);
    copy_int_kernel<<<512, B, 0, stream>>>(cur_lit, row_ptr_lit, N_LIT);
    fill_csr_kernel<<<2048, B, 0, stream>>>(edge_lit, edge_cls, cur_cls, cur_lit,
                                            lit_by_cls, cls_by_lit);

    // ---- encoder ----
    encoder_kernel<<<2048, B, 0, stream>>>(x_lit, x_cls, enc_w1, enc_b1, enc_w2, enc_b2,
                                           h_lit, h_cls);

    // layer-0 X; layers 1..3 get X from lit_update's fused epilogue
    gemmX_kernel<<<1024, B, 0, stream>>>(h_lit, Wc + 64 * 64, X);

    for (int l = 0; l < 4; ++l) {
        const float* Wl_l = Wl + (size_t)l * 192 * 64;
        const float* Wc_next = (l < 3) ? (Wc + (size_t)(l + 1) * 128 * 64 + 64 * 64) : nullptr;
        cls_update_kernel<<<2048, B, 0, stream>>>(h_cls, X, row_ptr_cls, lit_by_cls,
                                                  inv_cls, Wc + (size_t)l * 128 * 64,
                                                  bc + l * 64, l > 0);
        gather_lit_kernel<<<4096, B, 0, stream>>>(h_cls, row_ptr_lit, cls_by_lit,
                                                  inv_lit, X);
        lit_update_kernel<<<1024, B, 0, stream>>>(h_lit, X, Wl_l, bl + l * 64,
                                                  Wc_next, X);
    }

    // ---- readout ----
    var_hidden_kernel<<<4096, B, 0, stream>>>(h_lit, out_w1, out_b1, 0, X);
    var_hidden_kernel<<<4096, B, 0, stream>>>(h_lit, out_w1, out_b1, 64, X);
    out2_kernel<<<2048, B, 0, stream>>>(X, out_w2, out_b2, y);
}

// Round 8
// 2114.624 us; speedup vs baseline: 1.9056x; 1.2271x over previous
//
#include <hip/hip_runtime.h>
#include <math.h>

#define N_LIT 200000
#define N_CLS 800000
#define NEDGE 2400000
#define NVAR  (N_LIT / 2)

// CSR radix-partition parameters: 200 chunks x 12000 edges = NEDGE exactly; 196 buckets
#define NBLK_S 200
#define CHUNK  12000
#define NBKT   196

typedef __attribute__((ext_vector_type(8))) short bf16x8;
typedef __attribute__((ext_vector_type(4))) float f32x4;

__device__ __forceinline__ float silu_f(float x) { return x / (1.0f + expf(-x)); }

__device__ __forceinline__ float bf2f(unsigned short u) {
    unsigned int x = ((unsigned int)u) << 16;
    return __uint_as_float(x);
}
__device__ __forceinline__ unsigned short f2bf(float f) {
    unsigned int x = __float_as_uint(f);
    unsigned int r = (x + 0x7fffu + ((x >> 16) & 1u)) >> 16;
    return (unsigned short)r;
}

// ---------------------------------------------------------------- diagnostics
__global__ void diag_kernel(float* __restrict__ out, int n, float val) {
    int i = blockIdx.x * blockDim.x + threadIdx.x;
    int stride = gridDim.x * blockDim.x;
    for (; i < n; i += stride) out[i] = val;
}

// ---------------------------------------------------------------- CSR build: radix partition
// Phase A: per-(chunk,bucket) histogram. Chunk = contiguous edge range (write-combining!)
__global__ __launch_bounds__(256) void csr_hist_kernel(
    const int* __restrict__ key, int shift, int* __restrict__ bh) {
    __shared__ int h[NBKT];
    int b = blockIdx.x, t = threadIdx.x;
    for (int i = t; i < NBKT; i += 256) h[i] = 0;
    __syncthreads();
    int s = b * CHUNK;
    for (int i = t; i < CHUNK; i += 256) atomicAdd(&h[key[s + i] >> shift], 1);
    __syncthreads();
    for (int i = t; i < NBKT; i += 256) bh[b * NBKT + i] = h[i];
}

// Phase B: per-(chunk,bucket) output cursors + bucket bases (1 block)
__global__ __launch_bounds__(256) void csr_offsets_kernel(
    const int* __restrict__ bh, int* __restrict__ off, int* __restrict__ bktbase) {
    __shared__ int sc[256];
    int t = threadIdx.x;
    int sum = 0;
    if (t < NBKT)
        for (int b = 0; b < NBLK_S; ++b) sum += bh[b * NBKT + t];
    int v = sum;
    sc[t] = v; __syncthreads();
    for (int o = 1; o < 256; o <<= 1) {
        int add = (t >= o) ? sc[t - o] : 0; __syncthreads();
        sc[t] += add; __syncthreads();
    }
    int base = sc[t] - v;   // exclusive
    if (t < NBKT) {
        bktbase[t] = base;
        int run = base;
        for (int b = 0; b < NBLK_S; ++b) { off[b * NBKT + t] = run; run += bh[b * NBKT + t]; }
    }
    if (t == 0) bktbase[NBKT] = NEDGE;
}

// Phase C: scatter pairs into bucket-partitioned tmp; per-block runs are contiguous
__global__ __launch_bounds__(256) void csr_scatter_kernel(
    const int* __restrict__ key, const int* __restrict__ val, int shift,
    const int* __restrict__ off, int2* __restrict__ tmp) {
    __shared__ int cur[NBKT];
    int b = blockIdx.x, t = threadIdx.x;
    for (int i = t; i < NBKT; i += 256) cur[i] = off[b * NBKT + i];
    __syncthreads();
    int s = b * CHUNK;
    for (int i = t; i < CHUNK; i += 256) {
        int k = key[s + i], v = val[s + i];
        int p = atomicAdd(&cur[k >> shift], 1);
        tmp[p] = make_int2(k, v);
    }
}

// Phase D: per-bucket CSR finalize — LDS row hist + scan -> row_ptr, inv_deg, adjacency.
// Adjacency writes land in a ~49 KB L2-resident window -> dense write-back.
__global__ __launch_bounds__(256) void csr_build_kernel(
    const int2* __restrict__ tmp, const int* __restrict__ bktbase, int rows_per_bkt,
    int nrows, int* __restrict__ row_ptr, float* __restrict__ inv, int* __restrict__ adj) {
    __shared__ int hist[4096];
    __shared__ int part[256];
    int k = blockIdx.x, t = threadIdx.x;
    int rowbase = k * rows_per_bkt;
    for (int i = t; i < rows_per_bkt; i += 256) hist[i] = 0;
    __syncthreads();
    int e0 = bktbase[k], e1 = bktbase[k + 1];
    for (int e = e0 + t; e < e1; e += 256) atomicAdd(&hist[tmp[e].x - rowbase], 1);
    __syncthreads();
    // block exclusive scan over rows_per_bkt entries
    int per = rows_per_bkt >> 8;   // 16 (cls) or 4 (lit)
    int base_i = t * per;
    int vals[16];
    int s = 0;
    for (int i = 0; i < per; ++i) { vals[i] = hist[base_i + i]; s += vals[i]; }
    int v = s;
    part[t] = v; __syncthreads();
    for (int o = 1; o < 256; o <<= 1) {
        int add = (t >= o) ? part[t - o] : 0; __syncthreads();
        part[t] += add; __syncthreads();
    }
    int run = part[t] - v;
    for (int i = 0; i < per; ++i) { hist[base_i + i] = run; run += vals[i]; }
    __syncthreads();
    // row_ptr + inv_deg (deg = next_excl - excl)
    for (int i = t; i < rows_per_bkt; i += 256) {
        int row = rowbase + i;
        if (row < nrows) {
            int ex = hist[i];
            int nx = (i + 1 < rows_per_bkt) ? hist[i + 1] : (e1 - e0);
            row_ptr[row] = e0 + ex;
            int d = nx - ex;
            inv[row] = 1.0f / (float)(d > 0 ? d : 1);
        }
    }
    __syncthreads();
    // pass 2: place edges via LDS cursors
    for (int e = e0 + t; e < e1; e += 256) {
        int2 pr = tmp[e];
        int pos = atomicAdd(&hist[pr.x - rowbase], 1);
        adj[e0 + pos] = pr.y;
    }
}

__global__ void tail_kernel(int* __restrict__ rp_cls, int* __restrict__ rp_lit) {
    if (blockIdx.x == 0 && threadIdx.x == 0) {
        rp_cls[N_CLS] = NEDGE;
        rp_lit[N_LIT] = NEDGE;
    }
}

// ---------------------------------------------------------------- encoder (MFMA 2nd GEMM)
__global__ __launch_bounds__(256, 4) void encoder_kernel(
    const float* __restrict__ x_lit, const float* __restrict__ x_cls,
    const float* __restrict__ w1, const float* __restrict__ b1,
    const float* __restrict__ w2, const float* __restrict__ b2,
    float* __restrict__ h_lit, unsigned short* __restrict__ h_cls) {
    __shared__ float w1s[4 * 64];
    __shared__ float b1s[64], b2s[64];
    __shared__ __align__(16) unsigned short Bp[8 * 64 * 8];
    __shared__ float xt[4][64];
    __shared__ float hs[4][16 * 68];
    int t = threadIdx.x;
    w1s[t] = w1[t];
    if (t < 64) { b1s[t] = b1[t]; b2s[t] = b2[t]; }
    for (int idx = t; idx < 8 * 64 * 8; idx += 256) {
        int i = idx & 7, ln = (idx >> 3) & 63, fid = idx >> 9;
        int ks = fid >> 2, nt = fid & 3;
        Bp[idx] = f2bf(w2[(ks * 32 + ((ln >> 4) << 3) + i) * 64 + nt * 16 + (ln & 15)]);
    }
    __syncthreads();
    int w = t >> 6, lane = t & 63;
    int c = lane & 15, q = lane >> 4;
    bf16x8 Bf[8];
    #pragma unroll
    for (int f = 0; f < 8; ++f) Bf[f] = *(const bf16x8*)&Bp[(f * 64 + lane) * 8];
    float* hw = hs[w];
    int nwaves = gridDim.x * 4;
    int wid = blockIdx.x * 4 + w;
    const int ntiles = (N_LIT + N_CLS) / 16;
    for (int tile = wid; tile < ntiles; tile += nwaves) {
        int row0 = tile * 16;
        const float* xsrc = (row0 < N_LIT) ? x_lit + (size_t)row0 * 4
                                           : x_cls + (size_t)(row0 - N_LIT) * 4;
        xt[w][lane] = xsrc[lane];
        for (int r = 0; r < 16; ++r) {
            float pre = b1s[lane];
            #pragma unroll
            for (int k = 0; k < 4; ++k) pre += xt[w][r * 4 + k] * w1s[k * 64 + lane];
            hw[r * 68 + lane] = silu_f(pre);
        }
        bf16x8 A0, A1;
        const float* ap = &hw[c * 68 + q * 8];
        #pragma unroll
        for (int i = 0; i < 8; ++i) {
            A0[i] = (short)f2bf(ap[i]);
            A1[i] = (short)f2bf(ap[32 + i]);
        }
        f32x4 acc[4];
        #pragma unroll
        for (int nt = 0; nt < 4; ++nt) {
            float bv = b2s[nt * 16 + c];
            acc[nt] = (f32x4){bv, bv, bv, bv};
            acc[nt] = __builtin_amdgcn_mfma_f32_16x16x32_bf16(A0, Bf[nt], acc[nt], 0, 0, 0);
            acc[nt] = __builtin_amdgcn_mfma_f32_16x16x32_bf16(A1, Bf[4 + nt], acc[nt], 0, 0, 0);
        }
        #pragma unroll
        for (int nt = 0; nt < 4; ++nt)
            #pragma unroll
            for (int rg = 0; rg < 4; ++rg)
                hw[(q * 4 + rg) * 68 + nt * 16 + c] = acc[nt][rg];
        if (row0 < N_LIT) {
            for (int r = 0; r < 16; ++r)
                h_lit[(size_t)(row0 + r) * 64 + lane] = hw[r * 68 + lane];
        } else {
            for (int r = 0; r < 16; ++r)
                h_cls[(size_t)(row0 + r - N_LIT) * 64 + lane] = f2bf(hw[r * 68 + lane]);
        }
    }
}

// ---------------------------------------------------------------- X = h_lit @ Wc_bot (MFMA) — layer 0 only
__global__ __launch_bounds__(256, 4) void gemmX_kernel(
    const float* __restrict__ in, const float* __restrict__ W,
    unsigned short* __restrict__ out) {
    __shared__ __align__(16) unsigned short Bp[8 * 64 * 8];
    __shared__ float stage[4][16 * 66];
    int t = threadIdx.x;
    for (int idx = t; idx < 8 * 64 * 8; idx += 256) {
        int i = idx & 7, ln = (idx >> 3) & 63, fid = idx >> 9;
        int ks = fid >> 2, nt = fid & 3;
        Bp[idx] = f2bf(W[(ks * 32 + ((ln >> 4) << 3) + i) * 64 + nt * 16 + (ln & 15)]);
    }
    __syncthreads();
    int w = t >> 6, lane = t & 63;
    int c = lane & 15, q = lane >> 4;
    bf16x8 Bf[8];
    #pragma unroll
    for (int f = 0; f < 8; ++f) Bf[f] = *(const bf16x8*)&Bp[(f * 64 + lane) * 8];
    float* ms = stage[w];
    int nwaves = gridDim.x * 4;
    int wid = blockIdx.x * 4 + w;
    for (int tile = wid; tile < N_LIT / 16; tile += nwaves) {
        int row0 = tile * 16;
        const float* ap = in + (size_t)(row0 + c) * 64 + q * 8;
        bf16x8 A0, A1;
        #pragma unroll
        for (int i = 0; i < 8; ++i) {
            A0[i] = (short)f2bf(ap[i]);
            A1[i] = (short)f2bf(ap[32 + i]);
        }
        f32x4 acc[4];
        #pragma unroll
        for (int nt = 0; nt < 4; ++nt) {
            acc[nt] = (f32x4){0.f, 0.f, 0.f, 0.f};
            acc[nt] = __builtin_amdgcn_mfma_f32_16x16x32_bf16(A0, Bf[nt], acc[nt], 0, 0, 0);
            acc[nt] = __builtin_amdgcn_mfma_f32_16x16x32_bf16(A1, Bf[4 + nt], acc[nt], 0, 0, 0);
        }
        #pragma unroll
        for (int nt = 0; nt < 4; ++nt)
            #pragma unroll
            for (int rg = 0; rg < 4; ++rg)
                ms[(q * 4 + rg) * 66 + nt * 16 + c] = acc[nt][rg];
        for (int r = 0; r < 16; ++r)
            out[(size_t)(row0 + r) * 64 + lane] = f2bf(ms[r * 66 + lane]);
    }
}

// ---------------------------------------------------------------- clause update (MFMA + flattened-tile gather)
__global__ __launch_bounds__(256, 5) void cls_update_kernel(
    unsigned short* __restrict__ h_cls, const unsigned short* __restrict__ X,
    const int* __restrict__ rp, const int* __restrict__ lits,
    const float* __restrict__ inv_deg, const float* __restrict__ W,
    const float* __restrict__ b, int silu_in) {
    __shared__ __align__(16) unsigned short Bp[8 * 64 * 8];
    __shared__ float bs[64];
    __shared__ float stage[4][16 * 66];
    __shared__ int rps[4][17];
    __shared__ int lse[4][128];
    int t = threadIdx.x;
    for (int idx = t; idx < 8 * 64 * 8; idx += 256) {
        int i = idx & 7, ln = (idx >> 3) & 63, fid = idx >> 9;
        int ks = fid >> 2, nt = fid & 3;
        Bp[idx] = f2bf(W[(ks * 32 + ((ln >> 4) << 3) + i) * 64 + nt * 16 + (ln & 15)]);
    }
    if (t < 64) bs[t] = b[t];
    __syncthreads();
    int w = t >> 6, lane = t & 63;
    int c = lane & 15, q = lane >> 4;
    bf16x8 Bf[8];
    #pragma unroll
    for (int f = 0; f < 8; ++f) Bf[f] = *(const bf16x8*)&Bp[(f * 64 + lane) * 8];
    float* ms = stage[w];
    int* rpw = rps[w];
    int* lsw = lse[w];
    int nwaves = gridDim.x * 4;
    int wid = blockIdx.x * 4 + w;
    for (int tile = wid; tile < N_CLS / 16; tile += nwaves) {
        int row0 = tile * 16;
        const unsigned short* ap = h_cls + (size_t)(row0 + c) * 64 + q * 8;
        bf16x8 A0 = *(const bf16x8*)(ap);
        bf16x8 A1 = *(const bf16x8*)(ap + 32);
        if (silu_in) {
            #pragma unroll
            for (int i = 0; i < 8; ++i) {
                A0[i] = (short)f2bf(silu_f(bf2f((unsigned short)A0[i])));
                A1[i] = (short)f2bf(silu_f(bf2f((unsigned short)A1[i])));
            }
        }
        f32x4 acc[4];
        #pragma unroll
        for (int nt = 0; nt < 4; ++nt) {
            float bv = bs[nt * 16 + c];
            acc[nt] = (f32x4){bv, bv, bv, bv};
            acc[nt] = __builtin_amdgcn_mfma_f32_16x16x32_bf16(A0, Bf[nt], acc[nt], 0, 0, 0);
            acc[nt] = __builtin_amdgcn_mfma_f32_16x16x32_bf16(A1, Bf[4 + nt], acc[nt], 0, 0, 0);
        }
        #pragma unroll
        for (int r = 0; r < 16; ++r) ms[r * 66 + lane] = 0.f;
        if (lane < 17) rpw[lane] = rp[row0 + lane];
        int E0 = rpw[0], E1 = rpw[16];
        int r = 0, endr = rpw[1];
        for (int base = E0; base < E1; base += 128) {
            int n = E1 - base; if (n > 128) n = 128;
            for (int i = lane; i < n; i += 64) lsw[i] = lits[base + i];
            int i = 0;
            for (; i + 7 < n; i += 8) {
                float v[8];
                #pragma unroll
                for (int k = 0; k < 8; ++k)
                    v[k] = bf2f(X[(size_t)lsw[i + k] * 64 + lane]);
                #pragma unroll
                for (int k = 0; k < 8; ++k) {
                    int g = base + i + k;
                    while (g >= endr) { ++r; endr = rpw[r + 1]; }
                    ms[r * 66 + lane] += v[k];
                }
            }
            for (; i < n; ++i) {
                float v0 = bf2f(X[(size_t)lsw[i] * 64 + lane]);
                int g = base + i;
                while (g >= endr) { ++r; endr = rpw[r + 1]; }
                ms[r * 66 + lane] += v0;
            }
        }
        for (int rr = 0; rr < 16; ++rr)
            ms[rr * 66 + lane] *= inv_deg[row0 + rr];
        #pragma unroll
        for (int nt = 0; nt < 4; ++nt)
            #pragma unroll
            for (int rg = 0; rg < 4; ++rg)
                ms[(q * 4 + rg) * 66 + nt * 16 + c] += acc[nt][rg];
        for (int rr = 0; rr < 16; ++rr)
            h_cls[(size_t)(row0 + rr) * 64 + lane] = f2bf(ms[rr * 66 + lane]);
    }
}

// ---------------------------------------------------------------- lit-side gather (standalone, 4-way MLP)
__global__ __launch_bounds__(256, 8) void gather_lit_kernel(
    const unsigned short* __restrict__ h_cls, const int* __restrict__ rp,
    const int* __restrict__ clss, const float* __restrict__ inv_deg,
    unsigned short* __restrict__ m_out) {
    int nw = (gridDim.x * blockDim.x) >> 6;
    int wid = (blockIdx.x * blockDim.x + threadIdx.x) >> 6;
    int lane = threadIdx.x & 63;
    for (int row = wid; row < N_LIT; row += nw) {
        int e0 = rp[row], e1 = rp[row + 1];
        float g0 = 0.f, g1 = 0.f, g2 = 0.f, g3 = 0.f;
        int e = e0;
        for (; e + 3 < e1; e += 4) {
            int c0 = clss[e], c1 = clss[e + 1], c2 = clss[e + 2], c3 = clss[e + 3];
            g0 += silu_f(bf2f(h_cls[(size_t)c0 * 64 + lane]));
            g1 += silu_f(bf2f(h_cls[(size_t)c1 * 64 + lane]));
            g2 += silu_f(bf2f(h_cls[(size_t)c2 * 64 + lane]));
            g3 += silu_f(bf2f(h_cls[(size_t)c3 * 64 + lane]));
        }
        for (; e < e1; ++e)
            g0 += silu_f(bf2f(h_cls[(size_t)clss[e] * 64 + lane]));
        m_out[(size_t)row * 64 + lane] = f2bf(((g0 + g1) + (g2 + g3)) * inv_deg[row]);
    }
}

// ---------------------------------------------------------------- literal update (MFMA, in-place fp32, + fused next-layer X)
__global__ __launch_bounds__(256, 3) void lit_update_kernel(
    float* __restrict__ h, const unsigned short* __restrict__ m,
    const float* __restrict__ W, const float* __restrict__ b,
    const float* __restrict__ Wc_next, unsigned short* __restrict__ Xout) {
    __shared__ __align__(16) unsigned short Bp[24 * 64 * 8];
    __shared__ __align__(16) unsigned short Bp2[8 * 64 * 8];
    __shared__ float bs[64];
    __shared__ float stage[4][16 * 66];
    int t = threadIdx.x;
    for (int idx = t; idx < 24 * 64 * 8; idx += 256) {
        int i = idx & 7, ln = (idx >> 3) & 63, fid = idx >> 9;
        int ks = fid >> 2, nt = fid & 3;
        Bp[idx] = f2bf(W[(ks * 32 + ((ln >> 4) << 3) + i) * 64 + nt * 16 + (ln & 15)]);
    }
    if (Wc_next) {
        for (int idx = t; idx < 8 * 64 * 8; idx += 256) {
            int i = idx & 7, ln = (idx >> 3) & 63, fid = idx >> 9;
            int ks = fid >> 2, nt = fid & 3;
            Bp2[idx] = f2bf(Wc_next[(ks * 32 + ((ln >> 4) << 3) + i) * 64 + nt * 16 + (ln & 15)]);
        }
    }
    if (t < 64) bs[t] = b[t];
    __syncthreads();
    int w = t >> 6, lane = t & 63;
    int c = lane & 15, q = lane >> 4;
    bf16x8 Bf[24];
    #pragma unroll
    for (int f = 0; f < 24; ++f) Bf[f] = *(const bf16x8*)&Bp[(f * 64 + lane) * 8];
    float* ms = stage[w];
    int nwaves = gridDim.x * 4;
    int wid = blockIdx.x * 4 + w;
    for (int tile = wid; tile < N_LIT / 16; tile += nwaves) {
        int row0 = tile * 16;
        bf16x8 A[6];
        const float* hp = h + (size_t)(row0 + c) * 64 + q * 8;
        const float* hf = h + (size_t)((row0 + c) ^ 1) * 64 + q * 8;
        const unsigned short* mp = m + (size_t)(row0 + c) * 64 + q * 8;
        #pragma unroll
        for (int i = 0; i < 8; ++i) {
            A[0][i] = (short)f2bf(hp[i]);
            A[1][i] = (short)f2bf(hp[32 + i]);
            A[4][i] = (short)f2bf(hf[i]);
            A[5][i] = (short)f2bf(hf[32 + i]);
        }
        A[2] = *(const bf16x8*)(mp);
        A[3] = *(const bf16x8*)(mp + 32);
        f32x4 acc[4];
        #pragma unroll
        for (int nt = 0; nt < 4; ++nt) {
            float bv = bs[nt * 16 + c];
            acc[nt] = (f32x4){bv, bv, bv, bv};
            #pragma unroll
            for (int ks = 0; ks < 6; ++ks)
                acc[nt] = __builtin_amdgcn_mfma_f32_16x16x32_bf16(A[ks], Bf[ks * 4 + nt], acc[nt], 0, 0, 0);
        }
        #pragma unroll
        for (int nt = 0; nt < 4; ++nt)
            #pragma unroll
            for (int rg = 0; rg < 4; ++rg)
                ms[(q * 4 + rg) * 66 + nt * 16 + c] = silu_f(acc[nt][rg]);
        for (int r = 0; r < 16; ++r)
            h[(size_t)(row0 + r) * 64 + lane] = ms[r * 66 + lane];
        if (Wc_next) {
            bf16x8 NA0, NA1;
            const float* np = &ms[c * 66 + q * 8];
            #pragma unroll
            for (int i = 0; i < 8; ++i) {
                NA0[i] = (short)f2bf(np[i]);
                NA1[i] = (short)f2bf(np[32 + i]);
            }
            f32x4 xacc[4];
            #pragma unroll
            for (int nt = 0; nt < 4; ++nt) {
                xacc[nt] = (f32x4){0.f, 0.f, 0.f, 0.f};
                bf16x8 B0 = *(const bf16x8*)&Bp2[(nt * 64 + lane) * 8];
                xacc[nt] = __builtin_amdgcn_mfma_f32_16x16x32_bf16(NA0, B0, xacc[nt], 0, 0, 0);
                bf16x8 B1 = *(const bf16x8*)&Bp2[((4 + nt) * 64 + lane) * 8];
                xacc[nt] = __builtin_amdgcn_mfma_f32_16x16x32_bf16(NA1, B1, xacc[nt], 0, 0, 0);
            }
            #pragma unroll
            for (int nt = 0; nt < 4; ++nt)
                #pragma unroll
                for (int rg = 0; rg < 4; ++rg)
                    ms[(q * 4 + rg) * 66 + nt * 16 + c] = xacc[nt][rg];
            for (int r = 0; r < 16; ++r)
                Xout[(size_t)(row0 + r) * 64 + lane] = f2bf(ms[r * 66 + lane]);
        }
    }
}

// ---------------------------------------------------------------- readout stage 1 (fp32 VALU -> bf16 hid)
__global__ __launch_bounds__(256) void var_hidden_kernel(
    const float* __restrict__ h_var, const float* __restrict__ W,
    const float* __restrict__ b, int colofs, unsigned short* __restrict__ hid) {
    __shared__ float Ws[128 * 64];
    __shared__ float bs[64];
    __shared__ float rs[16 * 128];
    int t = threadIdx.x;
    for (int i = t; i < 128 * 64; i += 256) {
        int k = i >> 6, j = i & 63;
        Ws[i] = W[k * 128 + colofs + j];
    }
    if (t < 64) bs[t] = b[colofs + t];
    __syncthreads();
    const int ntiles = NVAR / 16;
    int w = t >> 6, j = t & 63;
    for (int tile = blockIdx.x; tile < ntiles; tile += gridDim.x) {
        int row0 = tile * 16;
        for (int i = t; i < 2048; i += 256) rs[i] = h_var[(size_t)row0 * 128 + i];
        __syncthreads();
        float acc0 = bs[j], acc1 = bs[j], acc2 = bs[j], acc3 = bs[j];
        const float* r0 = &rs[(w * 4 + 0) * 128];
        const float* r1 = &rs[(w * 4 + 1) * 128];
        const float* r2 = &rs[(w * 4 + 2) * 128];
        const float* r3 = &rs[(w * 4 + 3) * 128];
        #pragma unroll 4
        for (int k = 0; k < 128; k += 4) {
            float w0 = Ws[k * 64 + j], w1v = Ws[(k + 1) * 64 + j];
            float w2v = Ws[(k + 2) * 64 + j], w3v = Ws[(k + 3) * 64 + j];
            float4 a;
            a = *(const float4*)(r0 + k); acc0 += a.x * w0 + a.y * w1v + a.z * w2v + a.w * w3v;
            a = *(const float4*)(r1 + k); acc1 += a.x * w0 + a.y * w1v + a.z * w2v + a.w * w3v;
            a = *(const float4*)(r2 + k); acc2 += a.x * w0 + a.y * w1v + a.z * w2v + a.w * w3v;
            a = *(const float4*)(r3 + k); acc3 += a.x * w0 + a.y * w1v + a.z * w2v + a.w * w3v;
        }
        int row = row0 + w * 4;
        hid[(size_t)(row + 0) * 128 + colofs + j] = f2bf(silu_f(acc0));
        hid[(size_t)(row + 1) * 128 + colofs + j] = f2bf(silu_f(acc1));
        hid[(size_t)(row + 2) * 128 + colofs + j] = f2bf(silu_f(acc2));
        hid[(size_t)(row + 3) * 128 + colofs + j] = f2bf(silu_f(acc3));
        __syncthreads();
    }
}

// ---------------------------------------------------------------- readout stage 2
__global__ __launch_bounds__(256) void out2_kernel(
    const unsigned short* __restrict__ hid, const float* __restrict__ w2,
    const float* __restrict__ b2, float* __restrict__ out) {
    int nw = (gridDim.x * blockDim.x) >> 6;
    int wid = (blockIdx.x * blockDim.x + threadIdx.x) >> 6;
    int lane = threadIdx.x & 63;
    float w00 = w2[lane * 2 + 0], w01 = w2[lane * 2 + 1];
    float w10 = w2[(lane + 64) * 2 + 0], w11 = w2[(lane + 64) * 2 + 1];
    for (int row = wid; row < NVAR; row += nw) {
        float h0 = bf2f(hid[(size_t)row * 128 + lane]);
        float h1 = bf2f(hid[(size_t)row * 128 + 64 + lane]);
        float p0 = h0 * w00 + h1 * w10;
        float p1 = h0 * w01 + h1 * w11;
        #pragma unroll
        for (int off = 32; off > 0; off >>= 1) {
            p0 += __shfl_down(p0, off);
            p1 += __shfl_down(p1, off);
        }
        if (lane == 0) {
            out[(size_t)row * 2 + 0] = p0 + b2[0];
            out[(size_t)row * 2 + 1] = p1 + b2[1];
        }
    }
}

// ---------------------------------------------------------------- launch
extern "C" void kernel_launch(void* const* d_in, const int* in_sizes, int n_in,
                              void* d_out, int out_size, void* d_ws, size_t ws_size,
                              hipStream_t stream) {
    const float* x_lit  = (const float*)d_in[0];
    const float* x_cls  = (const float*)d_in[1];
    const int* edge_lit = (const int*)d_in[2];
    const int* edge_cls = (const int*)d_in[3];
    const float* enc_w1 = (const float*)d_in[4];
    const float* enc_b1 = (const float*)d_in[5];
    const float* enc_w2 = (const float*)d_in[6];
    const float* enc_b2 = (const float*)d_in[7];
    const float* Wc     = (const float*)d_in[8];    // [4][128][64]
    const float* bc     = (const float*)d_in[9];
    const float* Wl     = (const float*)d_in[10];   // [4][192][64]
    const float* bl     = (const float*)d_in[11];
    const float* out_w1 = (const float*)d_in[12];   // [128][128]
    const float* out_b1 = (const float*)d_in[13];
    const float* out_w2 = (const float*)d_in[14];   // [128][2]
    const float* out_b2 = (const float*)d_in[15];
    float* y = (float*)d_out;

    // ---- workspace carve (~208 MB) ----
    const size_t SZ_HLIT = (size_t)N_LIT * 64;
    const size_t SZ_HCLS = (size_t)N_CLS * 64;
    char* p = (char*)d_ws;
    auto take = [&](size_t bytes) -> char* {
        char* r = p; p += (bytes + 255) & ~(size_t)255; return r;
    };
    float*          h_lit      = (float*)take(SZ_HLIT * 4);
    unsigned short* h_cls      = (unsigned short*)take(SZ_HCLS * 2);
    unsigned short* X          = (unsigned short*)take(SZ_HLIT * 2);
    float*          inv_cls    = (float*)take((size_t)N_CLS * 4);
    float*          inv_lit    = (float*)take((size_t)N_LIT * 4);
    int*            row_ptr_cls= (int*)take((size_t)(N_CLS + 1) * 4);
    int*            row_ptr_lit= (int*)take((size_t)(N_LIT + 1) * 4);
    int*            lit_by_cls = (int*)take((size_t)NEDGE * 4);
    int*            cls_by_lit = (int*)take((size_t)NEDGE * 4);
    int*            bh         = (int*)take((size_t)NBLK_S * NBKT * 4);
    int*            off        = (int*)take((size_t)NBLK_S * NBKT * 4);
    int*            bktbase    = (int*)take((size_t)(NBKT + 1) * 4);
    size_t need = (size_t)(p - (char*)d_ws);

    // pair buffer aliases h_lit (dead until encoder): 19.2 MB <= 51.2 MB
    int2* tmp_pairs = (int2*)h_lit;

    dim3 B(256);

    if (ws_size < need) {
        float mb = (float)((double)ws_size / (1024.0 * 1024.0));
        diag_kernel<<<256, B, 0, stream>>>(y, out_size, mb);
        return;
    }

    // ---- CSR build (radix partition, write-combining-friendly) ----
    // cls side: bucket = c >> 12 (196 buckets x 4096 rows)
    csr_hist_kernel<<<NBLK_S, B, 0, stream>>>(edge_cls, 12, bh);
    csr_offsets_kernel<<<1, B, 0, stream>>>(bh, off, bktbase);
    csr_scatter_kernel<<<NBLK_S, B, 0, stream>>>(edge_cls, edge_lit, 12, off, tmp_pairs);
    csr_build_kernel<<<NBKT, B, 0, stream>>>(tmp_pairs, bktbase, 4096, N_CLS,
                                             row_ptr_cls, inv_cls, lit_by_cls);
    // lit side: bucket = l >> 10 (196 buckets x 1024 rows)
    csr_hist_kernel<<<NBLK_S, B, 0, stream>>>(edge_lit, 10, bh);
    csr_offsets_kernel<<<1, B, 0, stream>>>(bh, off, bktbase);
    csr_scatter_kernel<<<NBLK_S, B, 0, stream>>>(edge_lit, edge_cls, 10, off, tmp_pairs);
    csr_build_kernel<<<NBKT, B, 0, stream>>>(tmp_pairs, bktbase, 1024, N_LIT,
                                             row_ptr_lit, inv_lit, cls_by_lit);
    tail_kernel<<<1, 64, 0, stream>>>(row_ptr_cls, row_ptr_lit);

    // ---- encoder (overwrites tmp_pairs alias region) ----
    encoder_kernel<<<2048, B, 0, stream>>>(x_lit, x_cls, enc_w1, enc_b1, enc_w2, enc_b2,
                                           h_lit, h_cls);

    // layer-0 X; layers 1..3 get X from lit_update's fused epilogue
    gemmX_kernel<<<1024, B, 0, stream>>>(h_lit, Wc + 64 * 64, X);

    for (int l = 0; l < 4; ++l) {
        const float* Wl_l = Wl + (size_t)l * 192 * 64;
        const float* Wc_next = (l < 3) ? (Wc + (size_t)(l + 1) * 128 * 64 + 64 * 64) : nullptr;
        cls_update_kernel<<<2048, B, 0, stream>>>(h_cls, X, row_ptr_cls, lit_by_cls,
                                                  inv_cls, Wc + (size_t)l * 128 * 64,
                                                  bc + l * 64, l > 0);
        gather_lit_kernel<<<4096, B, 0, stream>>>(h_cls, row_ptr_lit, cls_by_lit,
                                                  inv_lit, X);
        lit_update_kernel<<<1024, B, 0, stream>>>(h_lit, X, Wl_l, bl + l * 64,
                                                  Wc_next, X);
    }

    // ---- readout ----
    var_hidden_kernel<<<4096, B, 0, stream>>>(h_lit, out_w1, out_b1, 0, X);
    var_hidden_kernel<<<4096, B, 0, stream>>>(h_lit, out_w1, out_b1, 64, X);
    out2_kernel<<<2048, B, 0, stream>>>(X, out_w2, out_b2, y);
}

// Round 9
// 1986.976 us; speedup vs baseline: 2.0280x; 1.0642x over previous
//
#include <hip/hip_runtime.h>
#include <math.h>

#define N_LIT 200000
#define N_CLS 800000
#define NEDGE 2400000
#define NVAR  (N_LIT / 2)

// CSR radix-partition parameters: 200 chunks x 12000 edges = NEDGE exactly; 196 buckets
#define NBLK_S 200
#define CHUNK  12000
#define NBKT   196

typedef __attribute__((ext_vector_type(8))) short bf16x8;
typedef __attribute__((ext_vector_type(4))) float f32x4;

__device__ __forceinline__ float silu_f(float x) { return x / (1.0f + expf(-x)); }

__device__ __forceinline__ float bf2f(unsigned short u) {
    unsigned int x = ((unsigned int)u) << 16;
    return __uint_as_float(x);
}
__device__ __forceinline__ unsigned short f2bf(float f) {
    unsigned int x = __float_as_uint(f);
    unsigned int r = (x + 0x7fffu + ((x >> 16) & 1u)) >> 16;
    return (unsigned short)r;
}

// ---------------------------------------------------------------- diagnostics
__global__ void diag_kernel(float* __restrict__ out, int n, float val) {
    int i = blockIdx.x * blockDim.x + threadIdx.x;
    int stride = gridDim.x * blockDim.x;
    for (; i < n; i += stride) out[i] = val;
}

// ---------------------------------------------------------------- CSR build: radix partition
__global__ __launch_bounds__(256) void csr_hist_kernel(
    const int* __restrict__ key, int shift, int* __restrict__ bh) {
    __shared__ int h[NBKT];
    int b = blockIdx.x, t = threadIdx.x;
    for (int i = t; i < NBKT; i += 256) h[i] = 0;
    __syncthreads();
    int s = b * CHUNK;
    for (int i = t; i < CHUNK; i += 256) atomicAdd(&h[key[s + i] >> shift], 1);
    __syncthreads();
    for (int i = t; i < NBKT; i += 256) bh[b * NBKT + i] = h[i];
}

__global__ __launch_bounds__(256) void csr_offsets_kernel(
    const int* __restrict__ bh, int* __restrict__ off, int* __restrict__ bktbase) {
    __shared__ int sc[256];
    int t = threadIdx.x;
    int sum = 0;
    if (t < NBKT)
        for (int b = 0; b < NBLK_S; ++b) sum += bh[b * NBKT + t];
    int v = sum;
    sc[t] = v; __syncthreads();
    for (int o = 1; o < 256; o <<= 1) {
        int add = (t >= o) ? sc[t - o] : 0; __syncthreads();
        sc[t] += add; __syncthreads();
    }
    int base = sc[t] - v;   // exclusive
    if (t < NBKT) {
        bktbase[t] = base;
        int run = base;
        for (int b = 0; b < NBLK_S; ++b) { off[b * NBKT + t] = run; run += bh[b * NBKT + t]; }
    }
    if (t == 0) bktbase[NBKT] = NEDGE;
}

__global__ __launch_bounds__(256) void csr_scatter_kernel(
    const int* __restrict__ key, const int* __restrict__ val, int shift,
    const int* __restrict__ off, int2* __restrict__ tmp) {
    __shared__ int cur[NBKT];
    int b = blockIdx.x, t = threadIdx.x;
    for (int i = t; i < NBKT; i += 256) cur[i] = off[b * NBKT + i];
    __syncthreads();
    int s = b * CHUNK;
    for (int i = t; i < CHUNK; i += 256) {
        int k = key[s + i], v = val[s + i];
        int p = atomicAdd(&cur[k >> shift], 1);
        tmp[p] = make_int2(k, v);
    }
}

__global__ __launch_bounds__(256) void csr_build_kernel(
    const int2* __restrict__ tmp, const int* __restrict__ bktbase, int rows_per_bkt,
    int nrows, int* __restrict__ row_ptr, float* __restrict__ inv, int* __restrict__ adj) {
    __shared__ int hist[4096];
    __shared__ int part[256];
    int k = blockIdx.x, t = threadIdx.x;
    int rowbase = k * rows_per_bkt;
    for (int i = t; i < rows_per_bkt; i += 256) hist[i] = 0;
    __syncthreads();
    int e0 = bktbase[k], e1 = bktbase[k + 1];
    for (int e = e0 + t; e < e1; e += 256) atomicAdd(&hist[tmp[e].x - rowbase], 1);
    __syncthreads();
    int per = rows_per_bkt >> 8;   // 16 (cls) or 4 (lit)
    int base_i = t * per;
    int vals[16];
    int s = 0;
    for (int i = 0; i < per; ++i) { vals[i] = hist[base_i + i]; s += vals[i]; }
    int v = s;
    part[t] = v; __syncthreads();
    for (int o = 1; o < 256; o <<= 1) {
        int add = (t >= o) ? part[t - o] : 0; __syncthreads();
        part[t] += add; __syncthreads();
    }
    int run = part[t] - v;
    for (int i = 0; i < per; ++i) { hist[base_i + i] = run; run += vals[i]; }
    __syncthreads();
    for (int i = t; i < rows_per_bkt; i += 256) {
        int row = rowbase + i;
        if (row < nrows) {
            int ex = hist[i];
            int nx = (i + 1 < rows_per_bkt) ? hist[i + 1] : (e1 - e0);
            row_ptr[row] = e0 + ex;
            int d = nx - ex;
            inv[row] = 1.0f / (float)(d > 0 ? d : 1);
        }
    }
    __syncthreads();
    for (int e = e0 + t; e < e1; e += 256) {
        int2 pr = tmp[e];
        int pos = atomicAdd(&hist[pr.x - rowbase], 1);
        adj[e0 + pos] = pr.y;
    }
}

__global__ void tail_kernel(int* __restrict__ rp_cls, int* __restrict__ rp_lit) {
    if (blockIdx.x == 0 && threadIdx.x == 0) {
        rp_cls[N_CLS] = NEDGE;
        rp_lit[N_LIT] = NEDGE;
    }
}

// ---------------------------------------------------------------- encoder (MFMA 2nd GEMM)
__global__ __launch_bounds__(256, 4) void encoder_kernel(
    const float* __restrict__ x_lit, const float* __restrict__ x_cls,
    const float* __restrict__ w1, const float* __restrict__ b1,
    const float* __restrict__ w2, const float* __restrict__ b2,
    float* __restrict__ h_lit, unsigned short* __restrict__ h_cls) {
    __shared__ float w1s[4 * 64];
    __shared__ float b1s[64], b2s[64];
    __shared__ __align__(16) unsigned short Bp[8 * 64 * 8];
    __shared__ float xt[4][64];
    __shared__ float hs[4][16 * 68];
    int t = threadIdx.x;
    w1s[t] = w1[t];
    if (t < 64) { b1s[t] = b1[t]; b2s[t] = b2[t]; }
    for (int idx = t; idx < 8 * 64 * 8; idx += 256) {
        int i = idx & 7, ln = (idx >> 3) & 63, fid = idx >> 9;
        int ks = fid >> 2, nt = fid & 3;
        Bp[idx] = f2bf(w2[(ks * 32 + ((ln >> 4) << 3) + i) * 64 + nt * 16 + (ln & 15)]);
    }
    __syncthreads();
    int w = t >> 6, lane = t & 63;
    int c = lane & 15, q = lane >> 4;
    bf16x8 Bf[8];
    #pragma unroll
    for (int f = 0; f < 8; ++f) Bf[f] = *(const bf16x8*)&Bp[(f * 64 + lane) * 8];
    float* hw = hs[w];
    int nwaves = gridDim.x * 4;
    int wid = blockIdx.x * 4 + w;
    const int ntiles = (N_LIT + N_CLS) / 16;
    for (int tile = wid; tile < ntiles; tile += nwaves) {
        int row0 = tile * 16;
        const float* xsrc = (row0 < N_LIT) ? x_lit + (size_t)row0 * 4
                                           : x_cls + (size_t)(row0 - N_LIT) * 4;
        xt[w][lane] = xsrc[lane];
        for (int r = 0; r < 16; ++r) {
            float pre = b1s[lane];
            #pragma unroll
            for (int k = 0; k < 4; ++k) pre += xt[w][r * 4 + k] * w1s[k * 64 + lane];
            hw[r * 68 + lane] = silu_f(pre);
        }
        bf16x8 A0, A1;
        const float* ap = &hw[c * 68 + q * 8];
        #pragma unroll
        for (int i = 0; i < 8; ++i) {
            A0[i] = (short)f2bf(ap[i]);
            A1[i] = (short)f2bf(ap[32 + i]);
        }
        f32x4 acc[4];
        #pragma unroll
        for (int nt = 0; nt < 4; ++nt) {
            float bv = b2s[nt * 16 + c];
            acc[nt] = (f32x4){bv, bv, bv, bv};
            acc[nt] = __builtin_amdgcn_mfma_f32_16x16x32_bf16(A0, Bf[nt], acc[nt], 0, 0, 0);
            acc[nt] = __builtin_amdgcn_mfma_f32_16x16x32_bf16(A1, Bf[4 + nt], acc[nt], 0, 0, 0);
        }
        #pragma unroll
        for (int nt = 0; nt < 4; ++nt)
            #pragma unroll
            for (int rg = 0; rg < 4; ++rg)
                hw[(q * 4 + rg) * 68 + nt * 16 + c] = acc[nt][rg];
        if (row0 < N_LIT) {
            for (int r = 0; r < 16; ++r)
                h_lit[(size_t)(row0 + r) * 64 + lane] = hw[r * 68 + lane];
        } else {
            for (int r = 0; r < 16; ++r)
                h_cls[(size_t)(row0 + r - N_LIT) * 64 + lane] = f2bf(hw[r * 68 + lane]);
        }
    }
}

// ---------------------------------------------------------------- X = h_lit @ Wc_bot (MFMA) — layer 0 only
__global__ __launch_bounds__(256, 4) void gemmX_kernel(
    const float* __restrict__ in, const float* __restrict__ W,
    unsigned short* __restrict__ out) {
    __shared__ __align__(16) unsigned short Bp[8 * 64 * 8];
    __shared__ float stage[4][16 * 66];
    int t = threadIdx.x;
    for (int idx = t; idx < 8 * 64 * 8; idx += 256) {
        int i = idx & 7, ln = (idx >> 3) & 63, fid = idx >> 9;
        int ks = fid >> 2, nt = fid & 3;
        Bp[idx] = f2bf(W[(ks * 32 + ((ln >> 4) << 3) + i) * 64 + nt * 16 + (ln & 15)]);
    }
    __syncthreads();
    int w = t >> 6, lane = t & 63;
    int c = lane & 15, q = lane >> 4;
    bf16x8 Bf[8];
    #pragma unroll
    for (int f = 0; f < 8; ++f) Bf[f] = *(const bf16x8*)&Bp[(f * 64 + lane) * 8];
    float* ms = stage[w];
    int nwaves = gridDim.x * 4;
    int wid = blockIdx.x * 4 + w;
    for (int tile = wid; tile < N_LIT / 16; tile += nwaves) {
        int row0 = tile * 16;
        const float* ap = in + (size_t)(row0 + c) * 64 + q * 8;
        bf16x8 A0, A1;
        #pragma unroll
        for (int i = 0; i < 8; ++i) {
            A0[i] = (short)f2bf(ap[i]);
            A1[i] = (short)f2bf(ap[32 + i]);
        }
        f32x4 acc[4];
        #pragma unroll
        for (int nt = 0; nt < 4; ++nt) {
            acc[nt] = (f32x4){0.f, 0.f, 0.f, 0.f};
            acc[nt] = __builtin_amdgcn_mfma_f32_16x16x32_bf16(A0, Bf[nt], acc[nt], 0, 0, 0);
            acc[nt] = __builtin_amdgcn_mfma_f32_16x16x32_bf16(A1, Bf[4 + nt], acc[nt], 0, 0, 0);
        }
        #pragma unroll
        for (int nt = 0; nt < 4; ++nt)
            #pragma unroll
            for (int rg = 0; rg < 4; ++rg)
                ms[(q * 4 + rg) * 66 + nt * 16 + c] = acc[nt][rg];
        for (int r = 0; r < 16; ++r)
            out[(size_t)(row0 + r) * 64 + lane] = f2bf(ms[r * 66 + lane]);
    }
}

// ---------------------------------------------------------------- clause update (MFMA + monotone register-flush gather)
// h_cls[c] = (silu?(h_cls[c]) @ Wc_top + bc) + inv[c] * sum_e X[lit[e]]
// gather: tile's edges are one contiguous CSR range, rows monotone -> accumulate
// in a register, flush once per row (plain LDS write), inv folded into flush.
__global__ __launch_bounds__(256, 5) void cls_update_kernel(
    unsigned short* __restrict__ h_cls, const unsigned short* __restrict__ X,
    const int* __restrict__ rp, const int* __restrict__ lits,
    const float* __restrict__ inv_deg, const float* __restrict__ W,
    const float* __restrict__ b, int silu_in) {
    __shared__ __align__(16) unsigned short Bp[8 * 64 * 8];
    __shared__ float bs[64];
    __shared__ float stage[4][16 * 66];
    __shared__ int rps[4][17];
    __shared__ float invs[4][16];
    __shared__ int lse[4][128];
    int t = threadIdx.x;
    for (int idx = t; idx < 8 * 64 * 8; idx += 256) {
        int i = idx & 7, ln = (idx >> 3) & 63, fid = idx >> 9;
        int ks = fid >> 2, nt = fid & 3;
        Bp[idx] = f2bf(W[(ks * 32 + ((ln >> 4) << 3) + i) * 64 + nt * 16 + (ln & 15)]);
    }
    if (t < 64) bs[t] = b[t];
    __syncthreads();
    int w = t >> 6, lane = t & 63;
    int c = lane & 15, q = lane >> 4;
    bf16x8 Bf[8];
    #pragma unroll
    for (int f = 0; f < 8; ++f) Bf[f] = *(const bf16x8*)&Bp[(f * 64 + lane) * 8];
    float* ms = stage[w];
    int* rpw = rps[w];
    float* ivw = invs[w];
    int* lsw = lse[w];
    int nwaves = gridDim.x * 4;
    int wid = blockIdx.x * 4 + w;
    for (int tile = wid; tile < N_CLS / 16; tile += nwaves) {
        int row0 = tile * 16;
        const unsigned short* ap = h_cls + (size_t)(row0 + c) * 64 + q * 8;
        bf16x8 A0 = *(const bf16x8*)(ap);
        bf16x8 A1 = *(const bf16x8*)(ap + 32);
        if (silu_in) {
            #pragma unroll
            for (int i = 0; i < 8; ++i) {
                A0[i] = (short)f2bf(silu_f(bf2f((unsigned short)A0[i])));
                A1[i] = (short)f2bf(silu_f(bf2f((unsigned short)A1[i])));
            }
        }
        f32x4 acc[4];
        #pragma unroll
        for (int nt = 0; nt < 4; ++nt) {
            float bv = bs[nt * 16 + c];
            acc[nt] = (f32x4){bv, bv, bv, bv};
            acc[nt] = __builtin_amdgcn_mfma_f32_16x16x32_bf16(A0, Bf[nt], acc[nt], 0, 0, 0);
            acc[nt] = __builtin_amdgcn_mfma_f32_16x16x32_bf16(A1, Bf[4 + nt], acc[nt], 0, 0, 0);
        }
        #pragma unroll
        for (int r2 = 0; r2 < 16; ++r2) ms[r2 * 66 + lane] = 0.f;
        if (lane < 17) rpw[lane] = rp[row0 + lane];
        if (lane < 16) ivw[lane] = inv_deg[row0 + lane];
        int E0 = rpw[0], E1 = rpw[16];
        int r = 0, endr = rpw[1];
        float racc = 0.f;
        for (int base = E0; base < E1; base += 128) {
            int n = E1 - base; if (n > 128) n = 128;
            for (int i = lane; i < n; i += 64) lsw[i] = lits[base + i];
            int i = 0;
            for (; i + 7 < n; i += 8) {
                float v[8];
                #pragma unroll
                for (int k = 0; k < 8; ++k)
                    v[k] = bf2f(X[(size_t)lsw[i + k] * 64 + lane]);
                #pragma unroll
                for (int k = 0; k < 8; ++k) {
                    int g = base + i + k;
                    while (g >= endr) {
                        ms[r * 66 + lane] = racc * ivw[r];
                        racc = 0.f; ++r; endr = rpw[r + 1];
                    }
                    racc += v[k];
                }
            }
            for (; i < n; ++i) {
                float v0 = bf2f(X[(size_t)lsw[i] * 64 + lane]);
                int g = base + i;
                while (g >= endr) {
                    ms[r * 66 + lane] = racc * ivw[r];
                    racc = 0.f; ++r; endr = rpw[r + 1];
                }
                racc += v0;
            }
        }
        if (E1 > E0) ms[r * 66 + lane] = racc * ivw[r];
        racc = 0.f;
        #pragma unroll
        for (int nt = 0; nt < 4; ++nt)
            #pragma unroll
            for (int rg = 0; rg < 4; ++rg)
                ms[(q * 4 + rg) * 66 + nt * 16 + c] += acc[nt][rg];
        for (int rr = 0; rr < 16; ++rr)
            h_cls[(size_t)(row0 + rr) * 64 + lane] = f2bf(ms[rr * 66 + lane]);
    }
}

// ---------------------------------------------------------------- lit-side gather (standalone, 4-way MLP)
__global__ __launch_bounds__(256, 8) void gather_lit_kernel(
    const unsigned short* __restrict__ h_cls, const int* __restrict__ rp,
    const int* __restrict__ clss, const float* __restrict__ inv_deg,
    unsigned short* __restrict__ m_out) {
    int nw = (gridDim.x * blockDim.x) >> 6;
    int wid = (blockIdx.x * blockDim.x + threadIdx.x) >> 6;
    int lane = threadIdx.x & 63;
    for (int row = wid; row < N_LIT; row += nw) {
        int e0 = rp[row], e1 = rp[row + 1];
        float g0 = 0.f, g1 = 0.f, g2 = 0.f, g3 = 0.f;
        int e = e0;
        for (; e + 3 < e1; e += 4) {
            int c0 = clss[e], c1 = clss[e + 1], c2 = clss[e + 2], c3 = clss[e + 3];
            g0 += silu_f(bf2f(h_cls[(size_t)c0 * 64 + lane]));
            g1 += silu_f(bf2f(h_cls[(size_t)c1 * 64 + lane]));
            g2 += silu_f(bf2f(h_cls[(size_t)c2 * 64 + lane]));
            g3 += silu_f(bf2f(h_cls[(size_t)c3 * 64 + lane]));
        }
        for (; e < e1; ++e)
            g0 += silu_f(bf2f(h_cls[(size_t)clss[e] * 64 + lane]));
        m_out[(size_t)row * 64 + lane] = f2bf(((g0 + g1) + (g2 + g3)) * inv_deg[row]);
    }
}

// ---------------------------------------------------------------- literal update (MFMA, in-place fp32, + fused next-layer X)
__global__ __launch_bounds__(256, 3) void lit_update_kernel(
    float* __restrict__ h, const unsigned short* __restrict__ m,
    const float* __restrict__ W, const float* __restrict__ b,
    const float* __restrict__ Wc_next, unsigned short* __restrict__ Xout) {
    __shared__ __align__(16) unsigned short Bp[24 * 64 * 8];
    __shared__ __align__(16) unsigned short Bp2[8 * 64 * 8];
    __shared__ float bs[64];
    __shared__ float stage[4][16 * 66];
    int t = threadIdx.x;
    for (int idx = t; idx < 24 * 64 * 8; idx += 256) {
        int i = idx & 7, ln = (idx >> 3) & 63, fid = idx >> 9;
        int ks = fid >> 2, nt = fid & 3;
        Bp[idx] = f2bf(W[(ks * 32 + ((ln >> 4) << 3) + i) * 64 + nt * 16 + (ln & 15)]);
    }
    if (Wc_next) {
        for (int idx = t; idx < 8 * 64 * 8; idx += 256) {
            int i = idx & 7, ln = (idx >> 3) & 63, fid = idx >> 9;
            int ks = fid >> 2, nt = fid & 3;
            Bp2[idx] = f2bf(Wc_next[(ks * 32 + ((ln >> 4) << 3) + i) * 64 + nt * 16 + (ln & 15)]);
        }
    }
    if (t < 64) bs[t] = b[t];
    __syncthreads();
    int w = t >> 6, lane = t & 63;
    int c = lane & 15, q = lane >> 4;
    bf16x8 Bf[24];
    #pragma unroll
    for (int f = 0; f < 24; ++f) Bf[f] = *(const bf16x8*)&Bp[(f * 64 + lane) * 8];
    float* ms = stage[w];
    int nwaves = gridDim.x * 4;
    int wid = blockIdx.x * 4 + w;
    for (int tile = wid; tile < N_LIT / 16; tile += nwaves) {
        int row0 = tile * 16;
        bf16x8 A[6];
        const float* hp = h + (size_t)(row0 + c) * 64 + q * 8;
        const float* hf = h + (size_t)((row0 + c) ^ 1) * 64 + q * 8;
        const unsigned short* mp = m + (size_t)(row0 + c) * 64 + q * 8;
        #pragma unroll
        for (int i = 0; i < 8; ++i) {
            A[0][i] = (short)f2bf(hp[i]);
            A[1][i] = (short)f2bf(hp[32 + i]);
            A[4][i] = (short)f2bf(hf[i]);
            A[5][i] = (short)f2bf(hf[32 + i]);
        }
        A[2] = *(const bf16x8*)(mp);
        A[3] = *(const bf16x8*)(mp + 32);
        f32x4 acc[4];
        #pragma unroll
        for (int nt = 0; nt < 4; ++nt) {
            float bv = bs[nt * 16 + c];
            acc[nt] = (f32x4){bv, bv, bv, bv};
            #pragma unroll
            for (int ks = 0; ks < 6; ++ks)
                acc[nt] = __builtin_amdgcn_mfma_f32_16x16x32_bf16(A[ks], Bf[ks * 4 + nt], acc[nt], 0, 0, 0);
        }
        #pragma unroll
        for (int nt = 0; nt < 4; ++nt)
            #pragma unroll
            for (int rg = 0; rg < 4; ++rg)
                ms[(q * 4 + rg) * 66 + nt * 16 + c] = silu_f(acc[nt][rg]);
        for (int r = 0; r < 16; ++r)
            h[(size_t)(row0 + r) * 64 + lane] = ms[r * 66 + lane];
        if (Wc_next) {
            bf16x8 NA0, NA1;
            const float* np = &ms[c * 66 + q * 8];
            #pragma unroll
            for (int i = 0; i < 8; ++i) {
                NA0[i] = (short)f2bf(np[i]);
                NA1[i] = (short)f2bf(np[32 + i]);
            }
            f32x4 xacc[4];
            #pragma unroll
            for (int nt = 0; nt < 4; ++nt) {
                xacc[nt] = (f32x4){0.f, 0.f, 0.f, 0.f};
                bf16x8 B0 = *(const bf16x8*)&Bp2[(nt * 64 + lane) * 8];
                xacc[nt] = __builtin_amdgcn_mfma_f32_16x16x32_bf16(NA0, B0, xacc[nt], 0, 0, 0);
                bf16x8 B1 = *(const bf16x8*)&Bp2[((4 + nt) * 64 + lane) * 8];
                xacc[nt] = __builtin_amdgcn_mfma_f32_16x16x32_bf16(NA1, B1, xacc[nt], 0, 0, 0);
            }
            #pragma unroll
            for (int nt = 0; nt < 4; ++nt)
                #pragma unroll
                for (int rg = 0; rg < 4; ++rg)
                    ms[(q * 4 + rg) * 66 + nt * 16 + c] = xacc[nt][rg];
            for (int r = 0; r < 16; ++r)
                Xout[(size_t)(row0 + r) * 64 + lane] = f2bf(ms[r * 66 + lane]);
        }
    }
}

// ---------------------------------------------------------------- readout stage 1 (fp32 VALU -> bf16 hid)
__global__ __launch_bounds__(256) void var_hidden_kernel(
    const float* __restrict__ h_var, const float* __restrict__ W,
    const float* __restrict__ b, int colofs, unsigned short* __restrict__ hid) {
    __shared__ float Ws[128 * 64];
    __shared__ float bs[64];
    __shared__ float rs[16 * 128];
    int t = threadIdx.x;
    for (int i = t; i < 128 * 64; i += 256) {
        int k = i >> 6, j = i & 63;
        Ws[i] = W[k * 128 + colofs + j];
    }
    if (t < 64) bs[t] = b[colofs + t];
    __syncthreads();
    const int ntiles = NVAR / 16;
    int w = t >> 6, j = t & 63;
    for (int tile = blockIdx.x; tile < ntiles; tile += gridDim.x) {
        int row0 = tile * 16;
        for (int i = t; i < 2048; i += 256) rs[i] = h_var[(size_t)row0 * 128 + i];
        __syncthreads();
        float acc0 = bs[j], acc1 = bs[j], acc2 = bs[j], acc3 = bs[j];
        const float* r0 = &rs[(w * 4 + 0) * 128];
        const float* r1 = &rs[(w * 4 + 1) * 128];
        const float* r2 = &rs[(w * 4 + 2) * 128];
        const float* r3 = &rs[(w * 4 + 3) * 128];
        #pragma unroll 4
        for (int k = 0; k < 128; k += 4) {
            float w0 = Ws[k * 64 + j], w1v = Ws[(k + 1) * 64 + j];
            float w2v = Ws[(k + 2) * 64 + j], w3v = Ws[(k + 3) * 64 + j];
            float4 a;
            a = *(const float4*)(r0 + k); acc0 += a.x * w0 + a.y * w1v + a.z * w2v + a.w * w3v;
            a = *(const float4*)(r1 + k); acc1 += a.x * w0 + a.y * w1v + a.z * w2v + a.w * w3v;
            a = *(const float4*)(r2 + k); acc2 += a.x * w0 + a.y * w1v + a.z * w2v + a.w * w3v;
            a = *(const float4*)(r3 + k); acc3 += a.x * w0 + a.y * w1v + a.z * w2v + a.w * w3v;
        }
        int row = row0 + w * 4;
        hid[(size_t)(row + 0) * 128 + colofs + j] = f2bf(silu_f(acc0));
        hid[(size_t)(row + 1) * 128 + colofs + j] = f2bf(silu_f(acc1));
        hid[(size_t)(row + 2) * 128 + colofs + j] = f2bf(silu_f(acc2));
        hid[(size_t)(row + 3) * 128 + colofs + j] = f2bf(silu_f(acc3));
        __syncthreads();
    }
}

// ---------------------------------------------------------------- readout stage 2
__global__ __launch_bounds__(256) void out2_kernel(
    const unsigned short* __restrict__ hid, const float* __restrict__ w2,
    const float* __restrict__ b2, float* __restrict__ out) {
    int nw = (gridDim.x * blockDim.x) >> 6;
    int wid = (blockIdx.x * blockDim.x + threadIdx.x) >> 6;
    int lane = threadIdx.x & 63;
    float w00 = w2[lane * 2 + 0], w01 = w2[lane * 2 + 1];
    float w10 = w2[(lane + 64) * 2 + 0], w11 = w2[(lane + 64) * 2 + 1];
    for (int row = wid; row < NVAR; row += nw) {
        float h0 = bf2f(hid[(size_t)row * 128 + lane]);
        float h1 = bf2f(hid[(size_t)row * 128 + 64 + lane]);
        float p0 = h0 * w00 + h1 * w10;
        float p1 = h0 * w01 + h1 * w11;
        #pragma unroll
        for (int off = 32; off > 0; off >>= 1) {
            p0 += __shfl_down(p0, off);
            p1 += __shfl_down(p1, off);
        }
        if (lane == 0) {
            out[(size_t)row * 2 + 0] = p0 + b2[0];
            out[(size_t)row * 2 + 1] = p1 + b2[1];
        }
    }
}

// ---------------------------------------------------------------- launch
extern "C" void kernel_launch(void* const* d_in, const int* in_sizes, int n_in,
                              void* d_out, int out_size, void* d_ws, size_t ws_size,
                              hipStream_t stream) {
    const float* x_lit  = (const float*)d_in[0];
    const float* x_cls  = (const float*)d_in[1];
    const int* edge_lit = (const int*)d_in[2];
    const int* edge_cls = (const int*)d_in[3];
    const float* enc_w1 = (const float*)d_in[4];
    const float* enc_b1 = (const float*)d_in[5];
    const float* enc_w2 = (const float*)d_in[6];
    const float* enc_b2 = (const float*)d_in[7];
    const float* Wc     = (const float*)d_in[8];    // [4][128][64]
    const float* bc     = (const float*)d_in[9];
    const float* Wl     = (const float*)d_in[10];   // [4][192][64]
    const float* bl     = (const float*)d_in[11];
    const float* out_w1 = (const float*)d_in[12];   // [128][128]
    const float* out_b1 = (const float*)d_in[13];
    const float* out_w2 = (const float*)d_in[14];   // [128][2]
    const float* out_b2 = (const float*)d_in[15];
    float* y = (float*)d_out;

    // ---- workspace carve (~208 MB) ----
    const size_t SZ_HLIT = (size_t)N_LIT * 64;
    const size_t SZ_HCLS = (size_t)N_CLS * 64;
    char* p = (char*)d_ws;
    auto take = [&](size_t bytes) -> char* {
        char* r = p; p += (bytes + 255) & ~(size_t)255; return r;
    };
    float*          h_lit      = (float*)take(SZ_HLIT * 4);
    unsigned short* h_cls      = (unsigned short*)take(SZ_HCLS * 2);
    unsigned short* X          = (unsigned short*)take(SZ_HLIT * 2);
    float*          inv_cls    = (float*)take((size_t)N_CLS * 4);
    float*          inv_lit    = (float*)take((size_t)N_LIT * 4);
    int*            row_ptr_cls= (int*)take((size_t)(N_CLS + 1) * 4);
    int*            row_ptr_lit= (int*)take((size_t)(N_LIT + 1) * 4);
    int*            lit_by_cls = (int*)take((size_t)NEDGE * 4);
    int*            cls_by_lit = (int*)take((size_t)NEDGE * 4);
    int*            bh         = (int*)take((size_t)NBLK_S * NBKT * 4);
    int*            off        = (int*)take((size_t)NBLK_S * NBKT * 4);
    int*            bktbase    = (int*)take((size_t)(NBKT + 1) * 4);
    size_t need = (size_t)(p - (char*)d_ws);

    // pair buffer aliases h_lit (dead until encoder): 19.2 MB <= 51.2 MB
    int2* tmp_pairs = (int2*)h_lit;

    dim3 B(256);

    if (ws_size < need) {
        float mb = (float)((double)ws_size / (1024.0 * 1024.0));
        diag_kernel<<<256, B, 0, stream>>>(y, out_size, mb);
        return;
    }

    // ---- CSR build (radix partition) ----
    csr_hist_kernel<<<NBLK_S, B, 0, stream>>>(edge_cls, 12, bh);
    csr_offsets_kernel<<<1, B, 0, stream>>>(bh, off, bktbase);
    csr_scatter_kernel<<<NBLK_S, B, 0, stream>>>(edge_cls, edge_lit, 12, off, tmp_pairs);
    csr_build_kernel<<<NBKT, B, 0, stream>>>(tmp_pairs, bktbase, 4096, N_CLS,
                                             row_ptr_cls, inv_cls, lit_by_cls);
    csr_hist_kernel<<<NBLK_S, B, 0, stream>>>(edge_lit, 10, bh);
    csr_offsets_kernel<<<1, B, 0, stream>>>(bh, off, bktbase);
    csr_scatter_kernel<<<NBLK_S, B, 0, stream>>>(edge_lit, edge_cls, 10, off, tmp_pairs);
    csr_build_kernel<<<NBKT, B, 0, stream>>>(tmp_pairs, bktbase, 1024, N_LIT,
                                             row_ptr_lit, inv_lit, cls_by_lit);
    tail_kernel<<<1, 64, 0, stream>>>(row_ptr_cls, row_ptr_lit);

    // ---- encoder (overwrites tmp_pairs alias region) ----
    encoder_kernel<<<2048, B, 0, stream>>>(x_lit, x_cls, enc_w1, enc_b1, enc_w2, enc_b2,
                                           h_lit, h_cls);

    // layer-0 X; layers 1..3 get X from lit_update's fused epilogue
    gemmX_kernel<<<1024, B, 0, stream>>>(h_lit, Wc + 64 * 64, X);

    for (int l = 0; l < 4; ++l) {
        const float* Wl_l = Wl + (size_t)l * 192 * 64;
        const float* Wc_next = (l < 3) ? (Wc + (size_t)(l + 1) * 128 * 64 + 64 * 64) : nullptr;
        cls_update_kernel<<<2048, B, 0, stream>>>(h_cls, X, row_ptr_cls, lit_by_cls,
                                                  inv_cls, Wc + (size_t)l * 128 * 64,
                                                  bc + l * 64, l > 0);
        gather_lit_kernel<<<4096, B, 0, stream>>>(h_cls, row_ptr_lit, cls_by_lit,
                                                  inv_lit, X);
        lit_update_kernel<<<1024, B, 0, stream>>>(h_lit, X, Wl_l, bl + l * 64,
                                                  Wc_next, X);
    }

    // ---- readout ----
    var_hidden_kernel<<<4096, B, 0, stream>>>(h_lit, out_w1, out_b1, 0, X);
    var_hidden_kernel<<<4096, B, 0, stream>>>(h_lit, out_w1, out_b1, 64, X);
    out2_kernel<<<2048, B, 0, stream>>>(X, out_w2, out_b2, y);
}

// Round 10
// 1707.316 us; speedup vs baseline: 2.3602x; 1.1638x over previous
//
#include <hip/hip_runtime.h>
#include <math.h>

#define N_LIT 200000
#define N_CLS 800000
#define NEDGE 2400000
#define NVAR  (N_LIT / 2)

// CSR radix-partition parameters: 200 chunks x 12000 edges = NEDGE exactly; 196 buckets
#define NBLK_S 200
#define CHUNK  12000
#define NBKT   196

typedef __attribute__((ext_vector_type(8))) short bf16x8;
typedef __attribute__((ext_vector_type(4))) float f32x4;

__device__ __forceinline__ float silu_f(float x) { return x / (1.0f + expf(-x)); }

__device__ __forceinline__ float bf2f(unsigned short u) {
    unsigned int x = ((unsigned int)u) << 16;
    return __uint_as_float(x);
}
__device__ __forceinline__ unsigned short f2bf(float f) {
    unsigned int x = __float_as_uint(f);
    unsigned int r = (x + 0x7fffu + ((x >> 16) & 1u)) >> 16;
    return (unsigned short)r;
}

// ---------------------------------------------------------------- diagnostics
__global__ void diag_kernel(float* __restrict__ out, int n, float val) {
    int i = blockIdx.x * blockDim.x + threadIdx.x;
    int stride = gridDim.x * blockDim.x;
    for (; i < n; i += stride) out[i] = val;
}

// ---------------------------------------------------------------- CSR build: radix partition
__global__ __launch_bounds__(256) void csr_hist_kernel(
    const int* __restrict__ key, int shift, int* __restrict__ bh) {
    __shared__ int h[NBKT];
    int b = blockIdx.x, t = threadIdx.x;
    for (int i = t; i < NBKT; i += 256) h[i] = 0;
    __syncthreads();
    int s = b * CHUNK;
    for (int i = t; i < CHUNK; i += 256) atomicAdd(&h[key[s + i] >> shift], 1);
    __syncthreads();
    for (int i = t; i < NBKT; i += 256) bh[b * NBKT + i] = h[i];
}

__global__ __launch_bounds__(256) void csr_offsets_kernel(
    const int* __restrict__ bh, int* __restrict__ off, int* __restrict__ bktbase) {
    __shared__ int sc[256];
    int t = threadIdx.x;
    int sum = 0;
    if (t < NBKT)
        for (int b = 0; b < NBLK_S; ++b) sum += bh[b * NBKT + t];
    int v = sum;
    sc[t] = v; __syncthreads();
    for (int o = 1; o < 256; o <<= 1) {
        int add = (t >= o) ? sc[t - o] : 0; __syncthreads();
        sc[t] += add; __syncthreads();
    }
    int base = sc[t] - v;   // exclusive
    if (t < NBKT) {
        bktbase[t] = base;
        int run = base;
        for (int b = 0; b < NBLK_S; ++b) { off[b * NBKT + t] = run; run += bh[b * NBKT + t]; }
    }
    if (t == 0) bktbase[NBKT] = NEDGE;
}

__global__ __launch_bounds__(256) void csr_scatter_kernel(
    const int* __restrict__ key, const int* __restrict__ val, int shift,
    const int* __restrict__ off, int2* __restrict__ tmp) {
    __shared__ int cur[NBKT];
    int b = blockIdx.x, t = threadIdx.x;
    for (int i = t; i < NBKT; i += 256) cur[i] = off[b * NBKT + i];
    __syncthreads();
    int s = b * CHUNK;
    for (int i = t; i < CHUNK; i += 256) {
        int k = key[s + i], v = val[s + i];
        int p = atomicAdd(&cur[k >> shift], 1);
        tmp[p] = make_int2(k, v);
    }
}

__global__ __launch_bounds__(256) void csr_build_kernel(
    const int2* __restrict__ tmp, const int* __restrict__ bktbase, int rows_per_bkt,
    int nrows, int* __restrict__ row_ptr, float* __restrict__ inv, int* __restrict__ adj) {
    __shared__ int hist[4096];
    __shared__ int part[256];
    int k = blockIdx.x, t = threadIdx.x;
    int rowbase = k * rows_per_bkt;
    for (int i = t; i < rows_per_bkt; i += 256) hist[i] = 0;
    __syncthreads();
    int e0 = bktbase[k], e1 = bktbase[k + 1];
    for (int e = e0 + t; e < e1; e += 256) atomicAdd(&hist[tmp[e].x - rowbase], 1);
    __syncthreads();
    int per = rows_per_bkt >> 8;   // 16 (cls) or 4 (lit)
    int base_i = t * per;
    int vals[16];
    int s = 0;
    for (int i = 0; i < per; ++i) { vals[i] = hist[base_i + i]; s += vals[i]; }
    int v = s;
    part[t] = v; __syncthreads();
    for (int o = 1; o < 256; o <<= 1) {
        int add = (t >= o) ? part[t - o] : 0; __syncthreads();
        part[t] += add; __syncthreads();
    }
    int run = part[t] - v;
    for (int i = 0; i < per; ++i) { hist[base_i + i] = run; run += vals[i]; }
    __syncthreads();
    for (int i = t; i < rows_per_bkt; i += 256) {
        int row = rowbase + i;
        if (row < nrows) {
            int ex = hist[i];
            int nx = (i + 1 < rows_per_bkt) ? hist[i + 1] : (e1 - e0);
            row_ptr[row] = e0 + ex;
            int d = nx - ex;
            inv[row] = 1.0f / (float)(d > 0 ? d : 1);
        }
    }
    __syncthreads();
    for (int e = e0 + t; e < e1; e += 256) {
        int2 pr = tmp[e];
        int pos = atomicAdd(&hist[pr.x - rowbase], 1);
        adj[e0 + pos] = pr.y;
    }
}

__global__ void tail_kernel(int* __restrict__ rp_cls, int* __restrict__ rp_lit) {
    if (blockIdx.x == 0 && threadIdx.x == 0) {
        rp_cls[N_CLS] = NEDGE;
        rp_lit[N_LIT] = NEDGE;
    }
}

// ---------------------------------------------------------------- encoder (MFMA 2nd GEMM)
__global__ __launch_bounds__(256, 4) void encoder_kernel(
    const float* __restrict__ x_lit, const float* __restrict__ x_cls,
    const float* __restrict__ w1, const float* __restrict__ b1,
    const float* __restrict__ w2, const float* __restrict__ b2,
    float* __restrict__ h_lit, unsigned short* __restrict__ h_cls) {
    __shared__ float w1s[4 * 64];
    __shared__ float b1s[64], b2s[64];
    __shared__ __align__(16) unsigned short Bp[8 * 64 * 8];
    __shared__ float xt[4][64];
    __shared__ float hs[4][16 * 68];
    int t = threadIdx.x;
    w1s[t] = w1[t];
    if (t < 64) { b1s[t] = b1[t]; b2s[t] = b2[t]; }
    for (int idx = t; idx < 8 * 64 * 8; idx += 256) {
        int i = idx & 7, ln = (idx >> 3) & 63, fid = idx >> 9;
        int ks = fid >> 2, nt = fid & 3;
        Bp[idx] = f2bf(w2[(ks * 32 + ((ln >> 4) << 3) + i) * 64 + nt * 16 + (ln & 15)]);
    }
    __syncthreads();
    int w = t >> 6, lane = t & 63;
    int c = lane & 15, q = lane >> 4;
    bf16x8 Bf[8];
    #pragma unroll
    for (int f = 0; f < 8; ++f) Bf[f] = *(const bf16x8*)&Bp[(f * 64 + lane) * 8];
    float* hw = hs[w];
    int nwaves = gridDim.x * 4;
    int wid = blockIdx.x * 4 + w;
    const int ntiles = (N_LIT + N_CLS) / 16;
    for (int tile = wid; tile < ntiles; tile += nwaves) {
        int row0 = tile * 16;
        const float* xsrc = (row0 < N_LIT) ? x_lit + (size_t)row0 * 4
                                           : x_cls + (size_t)(row0 - N_LIT) * 4;
        xt[w][lane] = xsrc[lane];
        for (int r = 0; r < 16; ++r) {
            float pre = b1s[lane];
            #pragma unroll
            for (int k = 0; k < 4; ++k) pre += xt[w][r * 4 + k] * w1s[k * 64 + lane];
            hw[r * 68 + lane] = silu_f(pre);
        }
        bf16x8 A0, A1;
        const float* ap = &hw[c * 68 + q * 8];
        #pragma unroll
        for (int i = 0; i < 8; ++i) {
            A0[i] = (short)f2bf(ap[i]);
            A1[i] = (short)f2bf(ap[32 + i]);
        }
        f32x4 acc[4];
        #pragma unroll
        for (int nt = 0; nt < 4; ++nt) {
            float bv = b2s[nt * 16 + c];
            acc[nt] = (f32x4){bv, bv, bv, bv};
            acc[nt] = __builtin_amdgcn_mfma_f32_16x16x32_bf16(A0, Bf[nt], acc[nt], 0, 0, 0);
            acc[nt] = __builtin_amdgcn_mfma_f32_16x16x32_bf16(A1, Bf[4 + nt], acc[nt], 0, 0, 0);
        }
        #pragma unroll
        for (int nt = 0; nt < 4; ++nt)
            #pragma unroll
            for (int rg = 0; rg < 4; ++rg)
                hw[(q * 4 + rg) * 68 + nt * 16 + c] = acc[nt][rg];
        if (row0 < N_LIT) {
            for (int r = 0; r < 16; ++r)
                h_lit[(size_t)(row0 + r) * 64 + lane] = hw[r * 68 + lane];
        } else {
            for (int r = 0; r < 16; ++r)
                h_cls[(size_t)(row0 + r - N_LIT) * 64 + lane] = f2bf(hw[r * 68 + lane]);
        }
    }
}

// ---------------------------------------------------------------- X = h_lit @ Wc_bot (MFMA) — layer 0 only
__global__ __launch_bounds__(256, 4) void gemmX_kernel(
    const float* __restrict__ in, const float* __restrict__ W,
    unsigned short* __restrict__ out) {
    __shared__ __align__(16) unsigned short Bp[8 * 64 * 8];
    __shared__ float stage[4][16 * 66];
    int t = threadIdx.x;
    for (int idx = t; idx < 8 * 64 * 8; idx += 256) {
        int i = idx & 7, ln = (idx >> 3) & 63, fid = idx >> 9;
        int ks = fid >> 2, nt = fid & 3;
        Bp[idx] = f2bf(W[(ks * 32 + ((ln >> 4) << 3) + i) * 64 + nt * 16 + (ln & 15)]);
    }
    __syncthreads();
    int w = t >> 6, lane = t & 63;
    int c = lane & 15, q = lane >> 4;
    bf16x8 Bf[8];
    #pragma unroll
    for (int f = 0; f < 8; ++f) Bf[f] = *(const bf16x8*)&Bp[(f * 64 + lane) * 8];
    float* ms = stage[w];
    int nwaves = gridDim.x * 4;
    int wid = blockIdx.x * 4 + w;
    for (int tile = wid; tile < N_LIT / 16; tile += nwaves) {
        int row0 = tile * 16;
        const float* ap = in + (size_t)(row0 + c) * 64 + q * 8;
        bf16x8 A0, A1;
        #pragma unroll
        for (int i = 0; i < 8; ++i) {
            A0[i] = (short)f2bf(ap[i]);
            A1[i] = (short)f2bf(ap[32 + i]);
        }
        f32x4 acc[4];
        #pragma unroll
        for (int nt = 0; nt < 4; ++nt) {
            acc[nt] = (f32x4){0.f, 0.f, 0.f, 0.f};
            acc[nt] = __builtin_amdgcn_mfma_f32_16x16x32_bf16(A0, Bf[nt], acc[nt], 0, 0, 0);
            acc[nt] = __builtin_amdgcn_mfma_f32_16x16x32_bf16(A1, Bf[4 + nt], acc[nt], 0, 0, 0);
        }
        #pragma unroll
        for (int nt = 0; nt < 4; ++nt)
            #pragma unroll
            for (int rg = 0; rg < 4; ++rg)
                ms[(q * 4 + rg) * 66 + nt * 16 + c] = acc[nt][rg];
        for (int r = 0; r < 16; ++r)
            out[(size_t)(row0 + r) * 64 + lane] = f2bf(ms[r * 66 + lane]);
    }
}

// ---------------------------------------------------------------- clause update (MFMA + monotone register-flush gather)
// S_new[c] = silu((S[c] @ Wc_top + bc) + inv[c] * sum_e X[lit[e]])
// h_cls buffer stores the ACTIVATED state (encoder output at layer 0 is raw,
// consumed raw — matches reference concat semantics). No silu on A-read.
__global__ __launch_bounds__(256, 5) void cls_update_kernel(
    unsigned short* __restrict__ h_cls, const unsigned short* __restrict__ X,
    const int* __restrict__ rp, const int* __restrict__ lits,
    const float* __restrict__ inv_deg, const float* __restrict__ W,
    const float* __restrict__ b) {
    __shared__ __align__(16) unsigned short Bp[8 * 64 * 8];
    __shared__ float bs[64];
    __shared__ float stage[4][16 * 66];
    __shared__ int rps[4][17];
    __shared__ float invs[4][16];
    __shared__ int lse[4][128];
    int t = threadIdx.x;
    for (int idx = t; idx < 8 * 64 * 8; idx += 256) {
        int i = idx & 7, ln = (idx >> 3) & 63, fid = idx >> 9;
        int ks = fid >> 2, nt = fid & 3;
        Bp[idx] = f2bf(W[(ks * 32 + ((ln >> 4) << 3) + i) * 64 + nt * 16 + (ln & 15)]);
    }
    if (t < 64) bs[t] = b[t];
    __syncthreads();
    int w = t >> 6, lane = t & 63;
    int c = lane & 15, q = lane >> 4;
    bf16x8 Bf[8];
    #pragma unroll
    for (int f = 0; f < 8; ++f) Bf[f] = *(const bf16x8*)&Bp[(f * 64 + lane) * 8];
    float* ms = stage[w];
    int* rpw = rps[w];
    float* ivw = invs[w];
    int* lsw = lse[w];
    int nwaves = gridDim.x * 4;
    int wid = blockIdx.x * 4 + w;
    for (int tile = wid; tile < N_CLS / 16; tile += nwaves) {
        int row0 = tile * 16;
        const unsigned short* ap = h_cls + (size_t)(row0 + c) * 64 + q * 8;
        bf16x8 A0 = *(const bf16x8*)(ap);
        bf16x8 A1 = *(const bf16x8*)(ap + 32);
        f32x4 acc[4];
        #pragma unroll
        for (int nt = 0; nt < 4; ++nt) {
            float bv = bs[nt * 16 + c];
            acc[nt] = (f32x4){bv, bv, bv, bv};
            acc[nt] = __builtin_amdgcn_mfma_f32_16x16x32_bf16(A0, Bf[nt], acc[nt], 0, 0, 0);
            acc[nt] = __builtin_amdgcn_mfma_f32_16x16x32_bf16(A1, Bf[4 + nt], acc[nt], 0, 0, 0);
        }
        #pragma unroll
        for (int r2 = 0; r2 < 16; ++r2) ms[r2 * 66 + lane] = 0.f;
        if (lane < 17) rpw[lane] = rp[row0 + lane];
        if (lane < 16) ivw[lane] = inv_deg[row0 + lane];
        int E0 = rpw[0], E1 = rpw[16];
        int r = 0, endr = rpw[1];
        float racc = 0.f;
        for (int base = E0; base < E1; base += 128) {
            int n = E1 - base; if (n > 128) n = 128;
            for (int i = lane; i < n; i += 64) lsw[i] = lits[base + i];
            int i = 0;
            for (; i + 7 < n; i += 8) {
                float v[8];
                #pragma unroll
                for (int k = 0; k < 8; ++k)
                    v[k] = bf2f(X[(size_t)lsw[i + k] * 64 + lane]);
                #pragma unroll
                for (int k = 0; k < 8; ++k) {
                    int g = base + i + k;
                    while (g >= endr) {
                        ms[r * 66 + lane] = racc * ivw[r];
                        racc = 0.f; ++r; endr = rpw[r + 1];
                    }
                    racc += v[k];
                }
            }
            for (; i < n; ++i) {
                float v0 = bf2f(X[(size_t)lsw[i] * 64 + lane]);
                int g = base + i;
                while (g >= endr) {
                    ms[r * 66 + lane] = racc * ivw[r];
                    racc = 0.f; ++r; endr = rpw[r + 1];
                }
                racc += v0;
            }
        }
        if (E1 > E0) ms[r * 66 + lane] = racc * ivw[r];
        racc = 0.f;
        #pragma unroll
        for (int nt = 0; nt < 4; ++nt)
            #pragma unroll
            for (int rg = 0; rg < 4; ++rg)
                ms[(q * 4 + rg) * 66 + nt * 16 + c] += acc[nt][rg];
        for (int rr = 0; rr < 16; ++rr)
            h_cls[(size_t)(row0 + rr) * 64 + lane] = f2bf(silu_f(ms[rr * 66 + lane]));
    }
}

// ---------------------------------------------------------------- lit-side gather (2 rows/wave, no silu — S is pre-activated)
__global__ __launch_bounds__(256, 8) void gather_lit_kernel(
    const unsigned short* __restrict__ S, const int* __restrict__ rp,
    const int* __restrict__ clss, const float* __restrict__ inv_deg,
    unsigned short* __restrict__ m_out) {
    int nw = (gridDim.x * blockDim.x) >> 6;
    int wid = (blockIdx.x * blockDim.x + threadIdx.x) >> 6;
    int lane = threadIdx.x & 63;
    const int HALF = N_LIT / 2;
    for (int row = wid; row < HALF; row += nw) {
        int rowB = row + HALF;
        int a0 = rp[row], a1 = rp[row + 1];
        int b0 = rp[rowB], b1 = rp[rowB + 1];
        float ga0 = 0.f, ga1 = 0.f, gb0 = 0.f, gb1 = 0.f;
        int ea = a0, eb = b0;
        for (; ea + 1 < a1 && eb + 1 < b1; ea += 2, eb += 2) {
            int ca0 = clss[ea], ca1 = clss[ea + 1];
            int cb0 = clss[eb], cb1 = clss[eb + 1];
            ga0 += bf2f(S[(size_t)ca0 * 64 + lane]);
            ga1 += bf2f(S[(size_t)ca1 * 64 + lane]);
            gb0 += bf2f(S[(size_t)cb0 * 64 + lane]);
            gb1 += bf2f(S[(size_t)cb1 * 64 + lane]);
        }
        for (; ea + 1 < a1; ea += 2) {
            ga0 += bf2f(S[(size_t)clss[ea] * 64 + lane]);
            ga1 += bf2f(S[(size_t)clss[ea + 1] * 64 + lane]);
        }
        for (; eb + 1 < b1; eb += 2) {
            gb0 += bf2f(S[(size_t)clss[eb] * 64 + lane]);
            gb1 += bf2f(S[(size_t)clss[eb + 1] * 64 + lane]);
        }
        if (ea < a1) ga0 += bf2f(S[(size_t)clss[ea] * 64 + lane]);
        if (eb < b1) gb0 += bf2f(S[(size_t)clss[eb] * 64 + lane]);
        m_out[(size_t)row * 64 + lane]  = f2bf((ga0 + ga1) * inv_deg[row]);
        m_out[(size_t)rowB * 64 + lane] = f2bf((gb0 + gb1) * inv_deg[rowB]);
    }
}

// ---------------------------------------------------------------- literal update (MFMA, in-place fp32, + fused next-layer X)
__global__ __launch_bounds__(256, 3) void lit_update_kernel(
    float* __restrict__ h, const unsigned short* __restrict__ m,
    const float* __restrict__ W, const float* __restrict__ b,
    const float* __restrict__ Wc_next, unsigned short* __restrict__ Xout) {
    __shared__ __align__(16) unsigned short Bp[24 * 64 * 8];
    __shared__ __align__(16) unsigned short Bp2[8 * 64 * 8];
    __shared__ float bs[64];
    __shared__ float stage[4][16 * 66];
    int t = threadIdx.x;
    for (int idx = t; idx < 24 * 64 * 8; idx += 256) {
        int i = idx & 7, ln = (idx >> 3) & 63, fid = idx >> 9;
        int ks = fid >> 2, nt = fid & 3;
        Bp[idx] = f2bf(W[(ks * 32 + ((ln >> 4) << 3) + i) * 64 + nt * 16 + (ln & 15)]);
    }
    if (Wc_next) {
        for (int idx = t; idx < 8 * 64 * 8; idx += 256) {
            int i = idx & 7, ln = (idx >> 3) & 63, fid = idx >> 9;
            int ks = fid >> 2, nt = fid & 3;
            Bp2[idx] = f2bf(Wc_next[(ks * 32 + ((ln >> 4) << 3) + i) * 64 + nt * 16 + (ln & 15)]);
        }
    }
    if (t < 64) bs[t] = b[t];
    __syncthreads();
    int w = t >> 6, lane = t & 63;
    int c = lane & 15, q = lane >> 4;
    bf16x8 Bf[24];
    #pragma unroll
    for (int f = 0; f < 24; ++f) Bf[f] = *(const bf16x8*)&Bp[(f * 64 + lane) * 8];
    float* ms = stage[w];
    int nwaves = gridDim.x * 4;
    int wid = blockIdx.x * 4 + w;
    for (int tile = wid; tile < N_LIT / 16; tile += nwaves) {
        int row0 = tile * 16;
        bf16x8 A[6];
        const float* hp = h + (size_t)(row0 + c) * 64 + q * 8;
        const float* hf = h + (size_t)((row0 + c) ^ 1) * 64 + q * 8;
        const unsigned short* mp = m + (size_t)(row0 + c) * 64 + q * 8;
        #pragma unroll
        for (int i = 0; i < 8; ++i) {
            A[0][i] = (short)f2bf(hp[i]);
            A[1][i] = (short)f2bf(hp[32 + i]);
            A[4][i] = (short)f2bf(hf[i]);
            A[5][i] = (short)f2bf(hf[32 + i]);
        }
        A[2] = *(const bf16x8*)(mp);
        A[3] = *(const bf16x8*)(mp + 32);
        f32x4 acc[4];
        #pragma unroll
        for (int nt = 0; nt < 4; ++nt) {
            float bv = bs[nt * 16 + c];
            acc[nt] = (f32x4){bv, bv, bv, bv};
            #pragma unroll
            for (int ks = 0; ks < 6; ++ks)
                acc[nt] = __builtin_amdgcn_mfma_f32_16x16x32_bf16(A[ks], Bf[ks * 4 + nt], acc[nt], 0, 0, 0);
        }
        #pragma unroll
        for (int nt = 0; nt < 4; ++nt)
            #pragma unroll
            for (int rg = 0; rg < 4; ++rg)
                ms[(q * 4 + rg) * 66 + nt * 16 + c] = silu_f(acc[nt][rg]);
        for (int r = 0; r < 16; ++r)
            h[(size_t)(row0 + r) * 64 + lane] = ms[r * 66 + lane];
        if (Wc_next) {
            bf16x8 NA0, NA1;
            const float* np = &ms[c * 66 + q * 8];
            #pragma unroll
            for (int i = 0; i < 8; ++i) {
                NA0[i] = (short)f2bf(np[i]);
                NA1[i] = (short)f2bf(np[32 + i]);
            }
            f32x4 xacc[4];
            #pragma unroll
            for (int nt = 0; nt < 4; ++nt) {
                xacc[nt] = (f32x4){0.f, 0.f, 0.f, 0.f};
                bf16x8 B0 = *(const bf16x8*)&Bp2[(nt * 64 + lane) * 8];
                xacc[nt] = __builtin_amdgcn_mfma_f32_16x16x32_bf16(NA0, B0, xacc[nt], 0, 0, 0);
                bf16x8 B1 = *(const bf16x8*)&Bp2[((4 + nt) * 64 + lane) * 8];
                xacc[nt] = __builtin_amdgcn_mfma_f32_16x16x32_bf16(NA1, B1, xacc[nt], 0, 0, 0);
            }
            #pragma unroll
            for (int nt = 0; nt < 4; ++nt)
                #pragma unroll
                for (int rg = 0; rg < 4; ++rg)
                    ms[(q * 4 + rg) * 66 + nt * 16 + c] = xacc[nt][rg];
            for (int r = 0; r < 16; ++r)
                Xout[(size_t)(row0 + r) * 64 + lane] = f2bf(ms[r * 66 + lane]);
        }
    }
}

// ---------------------------------------------------------------- readout stage 1 (fp32 VALU -> bf16 hid)
__global__ __launch_bounds__(256) void var_hidden_kernel(
    const float* __restrict__ h_var, const float* __restrict__ W,
    const float* __restrict__ b, int colofs, unsigned short* __restrict__ hid) {
    __shared__ float Ws[128 * 64];
    __shared__ float bs[64];
    __shared__ float rs[16 * 128];
    int t = threadIdx.x;
    for (int i = t; i < 128 * 64; i += 256) {
        int k = i >> 6, j = i & 63;
        Ws[i] = W[k * 128 + colofs + j];
    }
    if (t < 64) bs[t] = b[colofs + t];
    __syncthreads();
    const int ntiles = NVAR / 16;
    int w = t >> 6, j = t & 63;
    for (int tile = blockIdx.x; tile < ntiles; tile += gridDim.x) {
        int row0 = tile * 16;
        for (int i = t; i < 2048; i += 256) rs[i] = h_var[(size_t)row0 * 128 + i];
        __syncthreads();
        float acc0 = bs[j], acc1 = bs[j], acc2 = bs[j], acc3 = bs[j];
        const float* r0 = &rs[(w * 4 + 0) * 128];
        const float* r1 = &rs[(w * 4 + 1) * 128];
        const float* r2 = &rs[(w * 4 + 2) * 128];
        const float* r3 = &rs[(w * 4 + 3) * 128];
        #pragma unroll 4
        for (int k = 0; k < 128; k += 4) {
            float w0 = Ws[k * 64 + j], w1v = Ws[(k + 1) * 64 + j];
            float w2v = Ws[(k + 2) * 64 + j], w3v = Ws[(k + 3) * 64 + j];
            float4 a;
            a = *(const float4*)(r0 + k); acc0 += a.x * w0 + a.y * w1v + a.z * w2v + a.w * w3v;
            a = *(const float4*)(r1 + k); acc1 += a.x * w0 + a.y * w1v + a.z * w2v + a.w * w3v;
            a = *(const float4*)(r2 + k); acc2 += a.x * w0 + a.y * w1v + a.z * w2v + a.w * w3v;
            a = *(const float4*)(r3 + k); acc3 += a.x * w0 + a.y * w1v + a.z * w2v + a.w * w3v;
        }
        int row = row0 + w * 4;
        hid[(size_t)(row + 0) * 128 + colofs + j] = f2bf(silu_f(acc0));
        hid[(size_t)(row + 1) * 128 + colofs + j] = f2bf(silu_f(acc1));
        hid[(size_t)(row + 2) * 128 + colofs + j] = f2bf(silu_f(acc2));
        hid[(size_t)(row + 3) * 128 + colofs + j] = f2bf(silu_f(acc3));
        __syncthreads();
    }
}

// ---------------------------------------------------------------- readout stage 2
__global__ __launch_bounds__(256) void out2_kernel(
    const unsigned short* __restrict__ hid, const float* __restrict__ w2,
    const float* __restrict__ b2, float* __restrict__ out) {
    int nw = (gridDim.x * blockDim.x) >> 6;
    int wid = (blockIdx.x * blockDim.x + threadIdx.x) >> 6;
    int lane = threadIdx.x & 63;
    float w00 = w2[lane * 2 + 0], w01 = w2[lane * 2 + 1];
    float w10 = w2[(lane + 64) * 2 + 0], w11 = w2[(lane + 64) * 2 + 1];
    for (int row = wid; row < NVAR; row += nw) {
        float h0 = bf2f(hid[(size_t)row * 128 + lane]);
        float h1 = bf2f(hid[(size_t)row * 128 + 64 + lane]);
        float p0 = h0 * w00 + h1 * w10;
        float p1 = h0 * w01 + h1 * w11;
        #pragma unroll
        for (int off = 32; off > 0; off >>= 1) {
            p0 += __shfl_down(p0, off);
            p1 += __shfl_down(p1, off);
        }
        if (lane == 0) {
            out[(size_t)row * 2 + 0] = p0 + b2[0];
            out[(size_t)row * 2 + 1] = p1 + b2[1];
        }
    }
}

// ---------------------------------------------------------------- launch
extern "C" void kernel_launch(void* const* d_in, const int* in_sizes, int n_in,
                              void* d_out, int out_size, void* d_ws, size_t ws_size,
                              hipStream_t stream) {
    const float* x_lit  = (const float*)d_in[0];
    const float* x_cls  = (const float*)d_in[1];
    const int* edge_lit = (const int*)d_in[2];
    const int* edge_cls = (const int*)d_in[3];
    const float* enc_w1 = (const float*)d_in[4];
    const float* enc_b1 = (const float*)d_in[5];
    const float* enc_w2 = (const float*)d_in[6];
    const float* enc_b2 = (const float*)d_in[7];
    const float* Wc     = (const float*)d_in[8];    // [4][128][64]
    const float* bc     = (const float*)d_in[9];
    const float* Wl     = (const float*)d_in[10];   // [4][192][64]
    const float* bl     = (const float*)d_in[11];
    const float* out_w1 = (const float*)d_in[12];   // [128][128]
    const float* out_b1 = (const float*)d_in[13];
    const float* out_w2 = (const float*)d_in[14];   // [128][2]
    const float* out_b2 = (const float*)d_in[15];
    float* y = (float*)d_out;

    // ---- workspace carve (~208 MB) ----
    const size_t SZ_HLIT = (size_t)N_LIT * 64;
    const size_t SZ_HCLS = (size_t)N_CLS * 64;
    char* p = (char*)d_ws;
    auto take = [&](size_t bytes) -> char* {
        char* r = p; p += (bytes + 255) & ~(size_t)255; return r;
    };
    float*          h_lit      = (float*)take(SZ_HLIT * 4);
    unsigned short* h_cls      = (unsigned short*)take(SZ_HCLS * 2);
    unsigned short* X          = (unsigned short*)take(SZ_HLIT * 2);
    float*          inv_cls    = (float*)take((size_t)N_CLS * 4);
    float*          inv_lit    = (float*)take((size_t)N_LIT * 4);
    int*            row_ptr_cls= (int*)take((size_t)(N_CLS + 1) * 4);
    int*            row_ptr_lit= (int*)take((size_t)(N_LIT + 1) * 4);
    int*            lit_by_cls = (int*)take((size_t)NEDGE * 4);
    int*            cls_by_lit = (int*)take((size_t)NEDGE * 4);
    int*            bh         = (int*)take((size_t)NBLK_S * NBKT * 4);
    int*            off        = (int*)take((size_t)NBLK_S * NBKT * 4);
    int*            bktbase    = (int*)take((size_t)(NBKT + 1) * 4);
    size_t need = (size_t)(p - (char*)d_ws);

    // pair buffer aliases h_lit (dead until encoder): 19.2 MB <= 51.2 MB
    int2* tmp_pairs = (int2*)h_lit;

    dim3 B(256);

    if (ws_size < need) {
        float mb = (float)((double)ws_size / (1024.0 * 1024.0));
        diag_kernel<<<256, B, 0, stream>>>(y, out_size, mb);
        return;
    }

    // ---- CSR build (radix partition) ----
    csr_hist_kernel<<<NBLK_S, B, 0, stream>>>(edge_cls, 12, bh);
    csr_offsets_kernel<<<1, B, 0, stream>>>(bh, off, bktbase);
    csr_scatter_kernel<<<NBLK_S, B, 0, stream>>>(edge_cls, edge_lit, 12, off, tmp_pairs);
    csr_build_kernel<<<NBKT, B, 0, stream>>>(tmp_pairs, bktbase, 4096, N_CLS,
                                             row_ptr_cls, inv_cls, lit_by_cls);
    csr_hist_kernel<<<NBLK_S, B, 0, stream>>>(edge_lit, 10, bh);
    csr_offsets_kernel<<<1, B, 0, stream>>>(bh, off, bktbase);
    csr_scatter_kernel<<<NBLK_S, B, 0, stream>>>(edge_lit, edge_cls, 10, off, tmp_pairs);
    csr_build_kernel<<<NBKT, B, 0, stream>>>(tmp_pairs, bktbase, 1024, N_LIT,
                                             row_ptr_lit, inv_lit, cls_by_lit);
    tail_kernel<<<1, 64, 0, stream>>>(row_ptr_cls, row_ptr_lit);

    // ---- encoder (overwrites tmp_pairs alias region) ----
    encoder_kernel<<<2048, B, 0, stream>>>(x_lit, x_cls, enc_w1, enc_b1, enc_w2, enc_b2,
                                           h_lit, h_cls);

    // layer-0 X; layers 1..3 get X from lit_update's fused epilogue
    gemmX_kernel<<<1024, B, 0, stream>>>(h_lit, Wc + 64 * 64, X);

    for (int l = 0; l < 4; ++l) {
        const float* Wl_l = Wl + (size_t)l * 192 * 64;
        const float* Wc_next = (l < 3) ? (Wc + (size_t)(l + 1) * 128 * 64 + 64 * 64) : nullptr;
        cls_update_kernel<<<2048, B, 0, stream>>>(h_cls, X, row_ptr_cls, lit_by_cls,
                                                  inv_cls, Wc + (size_t)l * 128 * 64,
                                                  bc + l * 64);
        gather_lit_kernel<<<4096, B, 0, stream>>>(h_cls, row_ptr_lit, cls_by_lit,
                                                  inv_lit, X);
        lit_update_kernel<<<1024, B, 0, stream>>>(h_lit, X, Wl_l, bl + l * 64,
                                                  Wc_next, X);
    }

    // ---- readout ----
    var_hidden_kernel<<<4096, B, 0, stream>>>(h_lit, out_w1, out_b1, 0, X);
    var_hidden_kernel<<<4096, B, 0, stream>>>(h_lit, out_w1, out_b1, 64, X);
    out2_kernel<<<2048, B, 0, stream>>>(X, out_w2, out_b2, y);
}

// Round 11
// 1681.056 us; speedup vs baseline: 2.3971x; 1.0156x over previous
//
#include <hip/hip_runtime.h>
#include <math.h>

#define N_LIT 200000
#define N_CLS 800000
#define NEDGE 2400000
#define NVAR  (N_LIT / 2)

// CSR radix-partition parameters: 200 chunks x 12000 edges = NEDGE exactly; 196 buckets
#define NBLK_S 200
#define CHUNK  12000
#define NBKT   196

typedef __attribute__((ext_vector_type(8))) short bf16x8;
typedef __attribute__((ext_vector_type(4))) float f32x4;

__device__ __forceinline__ float silu_f(float x) { return x / (1.0f + expf(-x)); }

__device__ __forceinline__ float bf2f(unsigned short u) {
    unsigned int x = ((unsigned int)u) << 16;
    return __uint_as_float(x);
}
__device__ __forceinline__ unsigned short f2bf(float f) {
    unsigned int x = __float_as_uint(f);
    unsigned int r = (x + 0x7fffu + ((x >> 16) & 1u)) >> 16;
    return (unsigned short)r;
}

// ---------------------------------------------------------------- diagnostics
__global__ void diag_kernel(float* __restrict__ out, int n, float val) {
    int i = blockIdx.x * blockDim.x + threadIdx.x;
    int stride = gridDim.x * blockDim.x;
    for (; i < n; i += stride) out[i] = val;
}

// ---------------------------------------------------------------- CSR build: radix partition
__global__ __launch_bounds__(256) void csr_hist_kernel(
    const int* __restrict__ key, int shift, int* __restrict__ bh) {
    __shared__ int h[NBKT];
    int b = blockIdx.x, t = threadIdx.x;
    for (int i = t; i < NBKT; i += 256) h[i] = 0;
    __syncthreads();
    int s = b * CHUNK;
    for (int i = t; i < CHUNK; i += 256) atomicAdd(&h[key[s + i] >> shift], 1);
    __syncthreads();
    for (int i = t; i < NBKT; i += 256) bh[b * NBKT + i] = h[i];
}

__global__ __launch_bounds__(256) void csr_offsets_kernel(
    const int* __restrict__ bh, int* __restrict__ off, int* __restrict__ bktbase) {
    __shared__ int sc[256];
    int t = threadIdx.x;
    int sum = 0;
    if (t < NBKT)
        for (int b = 0; b < NBLK_S; ++b) sum += bh[b * NBKT + t];
    int v = sum;
    sc[t] = v; __syncthreads();
    for (int o = 1; o < 256; o <<= 1) {
        int add = (t >= o) ? sc[t - o] : 0; __syncthreads();
        sc[t] += add; __syncthreads();
    }
    int base = sc[t] - v;   // exclusive
    if (t < NBKT) {
        bktbase[t] = base;
        int run = base;
        for (int b = 0; b < NBLK_S; ++b) { off[b * NBKT + t] = run; run += bh[b * NBKT + t]; }
    }
    if (t == 0) bktbase[NBKT] = NEDGE;
}

__global__ __launch_bounds__(256) void csr_scatter_kernel(
    const int* __restrict__ key, const int* __restrict__ val, int shift,
    const int* __restrict__ off, int2* __restrict__ tmp) {
    __shared__ int cur[NBKT];
    int b = blockIdx.x, t = threadIdx.x;
    for (int i = t; i < NBKT; i += 256) cur[i] = off[b * NBKT + i];
    __syncthreads();
    int s = b * CHUNK;
    for (int i = t; i < CHUNK; i += 256) {
        int k = key[s + i], v = val[s + i];
        int p = atomicAdd(&cur[k >> shift], 1);
        tmp[p] = make_int2(k, v);
    }
}

__global__ __launch_bounds__(256) void csr_build_kernel(
    const int2* __restrict__ tmp, const int* __restrict__ bktbase, int rows_per_bkt,
    int nrows, int* __restrict__ row_ptr, float* __restrict__ inv, int* __restrict__ adj) {
    __shared__ int hist[4096];
    __shared__ int part[256];
    int k = blockIdx.x, t = threadIdx.x;
    int rowbase = k * rows_per_bkt;
    for (int i = t; i < rows_per_bkt; i += 256) hist[i] = 0;
    __syncthreads();
    int e0 = bktbase[k], e1 = bktbase[k + 1];
    for (int e = e0 + t; e < e1; e += 256) atomicAdd(&hist[tmp[e].x - rowbase], 1);
    __syncthreads();
    int per = rows_per_bkt >> 8;   // 16 (cls) or 4 (lit)
    int base_i = t * per;
    int vals[16];
    int s = 0;
    for (int i = 0; i < per; ++i) { vals[i] = hist[base_i + i]; s += vals[i]; }
    int v = s;
    part[t] = v; __syncthreads();
    for (int o = 1; o < 256; o <<= 1) {
        int add = (t >= o) ? part[t - o] : 0; __syncthreads();
        part[t] += add; __syncthreads();
    }
    int run = part[t] - v;
    for (int i = 0; i < per; ++i) { hist[base_i + i] = run; run += vals[i]; }
    __syncthreads();
    for (int i = t; i < rows_per_bkt; i += 256) {
        int row = rowbase + i;
        if (row < nrows) {
            int ex = hist[i];
            int nx = (i + 1 < rows_per_bkt) ? hist[i + 1] : (e1 - e0);
            row_ptr[row] = e0 + ex;
            int d = nx - ex;
            inv[row] = 1.0f / (float)(d > 0 ? d : 1);
        }
    }
    __syncthreads();
    for (int e = e0 + t; e < e1; e += 256) {
        int2 pr = tmp[e];
        int pos = atomicAdd(&hist[pr.x - rowbase], 1);
        adj[e0 + pos] = pr.y;
    }
}

__global__ void tail_kernel(int* __restrict__ rp_cls, int* __restrict__ rp_lit) {
    if (blockIdx.x == 0 && threadIdx.x == 0) {
        rp_cls[N_CLS] = NEDGE;
        rp_lit[N_LIT] = NEDGE;
    }
}

// ---------------------------------------------------------------- encoder (MFMA 2nd GEMM)
__global__ __launch_bounds__(256, 4) void encoder_kernel(
    const float* __restrict__ x_lit, const float* __restrict__ x_cls,
    const float* __restrict__ w1, const float* __restrict__ b1,
    const float* __restrict__ w2, const float* __restrict__ b2,
    float* __restrict__ h_lit, unsigned short* __restrict__ h_cls) {
    __shared__ float w1s[4 * 64];
    __shared__ float b1s[64], b2s[64];
    __shared__ __align__(16) unsigned short Bp[8 * 64 * 8];
    __shared__ float xt[4][64];
    __shared__ float hs[4][16 * 68];
    int t = threadIdx.x;
    w1s[t] = w1[t];
    if (t < 64) { b1s[t] = b1[t]; b2s[t] = b2[t]; }
    for (int idx = t; idx < 8 * 64 * 8; idx += 256) {
        int i = idx & 7, ln = (idx >> 3) & 63, fid = idx >> 9;
        int ks = fid >> 2, nt = fid & 3;
        Bp[idx] = f2bf(w2[(ks * 32 + ((ln >> 4) << 3) + i) * 64 + nt * 16 + (ln & 15)]);
    }
    __syncthreads();
    int w = t >> 6, lane = t & 63;
    int c = lane & 15, q = lane >> 4;
    bf16x8 Bf[8];
    #pragma unroll
    for (int f = 0; f < 8; ++f) Bf[f] = *(const bf16x8*)&Bp[(f * 64 + lane) * 8];
    float* hw = hs[w];
    int nwaves = gridDim.x * 4;
    int wid = blockIdx.x * 4 + w;
    const int ntiles = (N_LIT + N_CLS) / 16;
    for (int tile = wid; tile < ntiles; tile += nwaves) {
        int row0 = tile * 16;
        const float* xsrc = (row0 < N_LIT) ? x_lit + (size_t)row0 * 4
                                           : x_cls + (size_t)(row0 - N_LIT) * 4;
        xt[w][lane] = xsrc[lane];
        for (int r = 0; r < 16; ++r) {
            float pre = b1s[lane];
            #pragma unroll
            for (int k = 0; k < 4; ++k) pre += xt[w][r * 4 + k] * w1s[k * 64 + lane];
            hw[r * 68 + lane] = silu_f(pre);
        }
        bf16x8 A0, A1;
        const float* ap = &hw[c * 68 + q * 8];
        #pragma unroll
        for (int i = 0; i < 8; ++i) {
            A0[i] = (short)f2bf(ap[i]);
            A1[i] = (short)f2bf(ap[32 + i]);
        }
        f32x4 acc[4];
        #pragma unroll
        for (int nt = 0; nt < 4; ++nt) {
            float bv = b2s[nt * 16 + c];
            acc[nt] = (f32x4){bv, bv, bv, bv};
            acc[nt] = __builtin_amdgcn_mfma_f32_16x16x32_bf16(A0, Bf[nt], acc[nt], 0, 0, 0);
            acc[nt] = __builtin_amdgcn_mfma_f32_16x16x32_bf16(A1, Bf[4 + nt], acc[nt], 0, 0, 0);
        }
        #pragma unroll
        for (int nt = 0; nt < 4; ++nt)
            #pragma unroll
            for (int rg = 0; rg < 4; ++rg)
                hw[(q * 4 + rg) * 68 + nt * 16 + c] = acc[nt][rg];
        if (row0 < N_LIT) {
            for (int r = 0; r < 16; ++r)
                h_lit[(size_t)(row0 + r) * 64 + lane] = hw[r * 68 + lane];
        } else {
            for (int r = 0; r < 16; ++r)
                h_cls[(size_t)(row0 + r - N_LIT) * 64 + lane] = f2bf(hw[r * 68 + lane]);
        }
    }
}

// ---------------------------------------------------------------- X = h_lit @ Wc_bot (MFMA) — layer 0 only
__global__ __launch_bounds__(256, 4) void gemmX_kernel(
    const float* __restrict__ in, const float* __restrict__ W,
    unsigned short* __restrict__ out) {
    __shared__ __align__(16) unsigned short Bp[8 * 64 * 8];
    __shared__ float stage[4][16 * 66];
    int t = threadIdx.x;
    for (int idx = t; idx < 8 * 64 * 8; idx += 256) {
        int i = idx & 7, ln = (idx >> 3) & 63, fid = idx >> 9;
        int ks = fid >> 2, nt = fid & 3;
        Bp[idx] = f2bf(W[(ks * 32 + ((ln >> 4) << 3) + i) * 64 + nt * 16 + (ln & 15)]);
    }
    __syncthreads();
    int w = t >> 6, lane = t & 63;
    int c = lane & 15, q = lane >> 4;
    bf16x8 Bf[8];
    #pragma unroll
    for (int f = 0; f < 8; ++f) Bf[f] = *(const bf16x8*)&Bp[(f * 64 + lane) * 8];
    float* ms = stage[w];
    int nwaves = gridDim.x * 4;
    int wid = blockIdx.x * 4 + w;
    for (int tile = wid; tile < N_LIT / 16; tile += nwaves) {
        int row0 = tile * 16;
        const float* ap = in + (size_t)(row0 + c) * 64 + q * 8;
        bf16x8 A0, A1;
        #pragma unroll
        for (int i = 0; i < 8; ++i) {
            A0[i] = (short)f2bf(ap[i]);
            A1[i] = (short)f2bf(ap[32 + i]);
        }
        f32x4 acc[4];
        #pragma unroll
        for (int nt = 0; nt < 4; ++nt) {
            acc[nt] = (f32x4){0.f, 0.f, 0.f, 0.f};
            acc[nt] = __builtin_amdgcn_mfma_f32_16x16x32_bf16(A0, Bf[nt], acc[nt], 0, 0, 0);
            acc[nt] = __builtin_amdgcn_mfma_f32_16x16x32_bf16(A1, Bf[4 + nt], acc[nt], 0, 0, 0);
        }
        #pragma unroll
        for (int nt = 0; nt < 4; ++nt)
            #pragma unroll
            for (int rg = 0; rg < 4; ++rg)
                ms[(q * 4 + rg) * 66 + nt * 16 + c] = acc[nt][rg];
        for (int r = 0; r < 16; ++r)
            out[(size_t)(row0 + r) * 64 + lane] = f2bf(ms[r * 66 + lane]);
    }
}

// ---------------------------------------------------------------- clause update (MFMA + scalarized monotone gather)
// S_new[c] = silu((S[c] @ Wc_top + bc) + inv[c] * sum_e X[lit[e]])
// Gather uses readlane/readfirstlane to put lit indices and row bounds in
// SGPRs: addresses go SALU + saddr loads; boundary compares go scalar.
__global__ __launch_bounds__(256, 6) void cls_update_kernel(
    unsigned short* __restrict__ h_cls, const unsigned short* __restrict__ X,
    const int* __restrict__ rp, const int* __restrict__ lits,
    const float* __restrict__ inv_deg, const float* __restrict__ W,
    const float* __restrict__ b) {
    __shared__ __align__(16) unsigned short Bp[8 * 64 * 8];
    __shared__ float bs[64];
    __shared__ float stage[4][16 * 66];
    __shared__ int rps[4][17];
    __shared__ float invs[4][16];
    int t = threadIdx.x;
    for (int idx = t; idx < 8 * 64 * 8; idx += 256) {
        int i = idx & 7, ln = (idx >> 3) & 63, fid = idx >> 9;
        int ks = fid >> 2, nt = fid & 3;
        Bp[idx] = f2bf(W[(ks * 32 + ((ln >> 4) << 3) + i) * 64 + nt * 16 + (ln & 15)]);
    }
    if (t < 64) bs[t] = b[t];
    __syncthreads();
    int w = t >> 6, lane = t & 63;
    int c = lane & 15, q = lane >> 4;
    bf16x8 Bf[8];
    #pragma unroll
    for (int f = 0; f < 8; ++f) Bf[f] = *(const bf16x8*)&Bp[(f * 64 + lane) * 8];
    float* ms = stage[w];
    int* rpw = rps[w];
    float* ivw = invs[w];
    const unsigned short* Xl = X + lane;   // per-lane channel base; scalar row offset added per edge
    int nwaves = gridDim.x * 4;
    int wid = blockIdx.x * 4 + w;
    for (int tile = wid; tile < N_CLS / 16; tile += nwaves) {
        int row0 = tile * 16;
        const unsigned short* ap = h_cls + (size_t)(row0 + c) * 64 + q * 8;
        bf16x8 A0 = *(const bf16x8*)(ap);
        bf16x8 A1 = *(const bf16x8*)(ap + 32);
        f32x4 acc[4];
        #pragma unroll
        for (int nt = 0; nt < 4; ++nt) {
            float bv = bs[nt * 16 + c];
            acc[nt] = (f32x4){bv, bv, bv, bv};
            acc[nt] = __builtin_amdgcn_mfma_f32_16x16x32_bf16(A0, Bf[nt], acc[nt], 0, 0, 0);
            acc[nt] = __builtin_amdgcn_mfma_f32_16x16x32_bf16(A1, Bf[4 + nt], acc[nt], 0, 0, 0);
        }
        #pragma unroll
        for (int r2 = 0; r2 < 16; ++r2) ms[r2 * 66 + lane] = 0.f;
        if (lane < 17) rpw[lane] = rp[row0 + lane];
        if (lane < 16) ivw[lane] = inv_deg[row0 + lane];
        int E0 = __builtin_amdgcn_readfirstlane(rpw[0]);
        int E1 = __builtin_amdgcn_readfirstlane(rpw[16]);
        int r = 0;
        int endr = __builtin_amdgcn_readfirstlane(rpw[1]);
        float racc = 0.f;
        for (int base = E0; base < E1; base += 64) {
            int n = E1 - base; if (n > 64) n = 64;
            int myLit = (lane < n) ? lits[base + lane] : 0;
            int i = 0;
            for (; i + 7 < n; i += 8) {
                float v[8];
                #pragma unroll
                for (int k = 0; k < 8; ++k) {
                    int lit = __builtin_amdgcn_readlane(myLit, i + k);
                    v[k] = bf2f(Xl[(size_t)lit * 64]);
                }
                #pragma unroll
                for (int k = 0; k < 8; ++k) {
                    int g = base + i + k;
                    while (g >= endr) {
                        ms[r * 66 + lane] = racc * ivw[r];
                        racc = 0.f; ++r;
                        endr = __builtin_amdgcn_readfirstlane(rpw[r + 1]);
                    }
                    racc += v[k];
                }
            }
            for (; i < n; ++i) {
                int lit = __builtin_amdgcn_readlane(myLit, i);
                float v0 = bf2f(Xl[(size_t)lit * 64]);
                int g = base + i;
                while (g >= endr) {
                    ms[r * 66 + lane] = racc * ivw[r];
                    racc = 0.f; ++r;
                    endr = __builtin_amdgcn_readfirstlane(rpw[r + 1]);
                }
                racc += v0;
            }
        }
        if (E1 > E0) ms[r * 66 + lane] = racc * ivw[r];
        #pragma unroll
        for (int nt = 0; nt < 4; ++nt)
            #pragma unroll
            for (int rg = 0; rg < 4; ++rg)
                ms[(q * 4 + rg) * 66 + nt * 16 + c] += acc[nt][rg];
        for (int rr = 0; rr < 16; ++rr)
            h_cls[(size_t)(row0 + rr) * 64 + lane] = f2bf(silu_f(ms[rr * 66 + lane]));
    }
}

// ---------------------------------------------------------------- lit-side gather (scalarized indices, 4-way MLP)
__global__ __launch_bounds__(256, 8) void gather_lit_kernel(
    const unsigned short* __restrict__ S, const int* __restrict__ rp,
    const int* __restrict__ clss, const float* __restrict__ inv_deg,
    unsigned short* __restrict__ m_out) {
    int nw = (gridDim.x * blockDim.x) >> 6;
    int wid = (blockIdx.x * blockDim.x + threadIdx.x) >> 6;
    int lane = threadIdx.x & 63;
    const unsigned short* Sl = S + lane;
    for (int row = wid; row < N_LIT; row += nw) {
        int e0 = __builtin_amdgcn_readfirstlane(rp[row]);
        int e1 = __builtin_amdgcn_readfirstlane(rp[row + 1]);
        float g0 = 0.f, g1 = 0.f, g2 = 0.f, g3 = 0.f;
        for (int base = e0; base < e1; base += 64) {
            int n = e1 - base; if (n > 64) n = 64;
            int myCls = (lane < n) ? clss[base + lane] : 0;
            int i = 0;
            for (; i + 3 < n; i += 4) {
                int c0 = __builtin_amdgcn_readlane(myCls, i);
                int c1 = __builtin_amdgcn_readlane(myCls, i + 1);
                int c2 = __builtin_amdgcn_readlane(myCls, i + 2);
                int c3 = __builtin_amdgcn_readlane(myCls, i + 3);
                g0 += bf2f(Sl[(size_t)c0 * 64]);
                g1 += bf2f(Sl[(size_t)c1 * 64]);
                g2 += bf2f(Sl[(size_t)c2 * 64]);
                g3 += bf2f(Sl[(size_t)c3 * 64]);
            }
            for (; i < n; ++i) {
                int c0 = __builtin_amdgcn_readlane(myCls, i);
                g0 += bf2f(Sl[(size_t)c0 * 64]);
            }
        }
        m_out[(size_t)row * 64 + lane] = f2bf(((g0 + g1) + (g2 + g3)) * inv_deg[row]);
    }
}

// ---------------------------------------------------------------- literal update (MFMA, in-place fp32, + fused next-layer X)
__global__ __launch_bounds__(256, 3) void lit_update_kernel(
    float* __restrict__ h, const unsigned short* __restrict__ m,
    const float* __restrict__ W, const float* __restrict__ b,
    const float* __restrict__ Wc_next, unsigned short* __restrict__ Xout) {
    __shared__ __align__(16) unsigned short Bp[24 * 64 * 8];
    __shared__ __align__(16) unsigned short Bp2[8 * 64 * 8];
    __shared__ float bs[64];
    __shared__ float stage[4][16 * 66];
    int t = threadIdx.x;
    for (int idx = t; idx < 24 * 64 * 8; idx += 256) {
        int i = idx & 7, ln = (idx >> 3) & 63, fid = idx >> 9;
        int ks = fid >> 2, nt = fid & 3;
        Bp[idx] = f2bf(W[(ks * 32 + ((ln >> 4) << 3) + i) * 64 + nt * 16 + (ln & 15)]);
    }
    if (Wc_next) {
        for (int idx = t; idx < 8 * 64 * 8; idx += 256) {
            int i = idx & 7, ln = (idx >> 3) & 63, fid = idx >> 9;
            int ks = fid >> 2, nt = fid & 3;
            Bp2[idx] = f2bf(Wc_next[(ks * 32 + ((ln >> 4) << 3) + i) * 64 + nt * 16 + (ln & 15)]);
        }
    }
    if (t < 64) bs[t] = b[t];
    __syncthreads();
    int w = t >> 6, lane = t & 63;
    int c = lane & 15, q = lane >> 4;
    bf16x8 Bf[24];
    #pragma unroll
    for (int f = 0; f < 24; ++f) Bf[f] = *(const bf16x8*)&Bp[(f * 64 + lane) * 8];
    float* ms = stage[w];
    int nwaves = gridDim.x * 4;
    int wid = blockIdx.x * 4 + w;
    for (int tile = wid; tile < N_LIT / 16; tile += nwaves) {
        int row0 = tile * 16;
        bf16x8 A[6];
        const float* hp = h + (size_t)(row0 + c) * 64 + q * 8;
        const float* hf = h + (size_t)((row0 + c) ^ 1) * 64 + q * 8;
        const unsigned short* mp = m + (size_t)(row0 + c) * 64 + q * 8;
        #pragma unroll
        for (int i = 0; i < 8; ++i) {
            A[0][i] = (short)f2bf(hp[i]);
            A[1][i] = (short)f2bf(hp[32 + i]);
            A[4][i] = (short)f2bf(hf[i]);
            A[5][i] = (short)f2bf(hf[32 + i]);
        }
        A[2] = *(const bf16x8*)(mp);
        A[3] = *(const bf16x8*)(mp + 32);
        f32x4 acc[4];
        #pragma unroll
        for (int nt = 0; nt < 4; ++nt) {
            float bv = bs[nt * 16 + c];
            acc[nt] = (f32x4){bv, bv, bv, bv};
            #pragma unroll
            for (int ks = 0; ks < 6; ++ks)
                acc[nt] = __builtin_amdgcn_mfma_f32_16x16x32_bf16(A[ks], Bf[ks * 4 + nt], acc[nt], 0, 0, 0);
        }
        #pragma unroll
        for (int nt = 0; nt < 4; ++nt)
            #pragma unroll
            for (int rg = 0; rg < 4; ++rg)
                ms[(q * 4 + rg) * 66 + nt * 16 + c] = silu_f(acc[nt][rg]);
        for (int r = 0; r < 16; ++r)
            h[(size_t)(row0 + r) * 64 + lane] = ms[r * 66 + lane];
        if (Wc_next) {
            bf16x8 NA0, NA1;
            const float* np = &ms[c * 66 + q * 8];
            #pragma unroll
            for (int i = 0; i < 8; ++i) {
                NA0[i] = (short)f2bf(np[i]);
                NA1[i] = (short)f2bf(np[32 + i]);
            }
            f32x4 xacc[4];
            #pragma unroll
            for (int nt = 0; nt < 4; ++nt) {
                xacc[nt] = (f32x4){0.f, 0.f, 0.f, 0.f};
                bf16x8 B0 = *(const bf16x8*)&Bp2[(nt * 64 + lane) * 8];
                xacc[nt] = __builtin_amdgcn_mfma_f32_16x16x32_bf16(NA0, B0, xacc[nt], 0, 0, 0);
                bf16x8 B1 = *(const bf16x8*)&Bp2[((4 + nt) * 64 + lane) * 8];
                xacc[nt] = __builtin_amdgcn_mfma_f32_16x16x32_bf16(NA1, B1, xacc[nt], 0, 0, 0);
            }
            #pragma unroll
            for (int nt = 0; nt < 4; ++nt)
                #pragma unroll
                for (int rg = 0; rg < 4; ++rg)
                    ms[(q * 4 + rg) * 66 + nt * 16 + c] = xacc[nt][rg];
            for (int r = 0; r < 16; ++r)
                Xout[(size_t)(row0 + r) * 64 + lane] = f2bf(ms[r * 66 + lane]);
        }
    }
}

// ---------------------------------------------------------------- readout stage 1 (fp32 VALU -> bf16 hid)
__global__ __launch_bounds__(256) void var_hidden_kernel(
    const float* __restrict__ h_var, const float* __restrict__ W,
    const float* __restrict__ b, int colofs, unsigned short* __restrict__ hid) {
    __shared__ float Ws[128 * 64];
    __shared__ float bs[64];
    __shared__ float rs[16 * 128];
    int t = threadIdx.x;
    for (int i = t; i < 128 * 64; i += 256) {
        int k = i >> 6, j = i & 63;
        Ws[i] = W[k * 128 + colofs + j];
    }
    if (t < 64) bs[t] = b[colofs + t];
    __syncthreads();
    const int ntiles = NVAR / 16;
    int w = t >> 6, j = t & 63;
    for (int tile = blockIdx.x; tile < ntiles; tile += gridDim.x) {
        int row0 = tile * 16;
        for (int i = t; i < 2048; i += 256) rs[i] = h_var[(size_t)row0 * 128 + i];
        __syncthreads();
        float acc0 = bs[j], acc1 = bs[j], acc2 = bs[j], acc3 = bs[j];
        const float* r0 = &rs[(w * 4 + 0) * 128];
        const float* r1 = &rs[(w * 4 + 1) * 128];
        const float* r2 = &rs[(w * 4 + 2) * 128];
        const float* r3 = &rs[(w * 4 + 3) * 128];
        #pragma unroll 4
        for (int k = 0; k < 128; k += 4) {
            float w0 = Ws[k * 64 + j], w1v = Ws[(k + 1) * 64 + j];
            float w2v = Ws[(k + 2) * 64 + j], w3v = Ws[(k + 3) * 64 + j];
            float4 a;
            a = *(const float4*)(r0 + k); acc0 += a.x * w0 + a.y * w1v + a.z * w2v + a.w * w3v;
            a = *(const float4*)(r1 + k); acc1 += a.x * w0 + a.y * w1v + a.z * w2v + a.w * w3v;
            a = *(const float4*)(r2 + k); acc2 += a.x * w0 + a.y * w1v + a.z * w2v + a.w * w3v;
            a = *(const float4*)(r3 + k); acc3 += a.x * w0 + a.y * w1v + a.z * w2v + a.w * w3v;
        }
        int row = row0 + w * 4;
        hid[(size_t)(row + 0) * 128 + colofs + j] = f2bf(silu_f(acc0));
        hid[(size_t)(row + 1) * 128 + colofs + j] = f2bf(silu_f(acc1));
        hid[(size_t)(row + 2) * 128 + colofs + j] = f2bf(silu_f(acc2));
        hid[(size_t)(row + 3) * 128 + colofs + j] = f2bf(silu_f(acc3));
        __syncthreads();
    }
}

// ---------------------------------------------------------------- readout stage 2
__global__ __launch_bounds__(256) void out2_kernel(
    const unsigned short* __restrict__ hid, const float* __restrict__ w2,
    const float* __restrict__ b2, float* __restrict__ out) {
    int nw = (gridDim.x * blockDim.x) >> 6;
    int wid = (blockIdx.x * blockDim.x + threadIdx.x) >> 6;
    int lane = threadIdx.x & 63;
    float w00 = w2[lane * 2 + 0], w01 = w2[lane * 2 + 1];
    float w10 = w2[(lane + 64) * 2 + 0], w11 = w2[(lane + 64) * 2 + 1];
    for (int row = wid; row < NVAR; row += nw) {
        float h0 = bf2f(hid[(size_t)row * 128 + lane]);
        float h1 = bf2f(hid[(size_t)row * 128 + 64 + lane]);
        float p0 = h0 * w00 + h1 * w10;
        float p1 = h0 * w01 + h1 * w11;
        #pragma unroll
        for (int off = 32; off > 0; off >>= 1) {
            p0 += __shfl_down(p0, off);
            p1 += __shfl_down(p1, off);
        }
        if (lane == 0) {
            out[(size_t)row * 2 + 0] = p0 + b2[0];
            out[(size_t)row * 2 + 1] = p1 + b2[1];
        }
    }
}

// ---------------------------------------------------------------- launch
extern "C" void kernel_launch(void* const* d_in, const int* in_sizes, int n_in,
                              void* d_out, int out_size, void* d_ws, size_t ws_size,
                              hipStream_t stream) {
    const float* x_lit  = (const float*)d_in[0];
    const float* x_cls  = (const float*)d_in[1];
    const int* edge_lit = (const int*)d_in[2];
    const int* edge_cls = (const int*)d_in[3];
    const float* enc_w1 = (const float*)d_in[4];
    const float* enc_b1 = (const float*)d_in[5];
    const float* enc_w2 = (const float*)d_in[6];
    const float* enc_b2 = (const float*)d_in[7];
    const float* Wc     = (const float*)d_in[8];    // [4][128][64]
    const float* bc     = (const float*)d_in[9];
    const float* Wl     = (const float*)d_in[10];   // [4][192][64]
    const float* bl     = (const float*)d_in[11];
    const float* out_w1 = (const float*)d_in[12];   // [128][128]
    const float* out_b1 = (const float*)d_in[13];
    const float* out_w2 = (const float*)d_in[14];   // [128][2]
    const float* out_b2 = (const float*)d_in[15];
    float* y = (float*)d_out;

    // ---- workspace carve (~208 MB) ----
    const size_t SZ_HLIT = (size_t)N_LIT * 64;
    const size_t SZ_HCLS = (size_t)N_CLS * 64;
    char* p = (char*)d_ws;
    auto take = [&](size_t bytes) -> char* {
        char* r = p; p += (bytes + 255) & ~(size_t)255; return r;
    };
    float*          h_lit      = (float*)take(SZ_HLIT * 4);
    unsigned short* h_cls      = (unsigned short*)take(SZ_HCLS * 2);
    unsigned short* X          = (unsigned short*)take(SZ_HLIT * 2);
    float*          inv_cls    = (float*)take((size_t)N_CLS * 4);
    float*          inv_lit    = (float*)take((size_t)N_LIT * 4);
    int*            row_ptr_cls= (int*)take((size_t)(N_CLS + 1) * 4);
    int*            row_ptr_lit= (int*)take((size_t)(N_LIT + 1) * 4);
    int*            lit_by_cls = (int*)take((size_t)NEDGE * 4);
    int*            cls_by_lit = (int*)take((size_t)NEDGE * 4);
    int*            bh         = (int*)take((size_t)NBLK_S * NBKT * 4);
    int*            off        = (int*)take((size_t)NBLK_S * NBKT * 4);
    int*            bktbase    = (int*)take((size_t)(NBKT + 1) * 4);
    size_t need = (size_t)(p - (char*)d_ws);

    // pair buffer aliases h_lit (dead until encoder): 19.2 MB <= 51.2 MB
    int2* tmp_pairs = (int2*)h_lit;

    dim3 B(256);

    if (ws_size < need) {
        float mb = (float)((double)ws_size / (1024.0 * 1024.0));
        diag_kernel<<<256, B, 0, stream>>>(y, out_size, mb);
        return;
    }

    // ---- CSR build (radix partition) ----
    csr_hist_kernel<<<NBLK_S, B, 0, stream>>>(edge_cls, 12, bh);
    csr_offsets_kernel<<<1, B, 0, stream>>>(bh, off, bktbase);
    csr_scatter_kernel<<<NBLK_S, B, 0, stream>>>(edge_cls, edge_lit, 12, off, tmp_pairs);
    csr_build_kernel<<<NBKT, B, 0, stream>>>(tmp_pairs, bktbase, 4096, N_CLS,
                                             row_ptr_cls, inv_cls, lit_by_cls);
    csr_hist_kernel<<<NBLK_S, B, 0, stream>>>(edge_lit, 10, bh);
    csr_offsets_kernel<<<1, B, 0, stream>>>(bh, off, bktbase);
    csr_scatter_kernel<<<NBLK_S, B, 0, stream>>>(edge_lit, edge_cls, 10, off, tmp_pairs);
    csr_build_kernel<<<NBKT, B, 0, stream>>>(tmp_pairs, bktbase, 1024, N_LIT,
                                             row_ptr_lit, inv_lit, cls_by_lit);
    tail_kernel<<<1, 64, 0, stream>>>(row_ptr_cls, row_ptr_lit);

    // ---- encoder (overwrites tmp_pairs alias region) ----
    encoder_kernel<<<2048, B, 0, stream>>>(x_lit, x_cls, enc_w1, enc_b1, enc_w2, enc_b2,
                                           h_lit, h_cls);

    // layer-0 X; layers 1..3 get X from lit_update's fused epilogue
    gemmX_kernel<<<1024, B, 0, stream>>>(h_lit, Wc + 64 * 64, X);

    for (int l = 0; l < 4; ++l) {
        const float* Wl_l = Wl + (size_t)l * 192 * 64;
        const float* Wc_next = (l < 3) ? (Wc + (size_t)(l + 1) * 128 * 64 + 64 * 64) : nullptr;
        cls_update_kernel<<<2048, B, 0, stream>>>(h_cls, X, row_ptr_cls, lit_by_cls,
                                                  inv_cls, Wc + (size_t)l * 128 * 64,
                                                  bc + l * 64);
        gather_lit_kernel<<<4096, B, 0, stream>>>(h_cls, row_ptr_lit, cls_by_lit,
                                                  inv_lit, X);
        lit_update_kernel<<<1024, B, 0, stream>>>(h_lit, X, Wl_l, bl + l * 64,
                                                  Wc_next, X);
    }

    // ---- readout ----
    var_hidden_kernel<<<4096, B, 0, stream>>>(h_lit, out_w1, out_b1, 0, X);
    var_hidden_kernel<<<4096, B, 0, stream>>>(h_lit, out_w1, out_b1, 64, X);
    out2_kernel<<<2048, B, 0, stream>>>(X, out_w2, out_b2, y);
}

// Round 12
// 1585.417 us; speedup vs baseline: 2.5417x; 1.0603x over previous
//
#include <hip/hip_runtime.h>
#include <math.h>

#define N_LIT 200000
#define N_CLS 800000
#define NEDGE 2400000
#define NVAR  (N_LIT / 2)

// CSR radix-partition parameters: 200 chunks x 12000 edges = NEDGE exactly; 196 buckets
#define NBLK_S 200
#define CHUNK  12000
#define NBKT   196

typedef __attribute__((ext_vector_type(8))) short bf16x8;
typedef __attribute__((ext_vector_type(4))) float f32x4;

__device__ __forceinline__ float silu_f(float x) { return x / (1.0f + expf(-x)); }

__device__ __forceinline__ float bf2f(unsigned short u) {
    unsigned int x = ((unsigned int)u) << 16;
    return __uint_as_float(x);
}
__device__ __forceinline__ unsigned short f2bf(float f) {
    unsigned int x = __float_as_uint(f);
    unsigned int r = (x + 0x7fffu + ((x >> 16) & 1u)) >> 16;
    return (unsigned short)r;
}

// ---------------------------------------------------------------- diagnostics
__global__ void diag_kernel(float* __restrict__ out, int n, float val) {
    int i = blockIdx.x * blockDim.x + threadIdx.x;
    int stride = gridDim.x * blockDim.x;
    for (; i < n; i += stride) out[i] = val;
}

// ---------------------------------------------------------------- CSR build: radix partition
__global__ __launch_bounds__(256) void csr_hist_kernel(
    const int* __restrict__ key, int shift, int* __restrict__ bh) {
    __shared__ int h[NBKT];
    int b = blockIdx.x, t = threadIdx.x;
    for (int i = t; i < NBKT; i += 256) h[i] = 0;
    __syncthreads();
    int s = b * CHUNK;
    for (int i = t; i < CHUNK; i += 256) atomicAdd(&h[key[s + i] >> shift], 1);
    __syncthreads();
    for (int i = t; i < NBKT; i += 256) bh[b * NBKT + i] = h[i];
}

__global__ __launch_bounds__(256) void csr_offsets_kernel(
    const int* __restrict__ bh, int* __restrict__ off, int* __restrict__ bktbase) {
    __shared__ int sc[256];
    int t = threadIdx.x;
    int sum = 0;
    if (t < NBKT)
        for (int b = 0; b < NBLK_S; ++b) sum += bh[b * NBKT + t];
    int v = sum;
    sc[t] = v; __syncthreads();
    for (int o = 1; o < 256; o <<= 1) {
        int add = (t >= o) ? sc[t - o] : 0; __syncthreads();
        sc[t] += add; __syncthreads();
    }
    int base = sc[t] - v;   // exclusive
    if (t < NBKT) {
        bktbase[t] = base;
        int run = base;
        for (int b = 0; b < NBLK_S; ++b) { off[b * NBKT + t] = run; run += bh[b * NBKT + t]; }
    }
    if (t == 0) bktbase[NBKT] = NEDGE;
}

__global__ __launch_bounds__(256) void csr_scatter_kernel(
    const int* __restrict__ key, const int* __restrict__ val, int shift,
    const int* __restrict__ off, int2* __restrict__ tmp) {
    __shared__ int cur[NBKT];
    int b = blockIdx.x, t = threadIdx.x;
    for (int i = t; i < NBKT; i += 256) cur[i] = off[b * NBKT + i];
    __syncthreads();
    int s = b * CHUNK;
    for (int i = t; i < CHUNK; i += 256) {
        int k = key[s + i], v = val[s + i];
        int p = atomicAdd(&cur[k >> shift], 1);
        tmp[p] = make_int2(k, v);
    }
}

__global__ __launch_bounds__(256) void csr_build_kernel(
    const int2* __restrict__ tmp, const int* __restrict__ bktbase, int rows_per_bkt,
    int nrows, int* __restrict__ row_ptr, float* __restrict__ inv, int* __restrict__ adj) {
    __shared__ int hist[4096];
    __shared__ int part[256];
    int k = blockIdx.x, t = threadIdx.x;
    int rowbase = k * rows_per_bkt;
    for (int i = t; i < rows_per_bkt; i += 256) hist[i] = 0;
    __syncthreads();
    int e0 = bktbase[k], e1 = bktbase[k + 1];
    for (int e = e0 + t; e < e1; e += 256) atomicAdd(&hist[tmp[e].x - rowbase], 1);
    __syncthreads();
    int per = rows_per_bkt >> 8;   // 16 (cls) or 4 (lit)
    int base_i = t * per;
    int vals[16];
    int s = 0;
    for (int i = 0; i < per; ++i) { vals[i] = hist[base_i + i]; s += vals[i]; }
    int v = s;
    part[t] = v; __syncthreads();
    for (int o = 1; o < 256; o <<= 1) {
        int add = (t >= o) ? part[t - o] : 0; __syncthreads();
        part[t] += add; __syncthreads();
    }
    int run = part[t] - v;
    for (int i = 0; i < per; ++i) { hist[base_i + i] = run; run += vals[i]; }
    __syncthreads();
    for (int i = t; i < rows_per_bkt; i += 256) {
        int row = rowbase + i;
        if (row < nrows) {
            int ex = hist[i];
            int nx = (i + 1 < rows_per_bkt) ? hist[i + 1] : (e1 - e0);
            row_ptr[row] = e0 + ex;
            int d = nx - ex;
            inv[row] = 1.0f / (float)(d > 0 ? d : 1);
        }
    }
    __syncthreads();
    for (int e = e0 + t; e < e1; e += 256) {
        int2 pr = tmp[e];
        int pos = atomicAdd(&hist[pr.x - rowbase], 1);
        adj[e0 + pos] = pr.y;
    }
}

__global__ void tail_kernel(int* __restrict__ rp_cls, int* __restrict__ rp_lit) {
    if (blockIdx.x == 0 && threadIdx.x == 0) {
        rp_cls[N_CLS] = NEDGE;
        rp_lit[N_LIT] = NEDGE;
    }
}

// ---------------------------------------------------------------- encoder (MFMA 2nd GEMM)
__global__ __launch_bounds__(256, 4) void encoder_kernel(
    const float* __restrict__ x_lit, const float* __restrict__ x_cls,
    const float* __restrict__ w1, const float* __restrict__ b1,
    const float* __restrict__ w2, const float* __restrict__ b2,
    float* __restrict__ h_lit, unsigned short* __restrict__ h_cls) {
    __shared__ float w1s[4 * 64];
    __shared__ float b1s[64], b2s[64];
    __shared__ __align__(16) unsigned short Bp[8 * 64 * 8];
    __shared__ float xt[4][64];
    __shared__ float hs[4][16 * 68];
    int t = threadIdx.x;
    w1s[t] = w1[t];
    if (t < 64) { b1s[t] = b1[t]; b2s[t] = b2[t]; }
    for (int idx = t; idx < 8 * 64 * 8; idx += 256) {
        int i = idx & 7, ln = (idx >> 3) & 63, fid = idx >> 9;
        int ks = fid >> 2, nt = fid & 3;
        Bp[idx] = f2bf(w2[(ks * 32 + ((ln >> 4) << 3) + i) * 64 + nt * 16 + (ln & 15)]);
    }
    __syncthreads();
    int w = t >> 6, lane = t & 63;
    int c = lane & 15, q = lane >> 4;
    bf16x8 Bf[8];
    #pragma unroll
    for (int f = 0; f < 8; ++f) Bf[f] = *(const bf16x8*)&Bp[(f * 64 + lane) * 8];
    float* hw = hs[w];
    int nwaves = gridDim.x * 4;
    int wid = blockIdx.x * 4 + w;
    const int ntiles = (N_LIT + N_CLS) / 16;
    for (int tile = wid; tile < ntiles; tile += nwaves) {
        int row0 = tile * 16;
        const float* xsrc = (row0 < N_LIT) ? x_lit + (size_t)row0 * 4
                                           : x_cls + (size_t)(row0 - N_LIT) * 4;
        xt[w][lane] = xsrc[lane];
        for (int r = 0; r < 16; ++r) {
            float pre = b1s[lane];
            #pragma unroll
            for (int k = 0; k < 4; ++k) pre += xt[w][r * 4 + k] * w1s[k * 64 + lane];
            hw[r * 68 + lane] = silu_f(pre);
        }
        bf16x8 A0, A1;
        const float* ap = &hw[c * 68 + q * 8];
        #pragma unroll
        for (int i = 0; i < 8; ++i) {
            A0[i] = (short)f2bf(ap[i]);
            A1[i] = (short)f2bf(ap[32 + i]);
        }
        f32x4 acc[4];
        #pragma unroll
        for (int nt = 0; nt < 4; ++nt) {
            float bv = b2s[nt * 16 + c];
            acc[nt] = (f32x4){bv, bv, bv, bv};
            acc[nt] = __builtin_amdgcn_mfma_f32_16x16x32_bf16(A0, Bf[nt], acc[nt], 0, 0, 0);
            acc[nt] = __builtin_amdgcn_mfma_f32_16x16x32_bf16(A1, Bf[4 + nt], acc[nt], 0, 0, 0);
        }
        #pragma unroll
        for (int nt = 0; nt < 4; ++nt)
            #pragma unroll
            for (int rg = 0; rg < 4; ++rg)
                hw[(q * 4 + rg) * 68 + nt * 16 + c] = acc[nt][rg];
        if (row0 < N_LIT) {
            for (int r = 0; r < 16; ++r)
                h_lit[(size_t)(row0 + r) * 64 + lane] = hw[r * 68 + lane];
        } else {
            for (int r = 0; r < 16; ++r)
                h_cls[(size_t)(row0 + r - N_LIT) * 64 + lane] = f2bf(hw[r * 68 + lane]);
        }
    }
}

// ---------------------------------------------------------------- X = h_lit @ Wc_bot (MFMA) — layer 0 only
__global__ __launch_bounds__(256, 4) void gemmX_kernel(
    const float* __restrict__ in, const float* __restrict__ W,
    unsigned short* __restrict__ out) {
    __shared__ __align__(16) unsigned short Bp[8 * 64 * 8];
    __shared__ float stage[4][16 * 66];
    int t = threadIdx.x;
    for (int idx = t; idx < 8 * 64 * 8; idx += 256) {
        int i = idx & 7, ln = (idx >> 3) & 63, fid = idx >> 9;
        int ks = fid >> 2, nt = fid & 3;
        Bp[idx] = f2bf(W[(ks * 32 + ((ln >> 4) << 3) + i) * 64 + nt * 16 + (ln & 15)]);
    }
    __syncthreads();
    int w = t >> 6, lane = t & 63;
    int c = lane & 15, q = lane >> 4;
    bf16x8 Bf[8];
    #pragma unroll
    for (int f = 0; f < 8; ++f) Bf[f] = *(const bf16x8*)&Bp[(f * 64 + lane) * 8];
    float* ms = stage[w];
    int nwaves = gridDim.x * 4;
    int wid = blockIdx.x * 4 + w;
    for (int tile = wid; tile < N_LIT / 16; tile += nwaves) {
        int row0 = tile * 16;
        const float* ap = in + (size_t)(row0 + c) * 64 + q * 8;
        bf16x8 A0, A1;
        #pragma unroll
        for (int i = 0; i < 8; ++i) {
            A0[i] = (short)f2bf(ap[i]);
            A1[i] = (short)f2bf(ap[32 + i]);
        }
        f32x4 acc[4];
        #pragma unroll
        for (int nt = 0; nt < 4; ++nt) {
            acc[nt] = (f32x4){0.f, 0.f, 0.f, 0.f};
            acc[nt] = __builtin_amdgcn_mfma_f32_16x16x32_bf16(A0, Bf[nt], acc[nt], 0, 0, 0);
            acc[nt] = __builtin_amdgcn_mfma_f32_16x16x32_bf16(A1, Bf[4 + nt], acc[nt], 0, 0, 0);
        }
        #pragma unroll
        for (int nt = 0; nt < 4; ++nt)
            #pragma unroll
            for (int rg = 0; rg < 4; ++rg)
                ms[(q * 4 + rg) * 66 + nt * 16 + c] = acc[nt][rg];
        for (int r = 0; r < 16; ++r)
            out[(size_t)(row0 + r) * 64 + lane] = f2bf(ms[r * 66 + lane]);
    }
}

// ---------------------------------------------------------------- clause update (MFMA + scalarized monotone gather, 16-deep MLP)
// S_new[c] = silu((S[c] @ Wc_top + bc) + inv[c] * sum_e X[lit[e]])
__global__ __launch_bounds__(256, 6) void cls_update_kernel(
    unsigned short* __restrict__ h_cls, const unsigned short* __restrict__ X,
    const int* __restrict__ rp, const int* __restrict__ lits,
    const float* __restrict__ inv_deg, const float* __restrict__ W,
    const float* __restrict__ b) {
    __shared__ __align__(16) unsigned short Bp[8 * 64 * 8];
    __shared__ float bs[64];
    __shared__ float stage[4][16 * 66];
    __shared__ int rps[4][17];
    __shared__ float invs[4][16];
    int t = threadIdx.x;
    for (int idx = t; idx < 8 * 64 * 8; idx += 256) {
        int i = idx & 7, ln = (idx >> 3) & 63, fid = idx >> 9;
        int ks = fid >> 2, nt = fid & 3;
        Bp[idx] = f2bf(W[(ks * 32 + ((ln >> 4) << 3) + i) * 64 + nt * 16 + (ln & 15)]);
    }
    if (t < 64) bs[t] = b[t];
    __syncthreads();
    int w = t >> 6, lane = t & 63;
    int c = lane & 15, q = lane >> 4;
    bf16x8 Bf[8];
    #pragma unroll
    for (int f = 0; f < 8; ++f) Bf[f] = *(const bf16x8*)&Bp[(f * 64 + lane) * 8];
    float* ms = stage[w];
    int* rpw = rps[w];
    float* ivw = invs[w];
    const unsigned short* Xl = X + lane;
    int nwaves = gridDim.x * 4;
    int wid = blockIdx.x * 4 + w;
    for (int tile = wid; tile < N_CLS / 16; tile += nwaves) {
        int row0 = tile * 16;
        const unsigned short* ap = h_cls + (size_t)(row0 + c) * 64 + q * 8;
        bf16x8 A0 = *(const bf16x8*)(ap);
        bf16x8 A1 = *(const bf16x8*)(ap + 32);
        f32x4 acc[4];
        #pragma unroll
        for (int nt = 0; nt < 4; ++nt) {
            float bv = bs[nt * 16 + c];
            acc[nt] = (f32x4){bv, bv, bv, bv};
            acc[nt] = __builtin_amdgcn_mfma_f32_16x16x32_bf16(A0, Bf[nt], acc[nt], 0, 0, 0);
            acc[nt] = __builtin_amdgcn_mfma_f32_16x16x32_bf16(A1, Bf[4 + nt], acc[nt], 0, 0, 0);
        }
        #pragma unroll
        for (int r2 = 0; r2 < 16; ++r2) ms[r2 * 66 + lane] = 0.f;
        if (lane < 17) rpw[lane] = rp[row0 + lane];
        if (lane < 16) ivw[lane] = inv_deg[row0 + lane];
        int E0 = __builtin_amdgcn_readfirstlane(rpw[0]);
        int E1 = __builtin_amdgcn_readfirstlane(rpw[16]);
        int r = 0;
        int endr = __builtin_amdgcn_readfirstlane(rpw[1]);
        float racc = 0.f;
        for (int base = E0; base < E1; base += 64) {
            int n = E1 - base; if (n > 64) n = 64;
            int myLit = (lane < n) ? lits[base + lane] : 0;
            int i = 0;
            for (; i + 15 < n; i += 16) {
                float v[16];
                #pragma unroll
                for (int k = 0; k < 16; ++k) {
                    int lit = __builtin_amdgcn_readlane(myLit, i + k);
                    v[k] = bf2f(Xl[(size_t)lit * 64]);
                }
                #pragma unroll
                for (int k = 0; k < 16; ++k) {
                    int g = base + i + k;
                    while (g >= endr) {
                        ms[r * 66 + lane] = racc * ivw[r];
                        racc = 0.f; ++r;
                        endr = __builtin_amdgcn_readfirstlane(rpw[r + 1]);
                    }
                    racc += v[k];
                }
            }
            for (; i + 7 < n; i += 8) {
                float v[8];
                #pragma unroll
                for (int k = 0; k < 8; ++k) {
                    int lit = __builtin_amdgcn_readlane(myLit, i + k);
                    v[k] = bf2f(Xl[(size_t)lit * 64]);
                }
                #pragma unroll
                for (int k = 0; k < 8; ++k) {
                    int g = base + i + k;
                    while (g >= endr) {
                        ms[r * 66 + lane] = racc * ivw[r];
                        racc = 0.f; ++r;
                        endr = __builtin_amdgcn_readfirstlane(rpw[r + 1]);
                    }
                    racc += v[k];
                }
            }
            for (; i < n; ++i) {
                int lit = __builtin_amdgcn_readlane(myLit, i);
                float v0 = bf2f(Xl[(size_t)lit * 64]);
                int g = base + i;
                while (g >= endr) {
                    ms[r * 66 + lane] = racc * ivw[r];
                    racc = 0.f; ++r;
                    endr = __builtin_amdgcn_readfirstlane(rpw[r + 1]);
                }
                racc += v0;
            }
        }
        if (E1 > E0) ms[r * 66 + lane] = racc * ivw[r];
        #pragma unroll
        for (int nt = 0; nt < 4; ++nt)
            #pragma unroll
            for (int rg = 0; rg < 4; ++rg)
                ms[(q * 4 + rg) * 66 + nt * 16 + c] += acc[nt][rg];
        for (int rr = 0; rr < 16; ++rr)
            h_cls[(size_t)(row0 + rr) * 64 + lane] = f2bf(silu_f(ms[rr * 66 + lane]));
    }
}

// ---------------------------------------------------------------- lit-side gather (scalarized indices, 8-way MLP)
__global__ __launch_bounds__(256, 8) void gather_lit_kernel(
    const unsigned short* __restrict__ S, const int* __restrict__ rp,
    const int* __restrict__ clss, const float* __restrict__ inv_deg,
    unsigned short* __restrict__ m_out) {
    int nw = (gridDim.x * blockDim.x) >> 6;
    int wid = (blockIdx.x * blockDim.x + threadIdx.x) >> 6;
    int lane = threadIdx.x & 63;
    const unsigned short* Sl = S + lane;
    for (int row = wid; row < N_LIT; row += nw) {
        int e0 = __builtin_amdgcn_readfirstlane(rp[row]);
        int e1 = __builtin_amdgcn_readfirstlane(rp[row + 1]);
        float g0 = 0.f, g1 = 0.f, g2 = 0.f, g3 = 0.f;
        float g4 = 0.f, g5 = 0.f, g6 = 0.f, g7 = 0.f;
        for (int base = e0; base < e1; base += 64) {
            int n = e1 - base; if (n > 64) n = 64;
            int myCls = (lane < n) ? clss[base + lane] : 0;
            int i = 0;
            for (; i + 7 < n; i += 8) {
                int c0 = __builtin_amdgcn_readlane(myCls, i);
                int c1 = __builtin_amdgcn_readlane(myCls, i + 1);
                int c2 = __builtin_amdgcn_readlane(myCls, i + 2);
                int c3 = __builtin_amdgcn_readlane(myCls, i + 3);
                int c4 = __builtin_amdgcn_readlane(myCls, i + 4);
                int c5 = __builtin_amdgcn_readlane(myCls, i + 5);
                int c6 = __builtin_amdgcn_readlane(myCls, i + 6);
                int c7 = __builtin_amdgcn_readlane(myCls, i + 7);
                g0 += bf2f(Sl[(size_t)c0 * 64]);
                g1 += bf2f(Sl[(size_t)c1 * 64]);
                g2 += bf2f(Sl[(size_t)c2 * 64]);
                g3 += bf2f(Sl[(size_t)c3 * 64]);
                g4 += bf2f(Sl[(size_t)c4 * 64]);
                g5 += bf2f(Sl[(size_t)c5 * 64]);
                g6 += bf2f(Sl[(size_t)c6 * 64]);
                g7 += bf2f(Sl[(size_t)c7 * 64]);
            }
            for (; i + 3 < n; i += 4) {
                int c0 = __builtin_amdgcn_readlane(myCls, i);
                int c1 = __builtin_amdgcn_readlane(myCls, i + 1);
                int c2 = __builtin_amdgcn_readlane(myCls, i + 2);
                int c3 = __builtin_amdgcn_readlane(myCls, i + 3);
                g0 += bf2f(Sl[(size_t)c0 * 64]);
                g1 += bf2f(Sl[(size_t)c1 * 64]);
                g2 += bf2f(Sl[(size_t)c2 * 64]);
                g3 += bf2f(Sl[(size_t)c3 * 64]);
            }
            for (; i < n; ++i) {
                int c0 = __builtin_amdgcn_readlane(myCls, i);
                g0 += bf2f(Sl[(size_t)c0 * 64]);
            }
        }
        m_out[(size_t)row * 64 + lane] =
            f2bf((((g0 + g1) + (g2 + g3)) + ((g4 + g5) + (g6 + g7))) * inv_deg[row]);
    }
}

// ---------------------------------------------------------------- literal update (MFMA, in-place fp32, + fused next-layer X)
__global__ __launch_bounds__(256, 3) void lit_update_kernel(
    float* __restrict__ h, const unsigned short* __restrict__ m,
    const float* __restrict__ W, const float* __restrict__ b,
    const float* __restrict__ Wc_next, unsigned short* __restrict__ Xout) {
    __shared__ __align__(16) unsigned short Bp[24 * 64 * 8];
    __shared__ __align__(16) unsigned short Bp2[8 * 64 * 8];
    __shared__ float bs[64];
    __shared__ float stage[4][16 * 66];
    int t = threadIdx.x;
    for (int idx = t; idx < 24 * 64 * 8; idx += 256) {
        int i = idx & 7, ln = (idx >> 3) & 63, fid = idx >> 9;
        int ks = fid >> 2, nt = fid & 3;
        Bp[idx] = f2bf(W[(ks * 32 + ((ln >> 4) << 3) + i) * 64 + nt * 16 + (ln & 15)]);
    }
    if (Wc_next) {
        for (int idx = t; idx < 8 * 64 * 8; idx += 256) {
            int i = idx & 7, ln = (idx >> 3) & 63, fid = idx >> 9;
            int ks = fid >> 2, nt = fid & 3;
            Bp2[idx] = f2bf(Wc_next[(ks * 32 + ((ln >> 4) << 3) + i) * 64 + nt * 16 + (ln & 15)]);
        }
    }
    if (t < 64) bs[t] = b[t];
    __syncthreads();
    int w = t >> 6, lane = t & 63;
    int c = lane & 15, q = lane >> 4;
    bf16x8 Bf[24];
    #pragma unroll
    for (int f = 0; f < 24; ++f) Bf[f] = *(const bf16x8*)&Bp[(f * 64 + lane) * 8];
    float* ms = stage[w];
    int nwaves = gridDim.x * 4;
    int wid = blockIdx.x * 4 + w;
    for (int tile = wid; tile < N_LIT / 16; tile += nwaves) {
        int row0 = tile * 16;
        bf16x8 A[6];
        const float* hp = h + (size_t)(row0 + c) * 64 + q * 8;
        const float* hf = h + (size_t)((row0 + c) ^ 1) * 64 + q * 8;
        const unsigned short* mp = m + (size_t)(row0 + c) * 64 + q * 8;
        #pragma unroll
        for (int i = 0; i < 8; ++i) {
            A[0][i] = (short)f2bf(hp[i]);
            A[1][i] = (short)f2bf(hp[32 + i]);
            A[4][i] = (short)f2bf(hf[i]);
            A[5][i] = (short)f2bf(hf[32 + i]);
        }
        A[2] = *(const bf16x8*)(mp);
        A[3] = *(const bf16x8*)(mp + 32);
        f32x4 acc[4];
        #pragma unroll
        for (int nt = 0; nt < 4; ++nt) {
            float bv = bs[nt * 16 + c];
            acc[nt] = (f32x4){bv, bv, bv, bv};
            #pragma unroll
            for (int ks = 0; ks < 6; ++ks)
                acc[nt] = __builtin_amdgcn_mfma_f32_16x16x32_bf16(A[ks], Bf[ks * 4 + nt], acc[nt], 0, 0, 0);
        }
        #pragma unroll
        for (int nt = 0; nt < 4; ++nt)
            #pragma unroll
            for (int rg = 0; rg < 4; ++rg)
                ms[(q * 4 + rg) * 66 + nt * 16 + c] = silu_f(acc[nt][rg]);
        for (int r = 0; r < 16; ++r)
            h[(size_t)(row0 + r) * 64 + lane] = ms[r * 66 + lane];
        if (Wc_next) {
            bf16x8 NA0, NA1;
            const float* np = &ms[c * 66 + q * 8];
            #pragma unroll
            for (int i = 0; i < 8; ++i) {
                NA0[i] = (short)f2bf(np[i]);
                NA1[i] = (short)f2bf(np[32 + i]);
            }
            f32x4 xacc[4];
            #pragma unroll
            for (int nt = 0; nt < 4; ++nt) {
                xacc[nt] = (f32x4){0.f, 0.f, 0.f, 0.f};
                bf16x8 B0 = *(const bf16x8*)&Bp2[(nt * 64 + lane) * 8];
                xacc[nt] = __builtin_amdgcn_mfma_f32_16x16x32_bf16(NA0, B0, xacc[nt], 0, 0, 0);
                bf16x8 B1 = *(const bf16x8*)&Bp2[((4 + nt) * 64 + lane) * 8];
                xacc[nt] = __builtin_amdgcn_mfma_f32_16x16x32_bf16(NA1, B1, xacc[nt], 0, 0, 0);
            }
            #pragma unroll
            for (int nt = 0; nt < 4; ++nt)
                #pragma unroll
                for (int rg = 0; rg < 4; ++rg)
                    ms[(q * 4 + rg) * 66 + nt * 16 + c] = xacc[nt][rg];
            for (int r = 0; r < 16; ++r)
                Xout[(size_t)(row0 + r) * 64 + lane] = f2bf(ms[r * 66 + lane]);
        }
    }
}

// ---------------------------------------------------------------- readout stage 1 (fp32 VALU -> bf16 hid)
__global__ __launch_bounds__(256) void var_hidden_kernel(
    const float* __restrict__ h_var, const float* __restrict__ W,
    const float* __restrict__ b, int colofs, unsigned short* __restrict__ hid) {
    __shared__ float Ws[128 * 64];
    __shared__ float bs[64];
    __shared__ float rs[16 * 128];
    int t = threadIdx.x;
    for (int i = t; i < 128 * 64; i += 256) {
        int k = i >> 6, j = i & 63;
        Ws[i] = W[k * 128 + colofs + j];
    }
    if (t < 64) bs[t] = b[colofs + t];
    __syncthreads();
    const int ntiles = NVAR / 16;
    int w = t >> 6, j = t & 63;
    for (int tile = blockIdx.x; tile < ntiles; tile += gridDim.x) {
        int row0 = tile * 16;
        for (int i = t; i < 2048; i += 256) rs[i] = h_var[(size_t)row0 * 128 + i];
        __syncthreads();
        float acc0 = bs[j], acc1 = bs[j], acc2 = bs[j], acc3 = bs[j];
        const float* r0 = &rs[(w * 4 + 0) * 128];
        const float* r1 = &rs[(w * 4 + 1) * 128];
        const float* r2 = &rs[(w * 4 + 2) * 128];
        const float* r3 = &rs[(w * 4 + 3) * 128];
        #pragma unroll 4
        for (int k = 0; k < 128; k += 4) {
            float w0 = Ws[k * 64 + j], w1v = Ws[(k + 1) * 64 + j];
            float w2v = Ws[(k + 2) * 64 + j], w3v = Ws[(k + 3) * 64 + j];
            float4 a;
            a = *(const float4*)(r0 + k); acc0 += a.x * w0 + a.y * w1v + a.z * w2v + a.w * w3v;
            a = *(const float4*)(r1 + k); acc1 += a.x * w0 + a.y * w1v + a.z * w2v + a.w * w3v;
            a = *(const float4*)(r2 + k); acc2 += a.x * w0 + a.y * w1v + a.z * w2v + a.w * w3v;
            a = *(const float4*)(r3 + k); acc3 += a.x * w0 + a.y * w1v + a.z * w2v + a.w * w3v;
        }
        int row = row0 + w * 4;
        hid[(size_t)(row + 0) * 128 + colofs + j] = f2bf(silu_f(acc0));
        hid[(size_t)(row + 1) * 128 + colofs + j] = f2bf(silu_f(acc1));
        hid[(size_t)(row + 2) * 128 + colofs + j] = f2bf(silu_f(acc2));
        hid[(size_t)(row + 3) * 128 + colofs + j] = f2bf(silu_f(acc3));
        __syncthreads();
    }
}

// ---------------------------------------------------------------- readout stage 2
__global__ __launch_bounds__(256) void out2_kernel(
    const unsigned short* __restrict__ hid, const float* __restrict__ w2,
    const float* __restrict__ b2, float* __restrict__ out) {
    int nw = (gridDim.x * blockDim.x) >> 6;
    int wid = (blockIdx.x * blockDim.x + threadIdx.x) >> 6;
    int lane = threadIdx.x & 63;
    float w00 = w2[lane * 2 + 0], w01 = w2[lane * 2 + 1];
    float w10 = w2[(lane + 64) * 2 + 0], w11 = w2[(lane + 64) * 2 + 1];
    for (int row = wid; row < NVAR; row += nw) {
        float h0 = bf2f(hid[(size_t)row * 128 + lane]);
        float h1 = bf2f(hid[(size_t)row * 128 + 64 + lane]);
        float p0 = h0 * w00 + h1 * w10;
        float p1 = h0 * w01 + h1 * w11;
        #pragma unroll
        for (int off = 32; off > 0; off >>= 1) {
            p0 += __shfl_down(p0, off);
            p1 += __shfl_down(p1, off);
        }
        if (lane == 0) {
            out[(size_t)row * 2 + 0] = p0 + b2[0];
            out[(size_t)row * 2 + 1] = p1 + b2[1];
        }
    }
}

// ---------------------------------------------------------------- launch
extern "C" void kernel_launch(void* const* d_in, const int* in_sizes, int n_in,
                              void* d_out, int out_size, void* d_ws, size_t ws_size,
                              hipStream_t stream) {
    const float* x_lit  = (const float*)d_in[0];
    const float* x_cls  = (const float*)d_in[1];
    const int* edge_lit = (const int*)d_in[2];
    const int* edge_cls = (const int*)d_in[3];
    const float* enc_w1 = (const float*)d_in[4];
    const float* enc_b1 = (const float*)d_in[5];
    const float* enc_w2 = (const float*)d_in[6];
    const float* enc_b2 = (const float*)d_in[7];
    const float* Wc     = (const float*)d_in[8];    // [4][128][64]
    const float* bc     = (const float*)d_in[9];
    const float* Wl     = (const float*)d_in[10];   // [4][192][64]
    const float* bl     = (const float*)d_in[11];
    const float* out_w1 = (const float*)d_in[12];   // [128][128]
    const float* out_b1 = (const float*)d_in[13];
    const float* out_w2 = (const float*)d_in[14];   // [128][2]
    const float* out_b2 = (const float*)d_in[15];
    float* y = (float*)d_out;

    // ---- workspace carve (~208 MB) ----
    const size_t SZ_HLIT = (size_t)N_LIT * 64;
    const size_t SZ_HCLS = (size_t)N_CLS * 64;
    char* p = (char*)d_ws;
    auto take = [&](size_t bytes) -> char* {
        char* r = p; p += (bytes + 255) & ~(size_t)255; return r;
    };
    float*          h_lit      = (float*)take(SZ_HLIT * 4);
    unsigned short* h_cls      = (unsigned short*)take(SZ_HCLS * 2);
    unsigned short* X          = (unsigned short*)take(SZ_HLIT * 2);
    float*          inv_cls    = (float*)take((size_t)N_CLS * 4);
    float*          inv_lit    = (float*)take((size_t)N_LIT * 4);
    int*            row_ptr_cls= (int*)take((size_t)(N_CLS + 1) * 4);
    int*            row_ptr_lit= (int*)take((size_t)(N_LIT + 1) * 4);
    int*            lit_by_cls = (int*)take((size_t)NEDGE * 4);
    int*            cls_by_lit = (int*)take((size_t)NEDGE * 4);
    int*            bh         = (int*)take((size_t)NBLK_S * NBKT * 4);
    int*            off        = (int*)take((size_t)NBLK_S * NBKT * 4);
    int*            bktbase    = (int*)take((size_t)(NBKT + 1) * 4);
    size_t need = (size_t)(p - (char*)d_ws);

    // pair buffer aliases h_lit (dead until encoder): 19.2 MB <= 51.2 MB
    int2* tmp_pairs = (int2*)h_lit;

    dim3 B(256);

    if (ws_size < need) {
        float mb = (float)((double)ws_size / (1024.0 * 1024.0));
        diag_kernel<<<256, B, 0, stream>>>(y, out_size, mb);
        return;
    }

    // ---- CSR build (radix partition) ----
    csr_hist_kernel<<<NBLK_S, B, 0, stream>>>(edge_cls, 12, bh);
    csr_offsets_kernel<<<1, B, 0, stream>>>(bh, off, bktbase);
    csr_scatter_kernel<<<NBLK_S, B, 0, stream>>>(edge_cls, edge_lit, 12, off, tmp_pairs);
    csr_build_kernel<<<NBKT, B, 0, stream>>>(tmp_pairs, bktbase, 4096, N_CLS,
                                             row_ptr_cls, inv_cls, lit_by_cls);
    csr_hist_kernel<<<NBLK_S, B, 0, stream>>>(edge_lit, 10, bh);
    csr_offsets_kernel<<<1, B, 0, stream>>>(bh, off, bktbase);
    csr_scatter_kernel<<<NBLK_S, B, 0, stream>>>(edge_lit, edge_cls, 10, off, tmp_pairs);
    csr_build_kernel<<<NBKT, B, 0, stream>>>(tmp_pairs, bktbase, 1024, N_LIT,
                                             row_ptr_lit, inv_lit, cls_by_lit);
    tail_kernel<<<1, 64, 0, stream>>>(row_ptr_cls, row_ptr_lit);

    // ---- encoder (overwrites tmp_pairs alias region) ----
    encoder_kernel<<<2048, B, 0, stream>>>(x_lit, x_cls, enc_w1, enc_b1, enc_w2, enc_b2,
                                           h_lit, h_cls);

    // layer-0 X; layers 1..3 get X from lit_update's fused epilogue
    gemmX_kernel<<<1024, B, 0, stream>>>(h_lit, Wc + 64 * 64, X);

    for (int l = 0; l < 4; ++l) {
        const float* Wl_l = Wl + (size_t)l * 192 * 64;
        const float* Wc_next = (l < 3) ? (Wc + (size_t)(l + 1) * 128 * 64 + 64 * 64) : nullptr;
        cls_update_kernel<<<2048, B, 0, stream>>>(h_cls, X, row_ptr_cls, lit_by_cls,
                                                  inv_cls, Wc + (size_t)l * 128 * 64,
                                                  bc + l * 64);
        gather_lit_kernel<<<4096, B, 0, stream>>>(h_cls, row_ptr_lit, cls_by_lit,
                                                  inv_lit, X);
        lit_update_kernel<<<1024, B, 0, stream>>>(h_lit, X, Wl_l, bl + l * 64,
                                                  Wc_next, X);
    }

    // ---- readout ----
    var_hidden_kernel<<<4096, B, 0, stream>>>(h_lit, out_w1, out_b1, 0, X);
    var_hidden_kernel<<<4096, B, 0, stream>>>(h_lit, out_w1, out_b1, 64, X);
    out2_kernel<<<2048, B, 0, stream>>>(X, out_w2, out_b2, y);
}